// Round 5
// baseline (255.208 us; speedup 1.0000x reference)
//
#include <hip/hip_runtime.h>

// Problem constants: B=4, C=64, H=W=64, N=4096
// Workspace layout (float offsets) — 4,747,264 floats (same proven footprint).
#define OFF_POS   0u
#define OFF_QTH   1048576u
#define OFF_QTL   1572864u
#define OFF_KTH   2097152u
#define OFF_KTL   2621440u
#define OFF_VBH   3145728u
#define OFF_VBL   3670016u
#define OFF_WT    4194304u
#define OFF_INVL  4452352u
#define OFF_GPART 4468736u   // Gram partials; after k_asm reused as lpart (16*4*4096 = 262144 exact)
#define OFF_A     4730880u
#define WS_FLOATS 4747264u

typedef short s8v __attribute__((ext_vector_type(8)));
typedef float f4v __attribute__((ext_vector_type(4)));

#define MFMA16(a, b, c) __builtin_amdgcn_mfma_f32_16x16x32_bf16((a), (b), (c), 0, 0, 0)

__device__ __forceinline__ unsigned short bf16_rne(float f) {
    union { float f; unsigned int u; } v; v.f = f;
    unsigned int r = v.u + 0x7FFFu + ((v.u >> 16) & 1u);
    return (unsigned short)(r >> 16);
}
__device__ __forceinline__ float bf2f(unsigned short h) {
    union { unsigned int u; float f; } t; t.u = ((unsigned int)h) << 16;
    return t.f;
}
__device__ __forceinline__ void split2(float f, unsigned short& h, unsigned short& l) {
    unsigned short hh = bf16_rne(f);
    h = hh;
    l = bf16_rne(f - bf2f(hh));
}
// async global->LDS: lane copies 16B from (g + lane*16B) to ldsbase + lane*16B
__device__ __forceinline__ void gl_lds16(const unsigned short* g, unsigned short* l) {
    __builtin_amdgcn_global_load_lds(
        (const __attribute__((address_space(1))) unsigned int*)g,
        (__attribute__((address_space(3))) unsigned int*)l, 16, 0, 0);
}

// ---------------- weight transpose: w[o][ci][3][3] -> wt[conv][ci*9+tap][o]
__global__ void k_wtrans(const float* __restrict__ wq, const float* __restrict__ wk,
                         const float* __restrict__ wv, float* __restrict__ wt) {
    int idx = blockIdx.x * 256 + threadIdx.x;     // < 3*36864
    int conv = idx / 36864;
    int r = idx % 36864;
    int o = r & 63;
    int t2 = r >> 6;            // ci*9+tap
    int ci = t2 / 9, tap = t2 % 9;
    const float* w = (conv == 0) ? wq : (conv == 1) ? wk : wv;
    wt[idx] = w[(o * 64 + ci) * 9 + tap];
}

// ---------------- fused 3x3 conv (SAME) writing split-bf16 outputs
__global__ __launch_bounds__(256) void k_conv(
        const float* __restrict__ x, const float* __restrict__ wt,
        const float* __restrict__ bq, const float* __restrict__ bk, const float* __restrict__ bv,
        unsigned short* __restrict__ qth, unsigned short* __restrict__ qtl,
        unsigned short* __restrict__ kth, unsigned short* __restrict__ ktl,
        unsigned short* __restrict__ vbh, unsigned short* __restrict__ vbl) {
    int h = blockIdx.x, b = blockIdx.y, conv = blockIdx.z;
    const float* bias = (conv == 0) ? bq : (conv == 1) ? bk : bv;
    const float* wtc = wt + conv * 36864;

    __shared__ float xch[16 * 3 * 66];   // [cil][dy][col], col 0 & 65 zero pad
    __shared__ float wch[16 * 9 * 64];   // [cil][tap][o]

    int tid = threadIdx.x;
    int wtd = tid & 15, ot = tid >> 4;
    int w0 = wtd * 4, o0 = ot * 4;

    float acc[4][4];
    {
        float4 b4 = *(const float4*)(bias + o0);
        float bb[4] = {b4.x, b4.y, b4.z, b4.w};
#pragma unroll
        for (int oo = 0; oo < 4; ++oo)
#pragma unroll
            for (int ww = 0; ww < 4; ++ww) acc[oo][ww] = bb[oo];
    }

    for (int ck = 0; ck < 4; ++ck) {
        __syncthreads();
        for (int idx = tid; idx < 3168; idx += 256) {
            int col = idx % 66;
            int row = idx / 66;
            int dy = row % 3, cil = row / 3;
            int ci = ck * 16 + cil;
            int hs = h + dy - 1;
            float val = 0.0f;
            if (col >= 1 && col <= 64 && hs >= 0 && hs < 64)
                val = x[((b * 64 + ci) * 64 + hs) * 64 + (col - 1)];
            xch[(cil * 3 + dy) * 66 + col] = val;
        }
        for (int idx = tid; idx < 2304; idx += 256)
            ((float4*)wch)[idx] = ((const float4*)(wtc + ck * 9216))[idx];
        __syncthreads();

        for (int cil = 0; cil < 16; ++cil) {
#pragma unroll
            for (int dy = 0; dy < 3; ++dy) {
                float xv[6];
#pragma unroll
                for (int s = 0; s < 6; ++s) xv[s] = xch[(cil * 3 + dy) * 66 + w0 + s];
#pragma unroll
                for (int dx = 0; dx < 3; ++dx) {
                    float4 w4 = ((const float4*)wch)[(cil * 9 + dy * 3 + dx) * 16 + ot];
                    float wa[4] = {w4.x, w4.y, w4.z, w4.w};
#pragma unroll
                    for (int oo = 0; oo < 4; ++oo)
#pragma unroll
                        for (int ww = 0; ww < 4; ++ww)
                            acc[oo][ww] += xv[ww + dx] * wa[oo];
                }
            }
        }
    }

    if (conv < 2) {
        unsigned short* oh = (conv == 0) ? qth : kth;
        unsigned short* ol = (conv == 0) ? qtl : ktl;
#pragma unroll
        for (int ww = 0; ww < 4; ++ww) {
            unsigned short h4[4], l4[4];
#pragma unroll
            for (int oo = 0; oo < 4; ++oo) split2(acc[oo][ww], h4[oo], l4[oo]);
            int ad = (b * 4096 + h * 64 + w0 + ww) * 64 + o0;
            uint2 hv, lv;
            hv.x = h4[0] | ((unsigned int)h4[1] << 16);
            hv.y = h4[2] | ((unsigned int)h4[3] << 16);
            lv.x = l4[0] | ((unsigned int)l4[1] << 16);
            lv.y = l4[2] | ((unsigned int)l4[3] << 16);
            *(uint2*)(oh + ad) = hv;
            *(uint2*)(ol + ad) = lv;
        }
    } else {
        int cb = o0 >> 4, ccb = o0 & 15;
#pragma unroll
        for (int ww = 0; ww < 4; ++ww) {
            int n = h * 64 + w0 + ww;
            int n8 = n >> 3, e = n & 7;
            int basead = ((b * 4 + cb) * 512 + n8) * 16;
#pragma unroll
            for (int oo = 0; oo < 4; ++oo) {
                unsigned short hh, ll;
                split2(acc[oo][ww], hh, ll);
                vbh[(basead + ccb + oo) * 8 + e] = hh;
                vbl[(basead + ccb + oo) * 8 + e] = ll;
            }
        }
    }
}

// ---------------- channel Gram partials (unchanged)
__global__ __launch_bounds__(256) void k_gram(const float* __restrict__ x, float* __restrict__ Gpart) {
    int nc = blockIdx.x, b = blockIdx.y;
    __shared__ float xs[64 * 257];
    int tid = threadIdx.x;
    for (int it = 0; it < 16; ++it) {
        int f4i = tid + it * 256;
        int c = f4i >> 6, n4 = f4i & 63;
        float4 vv = *(const float4*)(x + (b * 64 + c) * 4096 + nc * 256 + n4 * 4);
        xs[c * 257 + n4 * 4 + 0] = vv.x;
        xs[c * 257 + n4 * 4 + 1] = vv.y;
        xs[c * 257 + n4 * 4 + 2] = vv.z;
        xs[c * 257 + n4 * 4 + 3] = vv.w;
    }
    __syncthreads();
    int tc = tid & 15, td = tid >> 4;
    int c0 = tc * 4, d0 = td * 4;
    float acc[4][4];
#pragma unroll
    for (int i = 0; i < 4; ++i)
#pragma unroll
        for (int j = 0; j < 4; ++j) acc[i][j] = 0.0f;
    for (int n = 0; n < 256; ++n) {
        float xc[4], xd[4];
#pragma unroll
        for (int i = 0; i < 4; ++i) xc[i] = xs[(c0 + i) * 257 + n];
#pragma unroll
        for (int j = 0; j < 4; ++j) xd[j] = xs[(d0 + j) * 257 + n];
#pragma unroll
        for (int i = 0; i < 4; ++i)
#pragma unroll
            for (int j = 0; j < 4; ++j) acc[i][j] += xc[i] * xd[j];
    }
#pragma unroll
    for (int i = 0; i < 4; ++i) {
        float4 o4 = {acc[i][0], acc[i][1], acc[i][2], acc[i][3]};
        *(float4*)(Gpart + ((nc * 4 + b) * 64 + c0 + i) * 64 + d0) = o4;
    }
}

// ---------------- channel softmax rows (unchanged)
__global__ void k_asm(const float* __restrict__ Gpart, float* __restrict__ A) {
    int row = blockIdx.x;      // b*64 + c
    int d = threadIdx.x;
    int b = row >> 6, c = row & 63;
    float g = 0.0f;
    for (int p = 0; p < 16; ++p) g += Gpart[(p * 4 + b) * 4096 + c * 64 + d];
    float mx = g;
    for (int off = 32; off >= 1; off >>= 1) mx = fmaxf(mx, __shfl_xor(mx, off, 64));
    float e = __expf(g - mx);
    float s = e;
    for (int off = 32; off >= 1; off >>= 1) s += __shfl_xor(s, off, 64);
    A[row * 64 + d] = e / s;
}

// ---------------- pass1: row sums l_i = sum_j exp(s_ij).
// grid 1024 = (itile 16 x jp 16 x b 4); block 256 (4 waves), wave = 64 i-rows.
// K tiles (64 j) LDS-staged; 4 blocks/CU.
__global__ __launch_bounds__(256, 4) void k_pass1(
        const unsigned short* __restrict__ qth, const unsigned short* __restrict__ qtl,
        const unsigned short* __restrict__ kth, const unsigned short* __restrict__ ktl,
        float* __restrict__ lpart) {
    int flat = blockIdx.x;                       // 0..1023
    int xcd = flat & 7, hi = flat >> 3;          // hi 0..127
    int b = xcd >> 1;
    int rem = (xcd & 1) * 128 + hi;              // 0..255
    int itile = rem & 15, jp = rem >> 4;         // itile 0..15, jp 0..15

    __shared__ unsigned short ksh[64 * 72];      // stride 72 shorts
    __shared__ unsigned short ksl[64 * 72];

    int tid = threadIdx.x;
    int lane = tid & 63, wv = tid >> 6;
    int l15 = lane & 15, g = lane >> 4;
    int iw = itile * 256 + wv * 64;              // wave strip base (64 rows)

    s8v qa[4][4];                                // [sub-strip][h0,l0,h1,l1]
#pragma unroll
    for (int ss = 0; ss < 4; ++ss) {
        int qb = (b * 4096 + iw + ss * 16 + l15) * 64 + g * 8;
        qa[ss][0] = *(const s8v*)(qth + qb);
        qa[ss][1] = *(const s8v*)(qtl + qb);
        qa[ss][2] = *(const s8v*)(qth + qb + 32);
        qa[ss][3] = *(const s8v*)(qtl + qb + 32);
    }

    float l[4][4];
#pragma unroll
    for (int ss = 0; ss < 4; ++ss)
#pragma unroll
        for (int r = 0; r < 4; ++r) l[ss][r] = 0.f;

    for (int jt = 0; jt < 4; ++jt) {
        int j0 = jp * 256 + jt * 64;
        __syncthreads();
#pragma unroll
        for (int itr = 0; itr < 2; ++itr) {      // 512 16B-segs, 2 per thread
            int s = tid + itr * 256;
            int row = s >> 3, c16 = s & 7;
            int gsrc = (b * 4096 + j0 + row) * 64 + c16 * 8;
            *(s8v*)(ksh + row * 72 + c16 * 8) = *(const s8v*)(kth + gsrc);
            *(s8v*)(ksl + row * 72 + c16 * 8) = *(const s8v*)(ktl + gsrc);
        }
        __syncthreads();
#pragma unroll
        for (int js = 0; js < 4; ++js) {
            int ro = (js * 16 + l15) * 72 + g * 8;
            s8v bh0 = *(const s8v*)(ksh + ro);
            s8v bl0 = *(const s8v*)(ksl + ro);
            s8v bh1 = *(const s8v*)(ksh + ro + 32);
            s8v bl1 = *(const s8v*)(ksl + ro + 32);
#pragma unroll
            for (int ss = 0; ss < 4; ++ss) {
                f4v acc = {0.f, 0.f, 0.f, 0.f};
                acc = MFMA16(qa[ss][0], bh0, acc);
                acc = MFMA16(qa[ss][0], bl0, acc);
                acc = MFMA16(qa[ss][1], bh0, acc);
                acc = MFMA16(qa[ss][2], bh1, acc);
                acc = MFMA16(qa[ss][2], bl1, acc);
                acc = MFMA16(qa[ss][3], bh1, acc);
                l[ss][0] += __expf(acc[0]);
                l[ss][1] += __expf(acc[1]);
                l[ss][2] += __expf(acc[2]);
                l[ss][3] += __expf(acc[3]);
            }
        }
    }
#pragma unroll
    for (int ss = 0; ss < 4; ++ss)
#pragma unroll
        for (int r = 0; r < 4; ++r) {
            float s = l[ss][r];
            s += __shfl_xor(s, 1);
            s += __shfl_xor(s, 2);
            s += __shfl_xor(s, 4);
            s += __shfl_xor(s, 8);
            l[ss][r] = s;
        }
    if (l15 == 0) {
        int ib = (jp * 4 + b) * 4096 + iw + g * 4;
#pragma unroll
        for (int ss = 0; ss < 4; ++ss)
#pragma unroll
            for (int r = 0; r < 4; ++r)
                lpart[ib + ss * 16 + r] = l[ss][r];
    }
}

// ---------------- merge 16 j-partials -> 1/l
__global__ void k_merge(const float* __restrict__ lpart, float* __restrict__ invl) {
    int idx = blockIdx.x * 256 + threadIdx.x;
    float s = 0.0f;
#pragma unroll
    for (int p = 0; p < 16; ++p) s += lpart[p * 16384 + idx];
    invl[idx] = 1.0f / s;
}

// ---------------- fold invl into V: vbh <- bf16((vh+vl) * invl_n), hi-only
__global__ __launch_bounds__(256) void k_vnorm(
        unsigned short* __restrict__ vbh, const unsigned short* __restrict__ vbl,
        const float* __restrict__ invl) {
    int u = blockIdx.x * 256 + threadIdx.x;      // < 131072
    int cc = u & 15, n8 = (u >> 4) & 511, cb = (u >> 13) & 3, b = u >> 15;
    int base = (((b * 4 + cb) * 512 + n8) * 16 + cc) * 8;
    s8v vh = *(s8v*)(vbh + base);
    s8v vl = *(const s8v*)(vbl + base);
    float4 iv0 = *(const float4*)(invl + b * 4096 + n8 * 8);
    float4 iv1 = *(const float4*)(invl + b * 4096 + n8 * 8 + 4);
    float ivv[8] = {iv0.x, iv0.y, iv0.z, iv0.w, iv1.x, iv1.y, iv1.z, iv1.w};
    s8v o;
#pragma unroll
    for (int e = 0; e < 8; ++e) {
        float v = bf2f((unsigned short)vh[e]) + bf2f((unsigned short)vl[e]);
        o[e] = (short)bf16_rne(v * ivv[e]);
    }
    *(s8v*)(vbh + base) = o;
}

// ---------------- pass2: grid 512 (2 blocks/CU), block 512 (8 waves), j-tile 32.
// K (32 j) in regs; V' (hi-only, invl-folded) double-buffered via global_load_lds;
// P = exp(s) hi-only bf16 in LDS [j][i].
__global__ __launch_bounds__(512, 4) void k_pass2(
        const unsigned short* __restrict__ qth, const unsigned short* __restrict__ qtl,
        const unsigned short* __restrict__ kth, const unsigned short* __restrict__ ktl,
        const unsigned short* __restrict__ vbh, float* __restrict__ pos) {
    int flat = blockIdx.x;                      // 0..511
    int xcd = flat & 7, slot = flat >> 3;       // slot 0..63
    int b = xcd >> 1;
    int jt = (xcd & 1) * 64 + slot;             // 0..127
    int j0 = jt * 32;

    int tid = threadIdx.x;
    int lane = tid & 63, wv = tid >> 6;
    int l15 = lane & 15, g = lane >> 4;

    __shared__ unsigned short Pt[32][136];      // [j][i 0..127]
    __shared__ unsigned short Vt[2][4][2048];   // [buf][cb][n8' 16][cc 16][e 8]

    s8v kf[2][4];                               // [js][{h0,l0,h1,l1}]
#pragma unroll
    for (int js = 0; js < 2; ++js) {
        int kb = (b * 4096 + j0 + js * 16 + l15) * 64 + g * 8;
        kf[js][0] = *(const s8v*)(kth + kb);
        kf[js][1] = *(const s8v*)(ktl + kb);
        kf[js][2] = *(const s8v*)(kth + kb + 32);
        kf[js][3] = *(const s8v*)(ktl + kb + 32);
    }

    int cq = wv & 3, jh = wv >> 2;
    f4v oacc = {0.f, 0.f, 0.f, 0.f};

    // stage 128-i chunk of V' for iteration `it` into Vt[buf].
    // 8 waves: wave handles (cb = wv&3, half h4 = wv>>2): 2 KB each.
    auto stageV = [&](int buf, int it) {
        int cb = wv & 3, h4 = wv >> 2;
        const unsigned short* sp = vbh + (((b * 4 + cb) * 512 + it * 16) * 128) + h4 * 1024;
        unsigned short* dp = &Vt[buf][cb][h4 * 1024];
        gl_lds16(sp + lane * 8, dp);
        gl_lds16(sp + 512 + lane * 8, dp + 512);
    };

    stageV(0, 0);
    for (int it = 0; it < 32; ++it) {
        int buf = it & 1;
        __syncthreads();                 // prev PV done reading Pt and Vt[buf^1]
        if (it < 31) stageV(buf ^ 1, it + 1);

        // ---- QK phase: wave = 16-row i-strip of the 128-chunk
        int iw = it * 128 + wv * 16;
        int qb = (b * 4096 + iw + l15) * 64 + g * 8;
        s8v qa0 = *(const s8v*)(qth + qb);
        s8v ql0 = *(const s8v*)(qtl + qb);
        s8v qa1 = *(const s8v*)(qth + qb + 32);
        s8v ql1 = *(const s8v*)(qtl + qb + 32);

#pragma unroll
        for (int js = 0; js < 2; ++js) {
            f4v acc = {0.f, 0.f, 0.f, 0.f};
            acc = MFMA16(qa0, kf[js][0], acc);
            acc = MFMA16(qa0, kf[js][1], acc);
            acc = MFMA16(ql0, kf[js][0], acc);
            acc = MFMA16(qa1, kf[js][2], acc);
            acc = MFMA16(qa1, kf[js][3], acc);
            acc = MFMA16(ql1, kf[js][2], acc);
            unsigned short pw[4];
#pragma unroll
            for (int r = 0; r < 4; ++r) pw[r] = bf16_rne(__expf(acc[r]));
            uint2 pk;
            pk.x = pw[0] | ((unsigned int)pw[1] << 16);
            pk.y = pw[2] | ((unsigned int)pw[3] << 16);
            *(uint2*)&Pt[js * 16 + l15][wv * 16 + g * 4] = pk;
        }
        __syncthreads();                 // Pt ready; Vt[buf] drained

        // ---- PV phase: wave = (cq: 16 c) x (jh: 16 j); 4 k-steps of 32 i
#pragma unroll
        for (int ks = 0; ks < 4; ++ks) {
            s8v ah = *(const s8v*)&Vt[buf][cq][((ks * 4 + g) * 16 + l15) * 8];
            s8v p = *(const s8v*)&Pt[jh * 16 + l15][ks * 32 + g * 8];
            oacc = MFMA16(ah, p, oacc);
        }
    }

    int cb2 = b * 64 + cq * 16 + g * 4;
    int jb = j0 + jh * 16 + l15;
#pragma unroll
    for (int r = 0; r < 4; ++r)
        pos[(cb2 + r) * 4096 + jb] = oacc[r];
}

// ---------------- final: out = pg*pos + cg*(A@x) + 2*x, LDS-staged x tile
__global__ __launch_bounds__(256) void k_final(
        const float* __restrict__ x, const float* __restrict__ pos,
        const float* __restrict__ A, const float* __restrict__ pg,
        const float* __restrict__ cg, float* __restrict__ out) {
    int n0 = blockIdx.x * 256, cg8 = blockIdx.y, b = blockIdx.z;
    __shared__ float xs[64 * 256];
    int tid = threadIdx.x;
    for (int it = 0; it < 16; ++it) {
        int idx = tid + it * 256;           // float4 index
        int d = idx >> 6, n4 = idx & 63;
        *(float4*)(xs + d * 256 + n4 * 4) =
            *(const float4*)(x + (b * 64 + d) * 4096 + n0 + n4 * 4);
    }
    __syncthreads();
    float pgv = pg[0], cgv = cg[0];
    int cbase = cg8 * 8;
#pragma unroll
    for (int c8 = 0; c8 < 8; ++c8) {
        int c = cbase + c8;
        const float* Ar = A + (b * 64 + c) * 64;
        float acc = 0.0f;
#pragma unroll
        for (int d = 0; d < 64; ++d) acc += Ar[d] * xs[d * 256 + tid];
        float xc = xs[c * 256 + tid];
        float p = pos[(b * 64 + c) * 4096 + n0 + tid];
        out[(b * 64 + c) * 4096 + n0 + tid] = pgv * p + cgv * acc + 2.0f * xc;
    }
}

extern "C" void kernel_launch(void* const* d_in, const int* in_sizes, int n_in,
                              void* d_out, int out_size, void* d_ws, size_t ws_size,
                              hipStream_t stream) {
    const float* x  = (const float*)d_in[0];
    const float* wq = (const float*)d_in[1];
    const float* bq = (const float*)d_in[2];
    const float* wk = (const float*)d_in[3];
    const float* bk = (const float*)d_in[4];
    const float* wv = (const float*)d_in[5];
    const float* bv = (const float*)d_in[6];
    const float* pg = (const float*)d_in[7];
    const float* cg = (const float*)d_in[8];
    float* out = (float*)d_out;

    if (ws_size < (size_t)WS_FLOATS * sizeof(float)) return;
    float* ws = (float*)d_ws;
    float* pos  = ws + OFF_POS;
    unsigned short* qth = (unsigned short*)(ws + OFF_QTH);
    unsigned short* qtl = (unsigned short*)(ws + OFF_QTL);
    unsigned short* kth = (unsigned short*)(ws + OFF_KTH);
    unsigned short* ktl = (unsigned short*)(ws + OFF_KTL);
    unsigned short* vbh = (unsigned short*)(ws + OFF_VBH);
    unsigned short* vbl = (unsigned short*)(ws + OFF_VBL);
    float* wt   = ws + OFF_WT;
    float* invl = ws + OFF_INVL;
    float* Gp   = ws + OFF_GPART;    // Gram partials, then reused as lpart
    float* A    = ws + OFF_A;

    k_wtrans<<<432, 256, 0, stream>>>(wq, wk, wv, wt);
    k_conv<<<dim3(64, 4, 3), 256, 0, stream>>>(x, wt, bq, bk, bv, qth, qtl, kth, ktl, vbh, vbl);
    k_gram<<<dim3(16, 4), 256, 0, stream>>>(x, Gp);
    k_asm<<<256, 64, 0, stream>>>(Gp, A);
    // Gp region now free -> lpart (16*4*4096 floats, exact fit)
    k_pass1<<<1024, 256, 0, stream>>>(qth, qtl, kth, ktl, Gp);
    k_merge<<<64, 256, 0, stream>>>(Gp, invl);
    k_vnorm<<<512, 256, 0, stream>>>(vbh, vbl, invl);
    k_pass2<<<512, 512, 0, stream>>>(qth, qtl, kth, ktl, vbh, pos);
    k_final<<<dim3(16, 8, 4), 256, 0, stream>>>(x, pos, A, pg, cg, out);
}

// Round 6
// 229.936 us; speedup vs baseline: 1.1099x; 1.1099x over previous
//
#include <hip/hip_runtime.h>

// Problem constants: B=4, C=64, H=W=64, N=4096
// Workspace layout (float offsets) — 4,747,264 floats (same proven footprint).
#define OFF_POS   0u
#define OFF_QTH   1048576u
#define OFF_QTL   1572864u
#define OFF_KTH   2097152u
#define OFF_KTL   2621440u
#define OFF_VBH   3145728u
#define OFF_VBL   3670016u
#define OFF_WT    4194304u
#define OFF_INVL  4452352u
#define OFF_GPART 4468736u   // Gram partials; after k_asm reused as lpart (16*4*4096 = 262144 exact)
#define OFF_A     4730880u
#define WS_FLOATS 4747264u

typedef short s8v __attribute__((ext_vector_type(8)));
typedef float f4v __attribute__((ext_vector_type(4)));

#define MFMA16(a, b, c) __builtin_amdgcn_mfma_f32_16x16x32_bf16((a), (b), (c), 0, 0, 0)

__device__ __forceinline__ unsigned short bf16_rne(float f) {
    union { float f; unsigned int u; } v; v.f = f;
    unsigned int r = v.u + 0x7FFFu + ((v.u >> 16) & 1u);
    return (unsigned short)(r >> 16);
}
__device__ __forceinline__ float bf2f(unsigned short h) {
    union { unsigned int u; float f; } t; t.u = ((unsigned int)h) << 16;
    return t.f;
}
__device__ __forceinline__ void split2(float f, unsigned short& h, unsigned short& l) {
    unsigned short hh = bf16_rne(f);
    h = hh;
    l = bf16_rne(f - bf2f(hh));
}
// async global->LDS: lane copies 16B from (g + lane*16B) to ldsbase + lane*16B
__device__ __forceinline__ void gl_lds16(const unsigned short* g, unsigned short* l) {
    __builtin_amdgcn_global_load_lds(
        (const __attribute__((address_space(1))) unsigned int*)g,
        (__attribute__((address_space(3))) unsigned int*)l, 16, 0, 0);
}

// ---------------- weight transpose: w[o][ci][3][3] -> wt[conv][ci*9+tap][o]
__global__ void k_wtrans(const float* __restrict__ wq, const float* __restrict__ wk,
                         const float* __restrict__ wv, float* __restrict__ wt) {
    int idx = blockIdx.x * 256 + threadIdx.x;     // < 3*36864
    int conv = idx / 36864;
    int r = idx % 36864;
    int o = r & 63;
    int t2 = r >> 6;            // ci*9+tap
    int ci = t2 / 9, tap = t2 % 9;
    const float* w = (conv == 0) ? wq : (conv == 1) ? wk : wv;
    wt[idx] = w[(o * 64 + ci) * 9 + tap];
}

// ---------------- fused 3x3 conv (SAME) writing split-bf16 outputs
__global__ __launch_bounds__(256) void k_conv(
        const float* __restrict__ x, const float* __restrict__ wt,
        const float* __restrict__ bq, const float* __restrict__ bk, const float* __restrict__ bv,
        unsigned short* __restrict__ qth, unsigned short* __restrict__ qtl,
        unsigned short* __restrict__ kth, unsigned short* __restrict__ ktl,
        unsigned short* __restrict__ vbh, unsigned short* __restrict__ vbl) {
    int h = blockIdx.x, b = blockIdx.y, conv = blockIdx.z;
    const float* bias = (conv == 0) ? bq : (conv == 1) ? bk : bv;
    const float* wtc = wt + conv * 36864;

    __shared__ float xch[16 * 3 * 66];   // [cil][dy][col], col 0 & 65 zero pad
    __shared__ float wch[16 * 9 * 64];   // [cil][tap][o]

    int tid = threadIdx.x;
    int wtd = tid & 15, ot = tid >> 4;
    int w0 = wtd * 4, o0 = ot * 4;

    float acc[4][4];
    {
        float4 b4 = *(const float4*)(bias + o0);
        float bb[4] = {b4.x, b4.y, b4.z, b4.w};
#pragma unroll
        for (int oo = 0; oo < 4; ++oo)
#pragma unroll
            for (int ww = 0; ww < 4; ++ww) acc[oo][ww] = bb[oo];
    }

    for (int ck = 0; ck < 4; ++ck) {
        __syncthreads();
        for (int idx = tid; idx < 3168; idx += 256) {
            int col = idx % 66;
            int row = idx / 66;
            int dy = row % 3, cil = row / 3;
            int ci = ck * 16 + cil;
            int hs = h + dy - 1;
            float val = 0.0f;
            if (col >= 1 && col <= 64 && hs >= 0 && hs < 64)
                val = x[((b * 64 + ci) * 64 + hs) * 64 + (col - 1)];
            xch[(cil * 3 + dy) * 66 + col] = val;
        }
        for (int idx = tid; idx < 2304; idx += 256)
            ((float4*)wch)[idx] = ((const float4*)(wtc + ck * 9216))[idx];
        __syncthreads();

        for (int cil = 0; cil < 16; ++cil) {
#pragma unroll
            for (int dy = 0; dy < 3; ++dy) {
                float xv[6];
#pragma unroll
                for (int s = 0; s < 6; ++s) xv[s] = xch[(cil * 3 + dy) * 66 + w0 + s];
#pragma unroll
                for (int dx = 0; dx < 3; ++dx) {
                    float4 w4 = ((const float4*)wch)[(cil * 9 + dy * 3 + dx) * 16 + ot];
                    float wa[4] = {w4.x, w4.y, w4.z, w4.w};
#pragma unroll
                    for (int oo = 0; oo < 4; ++oo)
#pragma unroll
                        for (int ww = 0; ww < 4; ++ww)
                            acc[oo][ww] += xv[ww + dx] * wa[oo];
                }
            }
        }
    }

    if (conv < 2) {
        unsigned short* oh = (conv == 0) ? qth : kth;
        unsigned short* ol = (conv == 0) ? qtl : ktl;
#pragma unroll
        for (int ww = 0; ww < 4; ++ww) {
            unsigned short h4[4], l4[4];
#pragma unroll
            for (int oo = 0; oo < 4; ++oo) split2(acc[oo][ww], h4[oo], l4[oo]);
            int ad = (b * 4096 + h * 64 + w0 + ww) * 64 + o0;
            uint2 hv, lv;
            hv.x = h4[0] | ((unsigned int)h4[1] << 16);
            hv.y = h4[2] | ((unsigned int)h4[3] << 16);
            lv.x = l4[0] | ((unsigned int)l4[1] << 16);
            lv.y = l4[2] | ((unsigned int)l4[3] << 16);
            *(uint2*)(oh + ad) = hv;
            *(uint2*)(ol + ad) = lv;
        }
    } else {
        int cb = o0 >> 4, ccb = o0 & 15;
#pragma unroll
        for (int ww = 0; ww < 4; ++ww) {
            int n = h * 64 + w0 + ww;
            int n8 = n >> 3, e = n & 7;
            int basead = ((b * 4 + cb) * 512 + n8) * 16;
#pragma unroll
            for (int oo = 0; oo < 4; ++oo) {
                unsigned short hh, ll;
                split2(acc[oo][ww], hh, ll);
                vbh[(basead + ccb + oo) * 8 + e] = hh;
                vbl[(basead + ccb + oo) * 8 + e] = ll;
            }
        }
    }
}

// ---------------- channel Gram partials (unchanged)
__global__ __launch_bounds__(256) void k_gram(const float* __restrict__ x, float* __restrict__ Gpart) {
    int nc = blockIdx.x, b = blockIdx.y;
    __shared__ float xs[64 * 257];
    int tid = threadIdx.x;
    for (int it = 0; it < 16; ++it) {
        int f4i = tid + it * 256;
        int c = f4i >> 6, n4 = f4i & 63;
        float4 vv = *(const float4*)(x + (b * 64 + c) * 4096 + nc * 256 + n4 * 4);
        xs[c * 257 + n4 * 4 + 0] = vv.x;
        xs[c * 257 + n4 * 4 + 1] = vv.y;
        xs[c * 257 + n4 * 4 + 2] = vv.z;
        xs[c * 257 + n4 * 4 + 3] = vv.w;
    }
    __syncthreads();
    int tc = tid & 15, td = tid >> 4;
    int c0 = tc * 4, d0 = td * 4;
    float acc[4][4];
#pragma unroll
    for (int i = 0; i < 4; ++i)
#pragma unroll
        for (int j = 0; j < 4; ++j) acc[i][j] = 0.0f;
    for (int n = 0; n < 256; ++n) {
        float xc[4], xd[4];
#pragma unroll
        for (int i = 0; i < 4; ++i) xc[i] = xs[(c0 + i) * 257 + n];
#pragma unroll
        for (int j = 0; j < 4; ++j) xd[j] = xs[(d0 + j) * 257 + n];
#pragma unroll
        for (int i = 0; i < 4; ++i)
#pragma unroll
            for (int j = 0; j < 4; ++j) acc[i][j] += xc[i] * xd[j];
    }
#pragma unroll
    for (int i = 0; i < 4; ++i) {
        float4 o4 = {acc[i][0], acc[i][1], acc[i][2], acc[i][3]};
        *(float4*)(Gpart + ((nc * 4 + b) * 64 + c0 + i) * 64 + d0) = o4;
    }
}

// ---------------- channel softmax rows (unchanged)
__global__ void k_asm(const float* __restrict__ Gpart, float* __restrict__ A) {
    int row = blockIdx.x;      // b*64 + c
    int d = threadIdx.x;
    int b = row >> 6, c = row & 63;
    float g = 0.0f;
    for (int p = 0; p < 16; ++p) g += Gpart[(p * 4 + b) * 4096 + c * 64 + d];
    float mx = g;
    for (int off = 32; off >= 1; off >>= 1) mx = fmaxf(mx, __shfl_xor(mx, off, 64));
    float e = __expf(g - mx);
    float s = e;
    for (int off = 32; off >= 1; off >>= 1) s += __shfl_xor(s, off, 64);
    A[row * 64 + d] = e / s;
}

// ---------------- pass1: row sums l_i = sum_j exp(s_ij).
// grid 1024 = (itile 16 x jp 16 x b 4); block 256 (4 waves), wave = 64 i-rows.
// K tiles LDS-staged with cross-iteration register prefetch (latency hidden
// under the 96-MFMA compute window). launch_bounds (256,2): VGPR cap 128, NO spill.
__global__ __launch_bounds__(256, 2) void k_pass1(
        const unsigned short* __restrict__ qth, const unsigned short* __restrict__ qtl,
        const unsigned short* __restrict__ kth, const unsigned short* __restrict__ ktl,
        float* __restrict__ lpart) {
    int flat = blockIdx.x;                       // 0..1023
    int xcd = flat & 7, hi = flat >> 3;          // hi 0..127
    int b = xcd >> 1;
    int rem = (xcd & 1) * 128 + hi;              // 0..255
    int itile = rem & 15, jp = rem >> 4;         // itile 0..15, jp 0..15

    __shared__ unsigned short ksh[64 * 72];      // stride 72 shorts
    __shared__ unsigned short ksl[64 * 72];

    int tid = threadIdx.x;
    int lane = tid & 63, wv = tid >> 6;
    int l15 = lane & 15, g = lane >> 4;
    int iw = itile * 256 + wv * 64;              // wave strip base (64 rows)

    s8v qa[4][4];                                // [sub-strip][h0,l0,h1,l1]
#pragma unroll
    for (int ss = 0; ss < 4; ++ss) {
        int qb = (b * 4096 + iw + ss * 16 + l15) * 64 + g * 8;
        qa[ss][0] = *(const s8v*)(qth + qb);
        qa[ss][1] = *(const s8v*)(qtl + qb);
        qa[ss][2] = *(const s8v*)(qth + qb + 32);
        qa[ss][3] = *(const s8v*)(qtl + qb + 32);
    }

    float l[4][4];
#pragma unroll
    for (int ss = 0; ss < 4; ++ss)
#pragma unroll
        for (int r = 0; r < 4; ++r) l[ss][r] = 0.f;

    // staging segment addresses for this thread (2 segs per array)
    int s0r = tid >> 3, s0c = tid & 7;
    int s1r = (tid + 256) >> 3, s1c = (tid + 256) & 7;
    int ga0 = (b * 4096 + jp * 256 + s0r) * 64 + s0c * 8;
    int ga1 = (b * 4096 + jp * 256 + s1r) * 64 + s1c * 8;

    // prologue prefetch jt=0
    s8v kh0 = *(const s8v*)(kth + ga0);
    s8v kh1 = *(const s8v*)(kth + ga1);
    s8v kl0 = *(const s8v*)(ktl + ga0);
    s8v kl1 = *(const s8v*)(ktl + ga1);

    for (int jt = 0; jt < 4; ++jt) {
        __syncthreads();                 // prev compute done reading LDS
        *(s8v*)(ksh + s0r * 72 + s0c * 8) = kh0;
        *(s8v*)(ksh + s1r * 72 + s1c * 8) = kh1;
        *(s8v*)(ksl + s0r * 72 + s0c * 8) = kl0;
        *(s8v*)(ksl + s1r * 72 + s1c * 8) = kl1;
        __syncthreads();                 // LDS writes visible
        if (jt < 3) {                    // issue next-tile loads; hidden under compute
            int o = (jt + 1) * 64 * 64;
            kh0 = *(const s8v*)(kth + ga0 + o);
            kh1 = *(const s8v*)(kth + ga1 + o);
            kl0 = *(const s8v*)(ktl + ga0 + o);
            kl1 = *(const s8v*)(ktl + ga1 + o);
        }
#pragma unroll
        for (int js = 0; js < 4; ++js) {
            int ro = (js * 16 + l15) * 72 + g * 8;
            s8v bh0 = *(const s8v*)(ksh + ro);
            s8v bl0 = *(const s8v*)(ksl + ro);
            s8v bh1 = *(const s8v*)(ksh + ro + 32);
            s8v bl1 = *(const s8v*)(ksl + ro + 32);
#pragma unroll
            for (int ss = 0; ss < 4; ++ss) {
                f4v acc = {0.f, 0.f, 0.f, 0.f};
                acc = MFMA16(qa[ss][0], bh0, acc);
                acc = MFMA16(qa[ss][0], bl0, acc);
                acc = MFMA16(qa[ss][1], bh0, acc);
                acc = MFMA16(qa[ss][2], bh1, acc);
                acc = MFMA16(qa[ss][2], bl1, acc);
                acc = MFMA16(qa[ss][3], bh1, acc);
                l[ss][0] += __expf(acc[0]);
                l[ss][1] += __expf(acc[1]);
                l[ss][2] += __expf(acc[2]);
                l[ss][3] += __expf(acc[3]);
            }
        }
    }
#pragma unroll
    for (int ss = 0; ss < 4; ++ss)
#pragma unroll
        for (int r = 0; r < 4; ++r) {
            float s = l[ss][r];
            s += __shfl_xor(s, 1);
            s += __shfl_xor(s, 2);
            s += __shfl_xor(s, 4);
            s += __shfl_xor(s, 8);
            l[ss][r] = s;
        }
    if (l15 == 0) {
        int ib = (jp * 4 + b) * 4096 + iw + g * 4;
#pragma unroll
        for (int ss = 0; ss < 4; ++ss)
#pragma unroll
            for (int r = 0; r < 4; ++r)
                lpart[ib + ss * 16 + r] = l[ss][r];
    }
}

// ---------------- merge 16 j-partials -> 1/l
__global__ void k_merge(const float* __restrict__ lpart, float* __restrict__ invl) {
    int idx = blockIdx.x * 256 + threadIdx.x;
    float s = 0.0f;
#pragma unroll
    for (int p = 0; p < 16; ++p) s += lpart[p * 16384 + idx];
    invl[idx] = 1.0f / s;
}

// ---------------- fold invl into V: vbh <- bf16((vh+vl) * invl_n), hi-only
__global__ __launch_bounds__(256) void k_vnorm(
        unsigned short* __restrict__ vbh, const unsigned short* __restrict__ vbl,
        const float* __restrict__ invl) {
    int u = blockIdx.x * 256 + threadIdx.x;      // < 131072
    int cc = u & 15, n8 = (u >> 4) & 511, cb = (u >> 13) & 3, b = u >> 15;
    int base = (((b * 4 + cb) * 512 + n8) * 16 + cc) * 8;
    s8v vh = *(s8v*)(vbh + base);
    s8v vl = *(const s8v*)(vbl + base);
    float4 iv0 = *(const float4*)(invl + b * 4096 + n8 * 8);
    float4 iv1 = *(const float4*)(invl + b * 4096 + n8 * 8 + 4);
    float ivv[8] = {iv0.x, iv0.y, iv0.z, iv0.w, iv1.x, iv1.y, iv1.z, iv1.w};
    s8v o;
#pragma unroll
    for (int e = 0; e < 8; ++e) {
        float v = bf2f((unsigned short)vh[e]) + bf2f((unsigned short)vl[e]);
        o[e] = (short)bf16_rne(v * ivv[e]);
    }
    *(s8v*)(vbh + base) = o;
}

// ---------------- pass2: grid 512 (2 blocks/CU), block 512 (8 waves), j-tile 32.
// K (32 j) in regs; V' (hi-only, invl-folded) double-buffered via global_load_lds
// (issued one full QK-phase ahead); Q fragments register-prefetched one iteration
// ahead (issued after barrier B, hidden under PV + barrier). P hi-only bf16 [j][i].
__global__ __launch_bounds__(512, 4) void k_pass2(
        const unsigned short* __restrict__ qth, const unsigned short* __restrict__ qtl,
        const unsigned short* __restrict__ kth, const unsigned short* __restrict__ ktl,
        const unsigned short* __restrict__ vbh, float* __restrict__ pos) {
    int flat = blockIdx.x;                      // 0..511
    int xcd = flat & 7, slot = flat >> 3;       // slot 0..63
    int b = xcd >> 1;
    int jt = (xcd & 1) * 64 + slot;             // 0..127
    int j0 = jt * 32;

    int tid = threadIdx.x;
    int lane = tid & 63, wv = tid >> 6;
    int l15 = lane & 15, g = lane >> 4;

    __shared__ unsigned short Pt[32][136];      // [j][i 0..127]
    __shared__ unsigned short Vt[2][4][2048];   // [buf][cb][n8' 16][cc 16][e 8]

    s8v kf[2][4];                               // [js][{h0,l0,h1,l1}]
#pragma unroll
    for (int js = 0; js < 2; ++js) {
        int kb = (b * 4096 + j0 + js * 16 + l15) * 64 + g * 8;
        kf[js][0] = *(const s8v*)(kth + kb);
        kf[js][1] = *(const s8v*)(ktl + kb);
        kf[js][2] = *(const s8v*)(kth + kb + 32);
        kf[js][3] = *(const s8v*)(ktl + kb + 32);
    }

    int cq = wv & 3, jh = wv >> 2;
    f4v oacc = {0.f, 0.f, 0.f, 0.f};

    // stage 128-i chunk of V' for iteration `it` into Vt[buf].
    auto stageV = [&](int buf, int it) {
        int cb = wv & 3, h4 = wv >> 2;
        const unsigned short* sp = vbh + (((b * 4 + cb) * 512 + it * 16) * 128) + h4 * 1024;
        unsigned short* dp = &Vt[buf][cb][h4 * 1024];
        gl_lds16(sp + lane * 8, dp);
        gl_lds16(sp + 512 + lane * 8, dp + 512);
    };

    int qbase = (b * 4096 + wv * 16 + l15) * 64 + g * 8;   // advances by 128*64 per it
    stageV(0, 0);
    // prologue Q(0)
    s8v qa0 = *(const s8v*)(qth + qbase);
    s8v ql0 = *(const s8v*)(qtl + qbase);
    s8v qa1 = *(const s8v*)(qth + qbase + 32);
    s8v ql1 = *(const s8v*)(qtl + qbase + 32);

    for (int it = 0; it < 32; ++it) {
        int buf = it & 1;
        __syncthreads();                 // barrier A: prev PV done; Q(it) drained
        if (it < 31) stageV(buf ^ 1, it + 1);

        // ---- QK phase: wave = 16-row i-strip of the 128-chunk
#pragma unroll
        for (int js = 0; js < 2; ++js) {
            f4v acc = {0.f, 0.f, 0.f, 0.f};
            acc = MFMA16(qa0, kf[js][0], acc);
            acc = MFMA16(qa0, kf[js][1], acc);
            acc = MFMA16(ql0, kf[js][0], acc);
            acc = MFMA16(qa1, kf[js][2], acc);
            acc = MFMA16(qa1, kf[js][3], acc);
            acc = MFMA16(ql1, kf[js][2], acc);
            unsigned short pw[4];
#pragma unroll
            for (int r = 0; r < 4; ++r) pw[r] = bf16_rne(__expf(acc[r]));
            uint2 pk;
            pk.x = pw[0] | ((unsigned int)pw[1] << 16);
            pk.y = pw[2] | ((unsigned int)pw[3] << 16);
            *(uint2*)&Pt[js * 16 + l15][wv * 16 + g * 4] = pk;
        }
        __syncthreads();                 // barrier B: Pt ready; Vt[buf] drained

        // prefetch Q(it+1): issued now, drains at barrier A of it+1 (PV window)
        s8v nqa0, nql0, nqa1, nql1;
        if (it < 31) {
            int nqb = qbase + (it + 1) * 128 * 64;
            nqa0 = *(const s8v*)(qth + nqb);
            nql0 = *(const s8v*)(qtl + nqb);
            nqa1 = *(const s8v*)(qth + nqb + 32);
            nql1 = *(const s8v*)(qtl + nqb + 32);
        }

        // ---- PV phase: wave = (cq: 16 c) x (jh: 16 j); 4 k-steps of 32 i
#pragma unroll
        for (int ks = 0; ks < 4; ++ks) {
            s8v ah = *(const s8v*)&Vt[buf][cq][((ks * 4 + g) * 16 + l15) * 8];
            s8v p = *(const s8v*)&Pt[jh * 16 + l15][ks * 32 + g * 8];
            oacc = MFMA16(ah, p, oacc);
        }
        qa0 = nqa0; ql0 = nql0; qa1 = nqa1; ql1 = nql1;
    }

    int cb2 = b * 64 + cq * 16 + g * 4;
    int jb = j0 + jh * 16 + l15;
#pragma unroll
    for (int r = 0; r < 4; ++r)
        pos[(cb2 + r) * 4096 + jb] = oacc[r];
}

// ---------------- final: out = pg*pos + cg*(A@x) + 2*x, LDS-staged x tile
__global__ __launch_bounds__(256) void k_final(
        const float* __restrict__ x, const float* __restrict__ pos,
        const float* __restrict__ A, const float* __restrict__ pg,
        const float* __restrict__ cg, float* __restrict__ out) {
    int n0 = blockIdx.x * 256, cg8 = blockIdx.y, b = blockIdx.z;
    __shared__ float xs[64 * 256];
    int tid = threadIdx.x;
    for (int it = 0; it < 16; ++it) {
        int idx = tid + it * 256;           // float4 index
        int d = idx >> 6, n4 = idx & 63;
        *(float4*)(xs + d * 256 + n4 * 4) =
            *(const float4*)(x + (b * 64 + d) * 4096 + n0 + n4 * 4);
    }
    __syncthreads();
    float pgv = pg[0], cgv = cg[0];
    int cbase = cg8 * 8;
#pragma unroll
    for (int c8 = 0; c8 < 8; ++c8) {
        int c = cbase + c8;
        const float* Ar = A + (b * 64 + c) * 64;
        float acc = 0.0f;
#pragma unroll
        for (int d = 0; d < 64; ++d) acc += Ar[d] * xs[d * 256 + tid];
        float xc = xs[c * 256 + tid];
        float p = pos[(b * 64 + c) * 4096 + n0 + tid];
        out[(b * 64 + c) * 4096 + n0 + tid] = pgv * p + cgv * acc + 2.0f * xc;
    }
}

extern "C" void kernel_launch(void* const* d_in, const int* in_sizes, int n_in,
                              void* d_out, int out_size, void* d_ws, size_t ws_size,
                              hipStream_t stream) {
    const float* x  = (const float*)d_in[0];
    const float* wq = (const float*)d_in[1];
    const float* bq = (const float*)d_in[2];
    const float* wk = (const float*)d_in[3];
    const float* bk = (const float*)d_in[4];
    const float* wv = (const float*)d_in[5];
    const float* bv = (const float*)d_in[6];
    const float* pg = (const float*)d_in[7];
    const float* cg = (const float*)d_in[8];
    float* out = (float*)d_out;

    if (ws_size < (size_t)WS_FLOATS * sizeof(float)) return;
    float* ws = (float*)d_ws;
    float* pos  = ws + OFF_POS;
    unsigned short* qth = (unsigned short*)(ws + OFF_QTH);
    unsigned short* qtl = (unsigned short*)(ws + OFF_QTL);
    unsigned short* kth = (unsigned short*)(ws + OFF_KTH);
    unsigned short* ktl = (unsigned short*)(ws + OFF_KTL);
    unsigned short* vbh = (unsigned short*)(ws + OFF_VBH);
    unsigned short* vbl = (unsigned short*)(ws + OFF_VBL);
    float* wt   = ws + OFF_WT;
    float* invl = ws + OFF_INVL;
    float* Gp   = ws + OFF_GPART;    // Gram partials, then reused as lpart
    float* A    = ws + OFF_A;

    k_wtrans<<<432, 256, 0, stream>>>(wq, wk, wv, wt);
    k_conv<<<dim3(64, 4, 3), 256, 0, stream>>>(x, wt, bq, bk, bv, qth, qtl, kth, ktl, vbh, vbl);
    k_gram<<<dim3(16, 4), 256, 0, stream>>>(x, Gp);
    k_asm<<<256, 64, 0, stream>>>(Gp, A);
    // Gp region now free -> lpart (16*4*4096 floats, exact fit)
    k_pass1<<<1024, 256, 0, stream>>>(qth, qtl, kth, ktl, Gp);
    k_merge<<<64, 256, 0, stream>>>(Gp, invl);
    k_vnorm<<<512, 256, 0, stream>>>(vbh, vbl, invl);
    k_pass2<<<512, 512, 0, stream>>>(qth, qtl, kth, ktl, vbh, pos);
    k_final<<<dim3(16, 8, 4), 256, 0, stream>>>(x, pos, A, pg, cg, out);
}

// Round 7
// 185.834 us; speedup vs baseline: 1.3733x; 1.2373x over previous
//
#include <hip/hip_runtime.h>

// Problem constants: B=4, C=64, H=W=64, N=4096
// Workspace layout (float offsets) — 4,747,264 floats (same proven footprint).
// Q2: fragment-blocked Q (hi/lo), 1,048,576 floats (4 MB) spanning old qth+qtl
// K2: same for K; V2: frag-blocked V hi (2 MB); VLO: V lo (2 MB)
#define OFF_POS   0u
#define OFF_Q2    1048576u
#define OFF_K2    2097152u
#define OFF_V2    3145728u
#define OFF_VLO   3670016u
#define OFF_WT    4194304u
#define OFF_INVL  4452352u
#define OFF_GPART 4468736u
#define OFF_A     4730880u
#define WS_FLOATS 4747264u

typedef short s8v __attribute__((ext_vector_type(8)));
typedef float f4v __attribute__((ext_vector_type(4)));
typedef float f16v __attribute__((ext_vector_type(16)));

#define MFMA32(a, b, c) __builtin_amdgcn_mfma_f32_32x32x16_bf16((a), (b), (c), 0, 0, 0)

__device__ __forceinline__ unsigned short bf16_rne(float f) {
    union { float f; unsigned int u; } v; v.f = f;
    unsigned int r = v.u + 0x7FFFu + ((v.u >> 16) & 1u);
    return (unsigned short)(r >> 16);
}
__device__ __forceinline__ float bf2f(unsigned short h) {
    union { unsigned int u; float f; } t; t.u = ((unsigned int)h) << 16;
    return t.f;
}
__device__ __forceinline__ void split2(float f, unsigned short& h, unsigned short& l) {
    unsigned short hh = bf16_rne(f);
    h = hh;
    l = bf16_rne(f - bf2f(hh));
}
__device__ __forceinline__ unsigned int pk2(float lo, float hi) {
    return (unsigned int)bf16_rne(lo) | ((unsigned int)bf16_rne(hi) << 16);
}
// v_permlane32_swap_b32: a.high32lanes <-> b.low32lanes (both regs updated)
__device__ __forceinline__ void pl32swap(unsigned int& a, unsigned int& b) {
    asm volatile("v_permlane32_swap_b32 %0, %1" : "+v"(a), "+v"(b));
}
__device__ __forceinline__ s8v mk8(unsigned int w0, unsigned int w1,
                                   unsigned int w2, unsigned int w3) {
    union { unsigned int u[4]; s8v v; } t;
    t.u[0] = w0; t.u[1] = w1; t.u[2] = w2; t.u[3] = w3;
    return t.v;
}
__device__ __forceinline__ f16v zero16() {
    f16v z;
#pragma unroll
    for (int i = 0; i < 16; ++i) z[i] = 0.0f;
    return z;
}

// Fragment layouts (all 32x32x16-ready, one layout serves A and B roles):
//  Q2/K2: idx = (((b*128 + nch)*4 + kst)*2 + hl)*512 + lane*8 + e
//         holds X[n = nch*32 + (lane&31)][c = kst*16 + (lane>>5)*8 + e]
//  V2:    idx = (((b*128 + ich)*2 + ksub)*2 + cb)*512 + lane*8 + e
//         holds V[c = cb*32 + (lane&31)][n = ich*32 + ksub*16 + (lane>>5)*8 + e]

// ---------------- weight transpose: w[o][ci][3][3] -> wt[conv][ci*9+tap][o]
__global__ void k_wtrans(const float* __restrict__ wq, const float* __restrict__ wk,
                         const float* __restrict__ wv, float* __restrict__ wt) {
    int idx = blockIdx.x * 256 + threadIdx.x;     // < 3*36864
    int conv = idx / 36864;
    int r = idx % 36864;
    int o = r & 63;
    int t2 = r >> 6;            // ci*9+tap
    int ci = t2 / 9, tap = t2 % 9;
    const float* w = (conv == 0) ? wq : (conv == 1) ? wk : wv;
    wt[idx] = w[(o * 64 + ci) * 9 + tap];
}

// ---------------- fused 3x3 conv (SAME) writing fragment-blocked split-bf16
__global__ __launch_bounds__(256) void k_conv(
        const float* __restrict__ x, const float* __restrict__ wt,
        const float* __restrict__ bq, const float* __restrict__ bk, const float* __restrict__ bv,
        unsigned short* __restrict__ Q2, unsigned short* __restrict__ K2,
        unsigned short* __restrict__ V2, unsigned short* __restrict__ VLO) {
    int h = blockIdx.x, b = blockIdx.y, conv = blockIdx.z;
    const float* bias = (conv == 0) ? bq : (conv == 1) ? bk : bv;
    const float* wtc = wt + conv * 36864;

    __shared__ float xch[16 * 3 * 66];   // [cil][dy][col], col 0 & 65 zero pad
    __shared__ float wch[16 * 9 * 64];   // [cil][tap][o]

    int tid = threadIdx.x;
    int wtd = tid & 15, ot = tid >> 4;
    int w0 = wtd * 4, o0 = ot * 4;

    float acc[4][4];
    {
        float4 b4 = *(const float4*)(bias + o0);
        float bb[4] = {b4.x, b4.y, b4.z, b4.w};
#pragma unroll
        for (int oo = 0; oo < 4; ++oo)
#pragma unroll
            for (int ww = 0; ww < 4; ++ww) acc[oo][ww] = bb[oo];
    }

    for (int ck = 0; ck < 4; ++ck) {
        __syncthreads();
        for (int idx = tid; idx < 3168; idx += 256) {
            int col = idx % 66;
            int row = idx / 66;
            int dy = row % 3, cil = row / 3;
            int ci = ck * 16 + cil;
            int hs = h + dy - 1;
            float val = 0.0f;
            if (col >= 1 && col <= 64 && hs >= 0 && hs < 64)
                val = x[((b * 64 + ci) * 64 + hs) * 64 + (col - 1)];
            xch[(cil * 3 + dy) * 66 + col] = val;
        }
        for (int idx = tid; idx < 2304; idx += 256)
            ((float4*)wch)[idx] = ((const float4*)(wtc + ck * 9216))[idx];
        __syncthreads();

        for (int cil = 0; cil < 16; ++cil) {
#pragma unroll
            for (int dy = 0; dy < 3; ++dy) {
                float xv[6];
#pragma unroll
                for (int s = 0; s < 6; ++s) xv[s] = xch[(cil * 3 + dy) * 66 + w0 + s];
#pragma unroll
                for (int dx = 0; dx < 3; ++dx) {
                    float4 w4 = ((const float4*)wch)[(cil * 9 + dy * 3 + dx) * 16 + ot];
                    float wa[4] = {w4.x, w4.y, w4.z, w4.w};
#pragma unroll
                    for (int oo = 0; oo < 4; ++oo)
#pragma unroll
                        for (int ww = 0; ww < 4; ++ww)
                            acc[oo][ww] += xv[ww + dx] * wa[oo];
                }
            }
        }
    }

    if (conv < 2) {
        unsigned short* dst = (conv == 0) ? Q2 : K2;
        int kst = o0 >> 4, hb = (o0 >> 3) & 1, e0 = o0 & 7;
#pragma unroll
        for (int ww = 0; ww < 4; ++ww) {
            int n = h * 64 + w0 + ww;
            int i5 = n & 31, nch = n >> 5;
            unsigned short h4[4], l4[4];
#pragma unroll
            for (int oo = 0; oo < 4; ++oo) split2(acc[oo][ww], h4[oo], l4[oo]);
            size_t baseh = (size_t)(((b * 128 + nch) * 4 + kst) * 2 + 0) * 512 + (hb * 32 + i5) * 8 + e0;
            size_t basel = (size_t)(((b * 128 + nch) * 4 + kst) * 2 + 1) * 512 + (hb * 32 + i5) * 8 + e0;
            uint2 hv, lv;
            hv.x = h4[0] | ((unsigned int)h4[1] << 16);
            hv.y = h4[2] | ((unsigned int)h4[3] << 16);
            lv.x = l4[0] | ((unsigned int)l4[1] << 16);
            lv.y = l4[2] | ((unsigned int)l4[3] << 16);
            *(uint2*)(dst + baseh) = hv;
            *(uint2*)(dst + basel) = lv;
        }
    } else {
        // V: pack over ww (4 consecutive n -> consecutive e)
        int ich = (h * 64 + w0) >> 5;
        int ksub = (w0 >> 4) & 1, hb2 = (w0 >> 3) & 1, e0 = w0 & 7;
#pragma unroll
        for (int oo = 0; oo < 4; ++oo) {
            int c = o0 + oo;
            int cb = c >> 5, cl = c & 31;
            unsigned short h4[4], l4[4];
#pragma unroll
            for (int ww = 0; ww < 4; ++ww) split2(acc[oo][ww], h4[ww], l4[ww]);
            size_t base = (size_t)(((b * 128 + ich) * 2 + ksub) * 2 + cb) * 512 + (hb2 * 32 + cl) * 8 + e0;
            uint2 hv, lv;
            hv.x = h4[0] | ((unsigned int)h4[1] << 16);
            hv.y = h4[2] | ((unsigned int)h4[3] << 16);
            lv.x = l4[0] | ((unsigned int)l4[1] << 16);
            lv.y = l4[2] | ((unsigned int)l4[3] << 16);
            *(uint2*)(V2 + base) = hv;
            *(uint2*)(VLO + base) = lv;
        }
    }
}

// ---------------- channel Gram partials (unchanged)
__global__ __launch_bounds__(256) void k_gram(const float* __restrict__ x, float* __restrict__ Gpart) {
    int nc = blockIdx.x, b = blockIdx.y;
    __shared__ float xs[64 * 257];
    int tid = threadIdx.x;
    for (int it = 0; it < 16; ++it) {
        int f4i = tid + it * 256;
        int c = f4i >> 6, n4 = f4i & 63;
        float4 vv = *(const float4*)(x + (b * 64 + c) * 4096 + nc * 256 + n4 * 4);
        xs[c * 257 + n4 * 4 + 0] = vv.x;
        xs[c * 257 + n4 * 4 + 1] = vv.y;
        xs[c * 257 + n4 * 4 + 2] = vv.z;
        xs[c * 257 + n4 * 4 + 3] = vv.w;
    }
    __syncthreads();
    int tc = tid & 15, td = tid >> 4;
    int c0 = tc * 4, d0 = td * 4;
    float acc[4][4];
#pragma unroll
    for (int i = 0; i < 4; ++i)
#pragma unroll
        for (int j = 0; j < 4; ++j) acc[i][j] = 0.0f;
    for (int n = 0; n < 256; ++n) {
        float xc[4], xd[4];
#pragma unroll
        for (int i = 0; i < 4; ++i) xc[i] = xs[(c0 + i) * 257 + n];
#pragma unroll
        for (int j = 0; j < 4; ++j) xd[j] = xs[(d0 + j) * 257 + n];
#pragma unroll
        for (int i = 0; i < 4; ++i)
#pragma unroll
            for (int j = 0; j < 4; ++j) acc[i][j] += xc[i] * xd[j];
    }
#pragma unroll
    for (int i = 0; i < 4; ++i) {
        float4 o4 = {acc[i][0], acc[i][1], acc[i][2], acc[i][3]};
        *(float4*)(Gpart + ((nc * 4 + b) * 64 + c0 + i) * 64 + d0) = o4;
    }
}

// ---------------- channel softmax rows (unchanged)
__global__ void k_asm(const float* __restrict__ Gpart, float* __restrict__ A) {
    int row = blockIdx.x;      // b*64 + c
    int d = threadIdx.x;
    int b = row >> 6, c = row & 63;
    float g = 0.0f;
    for (int p = 0; p < 16; ++p) g += Gpart[(p * 4 + b) * 4096 + c * 64 + d];
    float mx = g;
    for (int off = 32; off >= 1; off >>= 1) mx = fmaxf(mx, __shfl_xor(mx, off, 64));
    float e = __expf(g - mx);
    float s = e;
    for (int off = 32; off >= 1; off >>= 1) s += __shfl_xor(s, off, 64);
    A[row * 64 + d] = e / s;
}

// ---------------- pass1: invl_i = 1 / sum_j exp(s_ij). S^T = mfma32(K, Q).
// grid 256, block 512 (8 waves = 2 i-chunks x 4 j-parts). No staging LDS,
// no in-loop barriers; fragment loads coalesced (1 KB/instr) from L2.
__global__ __launch_bounds__(512) void k_pass1(
        const unsigned short* __restrict__ Q2, const unsigned short* __restrict__ K2,
        float* __restrict__ invl) {
    int flat = blockIdx.x;
    int xcd = flat & 7;
    int b = xcd >> 1;
    int pr = (xcd & 1) * 32 + (flat >> 3);   // ich-pair 0..63
    int tid = threadIdx.x, lane = tid & 63, wv = tid >> 6;
    int jp = wv & 3, ichL = wv >> 2;
    int ich = pr * 2 + ichL;

    __shared__ float lsum[2][4][32];

    const unsigned short* qp = Q2 + (size_t)(b * 128 + ich) * 4096 + lane * 8;
    s8v qf0 = *(const s8v*)(qp);
    s8v qf1 = *(const s8v*)(qp + 512);
    s8v qf2 = *(const s8v*)(qp + 1024);
    s8v qf3 = *(const s8v*)(qp + 1536);
    s8v qf4 = *(const s8v*)(qp + 2048);
    s8v qf5 = *(const s8v*)(qp + 2560);
    s8v qf6 = *(const s8v*)(qp + 3072);
    s8v qf7 = *(const s8v*)(qp + 3584);

    float la0 = 0.f, la1 = 0.f;
#pragma unroll 1
    for (int t = 0; t < 32; ++t) {
        int jch = jp * 32 + t;
        const unsigned short* kp = K2 + (size_t)(b * 128 + jch) * 4096 + lane * 8;
        s8v kf0 = *(const s8v*)(kp);
        s8v kf1 = *(const s8v*)(kp + 512);
        s8v kf2 = *(const s8v*)(kp + 1024);
        s8v kf3 = *(const s8v*)(kp + 1536);
        s8v kf4 = *(const s8v*)(kp + 2048);
        s8v kf5 = *(const s8v*)(kp + 2560);
        s8v kf6 = *(const s8v*)(kp + 3072);
        s8v kf7 = *(const s8v*)(kp + 3584);
        f16v Sa = zero16(), Sb = zero16();
        Sa = MFMA32(kf0, qf0, Sa);
        Sa = MFMA32(kf0, qf1, Sa);
        Sa = MFMA32(kf1, qf0, Sa);
        Sa = MFMA32(kf2, qf2, Sa);
        Sa = MFMA32(kf2, qf3, Sa);
        Sa = MFMA32(kf3, qf2, Sa);
        Sb = MFMA32(kf4, qf4, Sb);
        Sb = MFMA32(kf4, qf5, Sb);
        Sb = MFMA32(kf5, qf4, Sb);
        Sb = MFMA32(kf6, qf6, Sb);
        Sb = MFMA32(kf6, qf7, Sb);
        Sb = MFMA32(kf7, qf6, Sb);
#pragma unroll
        for (int r = 0; r < 8; ++r) la0 += __expf(Sa[r] + Sb[r]);
#pragma unroll
        for (int r = 8; r < 16; ++r) la1 += __expf(Sa[r] + Sb[r]);
    }
    float lacc = la0 + la1;
    lacc += __shfl_xor(lacc, 32);
    if (lane < 32) lsum[ichL][jp][lane] = lacc;
    __syncthreads();
    if (tid < 64) {
        int iL = tid & 31, iH = tid >> 5;
        float s = lsum[iH][0][iL] + lsum[iH][1][iL] + lsum[iH][2][iL] + lsum[iH][3][iL];
        invl[b * 4096 + (pr * 2 + iH) * 32 + iL] = 1.0f / s;
    }
}

// ---------------- fold invl into V (hi-only), in V2 fragment layout, in place
__global__ __launch_bounds__(256) void k_vnorm(
        unsigned short* __restrict__ V2, const unsigned short* __restrict__ VLO,
        const float* __restrict__ invl) {
    int u = blockIdx.x * 256 + threadIdx.x;      // < 131072 16B-segs
    int lane = u & 63, cb = (u >> 6) & 1, ksub = (u >> 7) & 1;
    int ich = (u >> 8) & 127, b = u >> 15;
    (void)cb;
    int n0 = ich * 32 + ksub * 16 + (lane >> 5) * 8;
    size_t base = (size_t)u * 8;
    s8v vh = *(s8v*)(V2 + base);
    s8v vl = *(const s8v*)(VLO + base);
    float4 iv0 = *(const float4*)(invl + b * 4096 + n0);
    float4 iv1 = *(const float4*)(invl + b * 4096 + n0 + 4);
    float ivv[8] = {iv0.x, iv0.y, iv0.z, iv0.w, iv1.x, iv1.y, iv1.z, iv1.w};
    s8v o;
#pragma unroll
    for (int e = 0; e < 8; ++e) {
        float v = bf2f((unsigned short)vh[e]) + bf2f((unsigned short)vl[e]);
        o[e] = (short)bf16_rne(v * ivv[e]);
    }
    *(s8v*)(V2 + base) = o;
}

// ---------------- pass2: barrier-free flash loop, in-register P via permlane.
// grid 256, block 512 (8 waves = 2 j-tiles x 4 i-parts). Per wave per chunk:
// 12 QK mfma32 -> 16 exp -> 8 pack + 4 permlane32_swap -> 4 PV mfma32.
// One barrier total (epilogue i-part reduction in LDS).
__global__ __launch_bounds__(512) void k_pass2(
        const unsigned short* __restrict__ Q2, const unsigned short* __restrict__ K2,
        const unsigned short* __restrict__ V2, float* __restrict__ pos) {
    int flat = blockIdx.x;
    int xcd = flat & 7;
    int b = xcd >> 1;
    int pr = (xcd & 1) * 32 + (flat >> 3);   // jt-pair 0..63
    int tid = threadIdx.x, lane = tid & 63, wv = tid >> 6;
    int ip = wv & 3, jhalf = wv >> 2;
    int jt = pr * 2 + jhalf;

    __shared__ float rlds[2][4][64][32];     // [jhalf][ipart][c][j]

    const unsigned short* kp = K2 + (size_t)(b * 128 + jt) * 4096 + lane * 8;
    s8v kf0 = *(const s8v*)(kp);
    s8v kf1 = *(const s8v*)(kp + 512);
    s8v kf2 = *(const s8v*)(kp + 1024);
    s8v kf3 = *(const s8v*)(kp + 1536);
    s8v kf4 = *(const s8v*)(kp + 2048);
    s8v kf5 = *(const s8v*)(kp + 2560);
    s8v kf6 = *(const s8v*)(kp + 3072);
    s8v kf7 = *(const s8v*)(kp + 3584);

    f16v O0 = zero16(), O1 = zero16();

#pragma unroll 1
    for (int t = 0; t < 32; ++t) {
        int ich = ip * 32 + t;
        const unsigned short* qp = Q2 + (size_t)(b * 128 + ich) * 4096 + lane * 8;
        s8v qf0 = *(const s8v*)(qp);
        s8v qf1 = *(const s8v*)(qp + 512);
        s8v qf2 = *(const s8v*)(qp + 1024);
        s8v qf3 = *(const s8v*)(qp + 1536);
        s8v qf4 = *(const s8v*)(qp + 2048);
        s8v qf5 = *(const s8v*)(qp + 2560);
        s8v qf6 = *(const s8v*)(qp + 3072);
        s8v qf7 = *(const s8v*)(qp + 3584);
        const unsigned short* vp = V2 + (size_t)(b * 128 + ich) * 2048 + lane * 8;
        s8v vA = *(const s8v*)(vp);           // ksub0, cb0
        s8v vB = *(const s8v*)(vp + 512);     // ksub0, cb1
        s8v vC = *(const s8v*)(vp + 1024);    // ksub1, cb0
        s8v vD = *(const s8v*)(vp + 1536);    // ksub1, cb1

        f16v Sa = zero16(), Sb = zero16();
        Sa = MFMA32(qf0, kf0, Sa);
        Sa = MFMA32(qf0, kf1, Sa);
        Sa = MFMA32(qf1, kf0, Sa);
        Sa = MFMA32(qf2, kf2, Sa);
        Sa = MFMA32(qf2, kf3, Sa);
        Sa = MFMA32(qf3, kf2, Sa);
        Sb = MFMA32(qf4, kf4, Sb);
        Sb = MFMA32(qf4, kf5, Sb);
        Sb = MFMA32(qf5, kf4, Sb);
        Sb = MFMA32(qf6, kf6, Sb);
        Sb = MFMA32(qf6, kf7, Sb);
        Sb = MFMA32(qf7, kf6, Sb);

        float p[16];
#pragma unroll
        for (int r = 0; r < 16; ++r) p[r] = __expf(Sa[r] + Sb[r]);

        unsigned int a0 = pk2(p[0], p[1]),  a1 = pk2(p[2], p[3]);
        unsigned int a2 = pk2(p[4], p[5]),  a3 = pk2(p[6], p[7]);
        pl32swap(a0, a2);
        pl32swap(a1, a3);
        s8v P0 = mk8(a0, a1, a2, a3);
        unsigned int b0 = pk2(p[8], p[9]),  b1 = pk2(p[10], p[11]);
        unsigned int b2 = pk2(p[12], p[13]), b3 = pk2(p[14], p[15]);
        pl32swap(b0, b2);
        pl32swap(b1, b3);
        s8v P1 = mk8(b0, b1, b2, b3);

        O0 = MFMA32(vA, P0, O0);
        O0 = MFMA32(vC, P1, O0);
        O1 = MFMA32(vB, P0, O1);
        O1 = MFMA32(vD, P1, O1);
    }

    int hh = lane >> 5, jj = lane & 31;
#pragma unroll
    for (int r = 0; r < 16; ++r) {
        int c = (r & 3) + 8 * (r >> 2) + 4 * hh;
        rlds[jhalf][ip][c][jj] = O0[r];
        rlds[jhalf][ip][c + 32][jj] = O1[r];
    }
    __syncthreads();
#pragma unroll
    for (int k = 0; k < 8; ++k) {
        int e = tid + k * 512;
        int jh = e >> 11, rem = e & 2047, c = rem >> 5, j2 = rem & 31;
        float s = rlds[jh][0][c][j2] + rlds[jh][1][c][j2]
                + rlds[jh][2][c][j2] + rlds[jh][3][c][j2];
        pos[(size_t)(b * 64 + c) * 4096 + (pr * 2 + jh) * 32 + j2] = s;
    }
}

// ---------------- final: out = pg*pos + cg*(A@x) + 2*x, LDS-staged x tile
__global__ __launch_bounds__(256) void k_final(
        const float* __restrict__ x, const float* __restrict__ pos,
        const float* __restrict__ A, const float* __restrict__ pg,
        const float* __restrict__ cg, float* __restrict__ out) {
    int n0 = blockIdx.x * 256, cg8 = blockIdx.y, b = blockIdx.z;
    __shared__ float xs[64 * 256];
    int tid = threadIdx.x;
    for (int it = 0; it < 16; ++it) {
        int idx = tid + it * 256;           // float4 index
        int d = idx >> 6, n4 = idx & 63;
        *(float4*)(xs + d * 256 + n4 * 4) =
            *(const float4*)(x + (b * 64 + d) * 4096 + n0 + n4 * 4);
    }
    __syncthreads();
    float pgv = pg[0], cgv = cg[0];
    int cbase = cg8 * 8;
#pragma unroll
    for (int c8 = 0; c8 < 8; ++c8) {
        int c = cbase + c8;
        const float* Ar = A + (b * 64 + c) * 64;
        float acc = 0.0f;
#pragma unroll
        for (int d = 0; d < 64; ++d) acc += Ar[d] * xs[d * 256 + tid];
        float xc = xs[c * 256 + tid];
        float p = pos[(b * 64 + c) * 4096 + n0 + tid];
        out[(b * 64 + c) * 4096 + n0 + tid] = pgv * p + cgv * acc + 2.0f * xc;
    }
}

extern "C" void kernel_launch(void* const* d_in, const int* in_sizes, int n_in,
                              void* d_out, int out_size, void* d_ws, size_t ws_size,
                              hipStream_t stream) {
    const float* x  = (const float*)d_in[0];
    const float* wq = (const float*)d_in[1];
    const float* bq = (const float*)d_in[2];
    const float* wk = (const float*)d_in[3];
    const float* bk = (const float*)d_in[4];
    const float* wv = (const float*)d_in[5];
    const float* bv = (const float*)d_in[6];
    const float* pg = (const float*)d_in[7];
    const float* cg = (const float*)d_in[8];
    float* out = (float*)d_out;

    if (ws_size < (size_t)WS_FLOATS * sizeof(float)) return;
    float* ws = (float*)d_ws;
    float* pos  = ws + OFF_POS;
    unsigned short* Q2  = (unsigned short*)(ws + OFF_Q2);
    unsigned short* K2  = (unsigned short*)(ws + OFF_K2);
    unsigned short* V2  = (unsigned short*)(ws + OFF_V2);
    unsigned short* VLO = (unsigned short*)(ws + OFF_VLO);
    float* wt   = ws + OFF_WT;
    float* invl = ws + OFF_INVL;
    float* Gp   = ws + OFF_GPART;
    float* A    = ws + OFF_A;

    k_wtrans<<<432, 256, 0, stream>>>(wq, wk, wv, wt);
    k_conv<<<dim3(64, 4, 3), 256, 0, stream>>>(x, wt, bq, bk, bv, Q2, K2, V2, VLO);
    k_gram<<<dim3(16, 4), 256, 0, stream>>>(x, Gp);
    k_asm<<<256, 64, 0, stream>>>(Gp, A);
    k_pass1<<<256, 512, 0, stream>>>(Q2, K2, invl);
    k_vnorm<<<512, 256, 0, stream>>>(V2, VLO, invl);
    k_pass2<<<256, 512, 0, stream>>>(Q2, K2, V2, pos);
    k_final<<<dim3(16, 8, 4), 256, 0, stream>>>(x, pos, A, pg, cg, out);
}

// Round 8
// 173.323 us; speedup vs baseline: 1.4724x; 1.0722x over previous
//
#include <hip/hip_runtime.h>

// Problem constants: B=4, C=64, H=W=64, N=4096
// Workspace layout (float offsets) — 4,747,264 floats (same proven footprint).
// OFF_POS region reused as 64-chunk Gram partials (64*4*4096 = 1,048,576 exact);
// pos is never materialized (final fused into pass2).
#define OFF_POS   0u
#define OFF_Q2    1048576u
#define OFF_K2    2097152u
#define OFF_V2    3145728u
#define OFF_VLO   3670016u
#define OFF_WT    4194304u
#define OFF_INVL  4452352u
#define OFF_GPART 4468736u
#define OFF_A     4730880u
#define WS_FLOATS 4747264u

typedef short s8v __attribute__((ext_vector_type(8)));
typedef float f4v __attribute__((ext_vector_type(4)));
typedef float f16v __attribute__((ext_vector_type(16)));

#define MFMA32(a, b, c) __builtin_amdgcn_mfma_f32_32x32x16_bf16((a), (b), (c), 0, 0, 0)

__device__ __forceinline__ unsigned short bf16_rne(float f) {
    union { float f; unsigned int u; } v; v.f = f;
    unsigned int r = v.u + 0x7FFFu + ((v.u >> 16) & 1u);
    return (unsigned short)(r >> 16);
}
__device__ __forceinline__ float bf2f(unsigned short h) {
    union { unsigned int u; float f; } t; t.u = ((unsigned int)h) << 16;
    return t.f;
}
__device__ __forceinline__ void split2(float f, unsigned short& h, unsigned short& l) {
    unsigned short hh = bf16_rne(f);
    h = hh;
    l = bf16_rne(f - bf2f(hh));
}
__device__ __forceinline__ unsigned int pk2(float lo, float hi) {
    return (unsigned int)bf16_rne(lo) | ((unsigned int)bf16_rne(hi) << 16);
}
// v_permlane32_swap_b32: a.high32lanes <-> b.low32lanes (both regs updated)
__device__ __forceinline__ void pl32swap(unsigned int& a, unsigned int& b) {
    asm volatile("v_permlane32_swap_b32 %0, %1" : "+v"(a), "+v"(b));
}
__device__ __forceinline__ s8v mk8(unsigned int w0, unsigned int w1,
                                   unsigned int w2, unsigned int w3) {
    union { unsigned int u[4]; s8v v; } t;
    t.u[0] = w0; t.u[1] = w1; t.u[2] = w2; t.u[3] = w3;
    return t.v;
}
__device__ __forceinline__ f16v zero16() {
    f16v z;
#pragma unroll
    for (int i = 0; i < 16; ++i) z[i] = 0.0f;
    return z;
}

// Fragment layouts (32x32x16-ready):
//  Q2/K2: idx = (((b*128 + nch)*4 + kst)*2 + hl)*512 + lane*8 + e
//         holds X[n = nch*32 + (lane&31)][c = kst*16 + (lane>>5)*8 + e]
//  V2:    idx = (((b*128 + ich)*2 + ksub)*2 + cb)*512 + lane*8 + e
//         holds V[c = cb*32 + (lane&31)][n = ich*32 + ksub*16 + (lane>>5)*8 + e]

// ---------------- weight transpose: w[o][ci][3][3] -> wt[conv][ci*9+tap][o]
__global__ void k_wtrans(const float* __restrict__ wq, const float* __restrict__ wk,
                         const float* __restrict__ wv, float* __restrict__ wt) {
    int idx = blockIdx.x * 256 + threadIdx.x;     // < 3*36864
    int conv = idx / 36864;
    int r = idx % 36864;
    int o = r & 63;
    int t2 = r >> 6;            // ci*9+tap
    int ci = t2 / 9, tap = t2 % 9;
    const float* w = (conv == 0) ? wq : (conv == 1) ? wk : wv;
    wt[idx] = w[(o * 64 + ci) * 9 + tap];
}

// ---------------- fused 3x3 conv (SAME), half-row blocks, 8-ci weight chunks.
// LDS 24.8 KB -> 6 blocks/CU; grid 1536 -> ~24 waves/CU.
__global__ __launch_bounds__(256) void k_conv(
        const float* __restrict__ x, const float* __restrict__ wt,
        const float* __restrict__ bq, const float* __restrict__ bk, const float* __restrict__ bv,
        unsigned short* __restrict__ Q2, unsigned short* __restrict__ K2,
        unsigned short* __restrict__ V2, unsigned short* __restrict__ VLO) {
    int hw = blockIdx.x;                 // 0..127
    int h = hw >> 1, wh = hw & 1;
    int b = blockIdx.y, conv = blockIdx.z;
    const float* bias = (conv == 0) ? bq : (conv == 1) ? bk : bv;
    const float* wtc = wt + conv * 36864;

    __shared__ float xch[8 * 3 * 34];    // 816 floats: [cil][dy][col], col pads +-1
    __shared__ float wch[8 * 9 * 64];    // 4608 floats: [cil][tap][o]

    int tid = threadIdx.x;
    int wtd = tid & 7, ot = tid >> 3;    // 8 w-groups (4 w) x 32 o-groups (2 o)
    int w0 = wtd * 4, o0 = ot * 2;

    float acc[2][4];
    {
        float2 b2 = *(const float2*)(bias + o0);
        acc[0][0] = acc[0][1] = acc[0][2] = acc[0][3] = b2.x;
        acc[1][0] = acc[1][1] = acc[1][2] = acc[1][3] = b2.y;
    }

    for (int ck = 0; ck < 8; ++ck) {
        __syncthreads();
        for (int idx = tid; idx < 816; idx += 256) {
            int col = idx % 34;
            int row = idx / 34;
            int dy = row % 3, cil = row / 3;
            int ci = ck * 8 + cil;
            int hs = h + dy - 1;
            int wg = wh * 32 + col - 1;
            float val = 0.0f;
            if (wg >= 0 && wg < 64 && hs >= 0 && hs < 64)
                val = x[((b * 64 + ci) * 64 + hs) * 64 + wg];
            xch[(cil * 3 + dy) * 34 + col] = val;
        }
        for (int idx = tid; idx < 1152; idx += 256)
            ((float4*)wch)[idx] = ((const float4*)(wtc + ck * 4608))[idx];
        __syncthreads();

        for (int cil = 0; cil < 8; ++cil) {
#pragma unroll
            for (int dy = 0; dy < 3; ++dy) {
                float xv[6];
#pragma unroll
                for (int s = 0; s < 6; ++s) xv[s] = xch[(cil * 3 + dy) * 34 + w0 + s];
#pragma unroll
                for (int dx = 0; dx < 3; ++dx) {
                    float2 w2 = *(const float2*)(wch + (cil * 9 + dy * 3 + dx) * 64 + o0);
#pragma unroll
                    for (int ww = 0; ww < 4; ++ww) {
                        acc[0][ww] += xv[ww + dx] * w2.x;
                        acc[1][ww] += xv[ww + dx] * w2.y;
                    }
                }
            }
        }
    }

    if (conv < 2) {
        unsigned short* dst = (conv == 0) ? Q2 : K2;
        int kst = o0 >> 4, hb = (o0 >> 3) & 1, e0 = o0 & 7;
#pragma unroll
        for (int ww = 0; ww < 4; ++ww) {
            int n = h * 64 + wh * 32 + w0 + ww;
            int i5 = n & 31, nch = n >> 5;
            unsigned short h0, l0, h1, l1;
            split2(acc[0][ww], h0, l0);
            split2(acc[1][ww], h1, l1);
            size_t baseh = (size_t)(((b * 128 + nch) * 4 + kst) * 2 + 0) * 512 + (hb * 32 + i5) * 8 + e0;
            *(unsigned int*)(dst + baseh) = (unsigned int)h0 | ((unsigned int)h1 << 16);
            *(unsigned int*)(dst + baseh + 512) = (unsigned int)l0 | ((unsigned int)l1 << 16);
        }
    } else {
        int w0g = wh * 32 + w0;
        int nb = h * 64 + w0g;
        int ich = nb >> 5, nloc = nb & 31;
        int ksub = (nloc >> 4) & 1, hb2 = (nloc >> 3) & 1, e0 = nloc & 7;
#pragma unroll
        for (int oo = 0; oo < 2; ++oo) {
            int c = o0 + oo;
            int cb = c >> 5, cl = c & 31;
            unsigned short h4[4], l4[4];
#pragma unroll
            for (int ww = 0; ww < 4; ++ww) split2(acc[oo][ww], h4[ww], l4[ww]);
            size_t base = (size_t)(((b * 128 + ich) * 2 + ksub) * 2 + cb) * 512 + (hb2 * 32 + cl) * 8 + e0;
            uint2 hv, lv;
            hv.x = h4[0] | ((unsigned int)h4[1] << 16);
            hv.y = h4[2] | ((unsigned int)h4[3] << 16);
            lv.x = l4[0] | ((unsigned int)l4[1] << 16);
            lv.y = l4[2] | ((unsigned int)l4[3] << 16);
            *(uint2*)(V2 + base) = hv;
            *(uint2*)(VLO + base) = lv;
        }
    }
}

// ---------------- channel Gram partials: 64 n-chunks x 4 b = 256 blocks
__global__ __launch_bounds__(256) void k_gram(const float* __restrict__ x, float* __restrict__ Gp64) {
    int nc = blockIdx.x, b = blockIdx.y;
    __shared__ float xs[64 * 65];
    int tid = threadIdx.x;
#pragma unroll
    for (int it = 0; it < 4; ++it) {
        int f4i = tid + it * 256;
        int c = f4i >> 4, n4 = f4i & 15;
        float4 vv = *(const float4*)(x + (size_t)(b * 64 + c) * 4096 + nc * 64 + n4 * 4);
        xs[c * 65 + n4 * 4 + 0] = vv.x;
        xs[c * 65 + n4 * 4 + 1] = vv.y;
        xs[c * 65 + n4 * 4 + 2] = vv.z;
        xs[c * 65 + n4 * 4 + 3] = vv.w;
    }
    __syncthreads();
    int tc = tid & 15, td = tid >> 4;
    int c0 = tc * 4, d0 = td * 4;
    float acc[4][4];
#pragma unroll
    for (int i = 0; i < 4; ++i)
#pragma unroll
        for (int j = 0; j < 4; ++j) acc[i][j] = 0.0f;
    for (int n = 0; n < 64; ++n) {
        float xc[4], xd[4];
#pragma unroll
        for (int i = 0; i < 4; ++i) xc[i] = xs[(c0 + i) * 65 + n];
#pragma unroll
        for (int j = 0; j < 4; ++j) xd[j] = xs[(d0 + j) * 65 + n];
#pragma unroll
        for (int i = 0; i < 4; ++i)
#pragma unroll
            for (int j = 0; j < 4; ++j) acc[i][j] += xc[i] * xd[j];
    }
#pragma unroll
    for (int i = 0; i < 4; ++i) {
        float4 o4 = {acc[i][0], acc[i][1], acc[i][2], acc[i][3]};
        *(float4*)(Gp64 + (size_t)(nc * 4 + b) * 4096 + (c0 + i) * 64 + d0) = o4;
    }
}

// ---------------- channel softmax rows (64 partials)
__global__ void k_asm(const float* __restrict__ Gp64, float* __restrict__ A) {
    int row = blockIdx.x;      // b*64 + c
    int d = threadIdx.x;
    int b = row >> 6, c = row & 63;
    float g = 0.0f;
    for (int p = 0; p < 64; ++p) g += Gp64[(size_t)(p * 4 + b) * 4096 + c * 64 + d];
    float mx = g;
    for (int off = 32; off >= 1; off >>= 1) mx = fmaxf(mx, __shfl_xor(mx, off, 64));
    float e = __expf(g - mx);
    float s = e;
    for (int off = 32; off >= 1; off >>= 1) s += __shfl_xor(s, off, 64);
    A[row * 64 + d] = e / s;
}

// ---------------- pass1: invl_i = 1 / sum_j exp(s_ij). S^T = mfma32(K, Q).
__global__ __launch_bounds__(512) void k_pass1(
        const unsigned short* __restrict__ Q2, const unsigned short* __restrict__ K2,
        float* __restrict__ invl) {
    int flat = blockIdx.x;
    int xcd = flat & 7;
    int b = xcd >> 1;
    int pr = (xcd & 1) * 32 + (flat >> 3);   // ich-pair 0..63
    int tid = threadIdx.x, lane = tid & 63, wv = tid >> 6;
    int jp = wv & 3, ichL = wv >> 2;
    int ich = pr * 2 + ichL;

    __shared__ float lsum[2][4][32];

    const unsigned short* qp = Q2 + (size_t)(b * 128 + ich) * 4096 + lane * 8;
    s8v qf0 = *(const s8v*)(qp);
    s8v qf1 = *(const s8v*)(qp + 512);
    s8v qf2 = *(const s8v*)(qp + 1024);
    s8v qf3 = *(const s8v*)(qp + 1536);
    s8v qf4 = *(const s8v*)(qp + 2048);
    s8v qf5 = *(const s8v*)(qp + 2560);
    s8v qf6 = *(const s8v*)(qp + 3072);
    s8v qf7 = *(const s8v*)(qp + 3584);

    float la0 = 0.f, la1 = 0.f;
#pragma unroll 1
    for (int t = 0; t < 32; ++t) {
        int jch = jp * 32 + t;
        const unsigned short* kp = K2 + (size_t)(b * 128 + jch) * 4096 + lane * 8;
        s8v kf0 = *(const s8v*)(kp);
        s8v kf1 = *(const s8v*)(kp + 512);
        s8v kf2 = *(const s8v*)(kp + 1024);
        s8v kf3 = *(const s8v*)(kp + 1536);
        s8v kf4 = *(const s8v*)(kp + 2048);
        s8v kf5 = *(const s8v*)(kp + 2560);
        s8v kf6 = *(const s8v*)(kp + 3072);
        s8v kf7 = *(const s8v*)(kp + 3584);
        f16v Sa = zero16(), Sb = zero16();
        Sa = MFMA32(kf0, qf0, Sa);
        Sa = MFMA32(kf0, qf1, Sa);
        Sa = MFMA32(kf1, qf0, Sa);
        Sa = MFMA32(kf2, qf2, Sa);
        Sa = MFMA32(kf2, qf3, Sa);
        Sa = MFMA32(kf3, qf2, Sa);
        Sb = MFMA32(kf4, qf4, Sb);
        Sb = MFMA32(kf4, qf5, Sb);
        Sb = MFMA32(kf5, qf4, Sb);
        Sb = MFMA32(kf6, qf6, Sb);
        Sb = MFMA32(kf6, qf7, Sb);
        Sb = MFMA32(kf7, qf6, Sb);
#pragma unroll
        for (int r = 0; r < 8; ++r) la0 += __expf(Sa[r] + Sb[r]);
#pragma unroll
        for (int r = 8; r < 16; ++r) la1 += __expf(Sa[r] + Sb[r]);
    }
    float lacc = la0 + la1;
    lacc += __shfl_xor(lacc, 32);
    if (lane < 32) lsum[ichL][jp][lane] = lacc;
    __syncthreads();
    if (tid < 64) {
        int iL = tid & 31, iH = tid >> 5;
        float s = lsum[iH][0][iL] + lsum[iH][1][iL] + lsum[iH][2][iL] + lsum[iH][3][iL];
        invl[b * 4096 + (pr * 2 + iH) * 32 + iL] = 1.0f / s;
    }
}

// ---------------- fold invl into V (hi-only), in V2 fragment layout, in place
__global__ __launch_bounds__(256) void k_vnorm(
        unsigned short* __restrict__ V2, const unsigned short* __restrict__ VLO,
        const float* __restrict__ invl) {
    int u = blockIdx.x * 256 + threadIdx.x;      // < 131072 16B-segs
    int lane = u & 63, ksub = (u >> 7) & 1;
    int ich = (u >> 8) & 127, b = u >> 15;
    int n0 = ich * 32 + ksub * 16 + (lane >> 5) * 8;
    size_t base = (size_t)u * 8;
    s8v vh = *(s8v*)(V2 + base);
    s8v vl = *(const s8v*)(VLO + base);
    float4 iv0 = *(const float4*)(invl + b * 4096 + n0);
    float4 iv1 = *(const float4*)(invl + b * 4096 + n0 + 4);
    float ivv[8] = {iv0.x, iv0.y, iv0.z, iv0.w, iv1.x, iv1.y, iv1.z, iv1.w};
    s8v o;
#pragma unroll
    for (int e = 0; e < 8; ++e) {
        float v = bf2f((unsigned short)vh[e]) + bf2f((unsigned short)vl[e]);
        o[e] = (short)bf16_rne(v * ivv[e]);
    }
    *(s8v*)(V2 + base) = o;
}

// ---------------- pass2 + fused final: barrier-free flash loop, in-register P
// via permlane; epilogue computes out = pg*pos + cg*(A@x) + 2x directly.
__global__ __launch_bounds__(512) void k_pass2(
        const unsigned short* __restrict__ Q2, const unsigned short* __restrict__ K2,
        const unsigned short* __restrict__ V2, const float* __restrict__ x,
        const float* __restrict__ A, const float* __restrict__ pg,
        const float* __restrict__ cg, float* __restrict__ out) {
    int flat = blockIdx.x;
    int xcd = flat & 7;
    int b = xcd >> 1;
    int pr = (xcd & 1) * 32 + (flat >> 3);   // jt-pair 0..63
    int tid = threadIdx.x, lane = tid & 63, wv = tid >> 6;
    int ip = wv & 3, jhalf = wv >> 2;
    int jt = pr * 2 + jhalf;

    __shared__ float rlds[2][4][64][32];     // [jhalf][ipart][c][j]; reused in epilogue

    const unsigned short* kp = K2 + (size_t)(b * 128 + jt) * 4096 + lane * 8;
    s8v kf0 = *(const s8v*)(kp);
    s8v kf1 = *(const s8v*)(kp + 512);
    s8v kf2 = *(const s8v*)(kp + 1024);
    s8v kf3 = *(const s8v*)(kp + 1536);
    s8v kf4 = *(const s8v*)(kp + 2048);
    s8v kf5 = *(const s8v*)(kp + 2560);
    s8v kf6 = *(const s8v*)(kp + 3072);
    s8v kf7 = *(const s8v*)(kp + 3584);

    f16v O0 = zero16(), O1 = zero16();

#pragma unroll 1
    for (int t = 0; t < 32; ++t) {
        int ich = ip * 32 + t;
        const unsigned short* qp = Q2 + (size_t)(b * 128 + ich) * 4096 + lane * 8;
        s8v qf0 = *(const s8v*)(qp);
        s8v qf1 = *(const s8v*)(qp + 512);
        s8v qf2 = *(const s8v*)(qp + 1024);
        s8v qf3 = *(const s8v*)(qp + 1536);
        s8v qf4 = *(const s8v*)(qp + 2048);
        s8v qf5 = *(const s8v*)(qp + 2560);
        s8v qf6 = *(const s8v*)(qp + 3072);
        s8v qf7 = *(const s8v*)(qp + 3584);
        const unsigned short* vp = V2 + (size_t)(b * 128 + ich) * 2048 + lane * 8;
        s8v vA = *(const s8v*)(vp);
        s8v vB = *(const s8v*)(vp + 512);
        s8v vC = *(const s8v*)(vp + 1024);
        s8v vD = *(const s8v*)(vp + 1536);

        f16v Sa = zero16(), Sb = zero16();
        Sa = MFMA32(qf0, kf0, Sa);
        Sa = MFMA32(qf0, kf1, Sa);
        Sa = MFMA32(qf1, kf0, Sa);
        Sa = MFMA32(qf2, kf2, Sa);
        Sa = MFMA32(qf2, kf3, Sa);
        Sa = MFMA32(qf3, kf2, Sa);
        Sb = MFMA32(qf4, kf4, Sb);
        Sb = MFMA32(qf4, kf5, Sb);
        Sb = MFMA32(qf5, kf4, Sb);
        Sb = MFMA32(qf6, kf6, Sb);
        Sb = MFMA32(qf6, kf7, Sb);
        Sb = MFMA32(qf7, kf6, Sb);

        float p[16];
#pragma unroll
        for (int r = 0; r < 16; ++r) p[r] = __expf(Sa[r] + Sb[r]);

        unsigned int a0 = pk2(p[0], p[1]),  a1 = pk2(p[2], p[3]);
        unsigned int a2 = pk2(p[4], p[5]),  a3 = pk2(p[6], p[7]);
        pl32swap(a0, a2);
        pl32swap(a1, a3);
        s8v P0 = mk8(a0, a1, a2, a3);
        unsigned int b0 = pk2(p[8], p[9]),  b1 = pk2(p[10], p[11]);
        unsigned int b2 = pk2(p[12], p[13]), b3 = pk2(p[14], p[15]);
        pl32swap(b0, b2);
        pl32swap(b1, b3);
        s8v P1 = mk8(b0, b1, b2, b3);

        O0 = MFMA32(vA, P0, O0);
        O0 = MFMA32(vC, P1, O0);
        O1 = MFMA32(vB, P0, O1);
        O1 = MFMA32(vD, P1, O1);
    }

    int hh = lane >> 5, jj = lane & 31;
#pragma unroll
    for (int r = 0; r < 16; ++r) {
        int c = (r & 3) + 8 * (r >> 2) + 4 * hh;
        rlds[jhalf][ip][c][jj] = O0[r];
        rlds[jhalf][ip][c + 32][jj] = O1[r];
    }
    __syncthreads();
    float sums[8];
#pragma unroll
    for (int k = 0; k < 8; ++k) {
        int e = tid + k * 512;
        int jh = e >> 11, rem = e & 2047, c = rem >> 5, j2 = rem & 31;
        sums[k] = rlds[jh][0][c][j2] + rlds[jh][1][c][j2]
                + rlds[jh][2][c][j2] + rlds[jh][3][c][j2];
    }
    __syncthreads();                 // all sums read; rlds reusable
    // restage x tile [64 d][64 j] and A [64 c][64 d] into rlds space
    float* sb = &rlds[0][0][0][0];
    float* xs2 = sb;                 // [64][65]
    float* As2 = sb + 4160;          // [64][64]
    int n0 = pr * 64;
#pragma unroll
    for (int it = 0; it < 2; ++it) {
        int f4i = tid + it * 512;
        int d = f4i >> 4, j4 = f4i & 15;
        float4 vv = *(const float4*)(x + (size_t)(b * 64 + d) * 4096 + n0 + j4 * 4);
        xs2[d * 65 + j4 * 4 + 0] = vv.x;
        xs2[d * 65 + j4 * 4 + 1] = vv.y;
        xs2[d * 65 + j4 * 4 + 2] = vv.z;
        xs2[d * 65 + j4 * 4 + 3] = vv.w;
        ((float4*)As2)[f4i] = ((const float4*)(A + (size_t)b * 4096))[f4i];
    }
    __syncthreads();
    float pgv = pg[0], cgv = cg[0];
#pragma unroll
    for (int k = 0; k < 8; ++k) {
        int e = tid + k * 512;
        int jh = e >> 11, rem = e & 2047, c = rem >> 5, j2 = rem & 31;
        int jt2 = jh * 32 + j2;
        float ch = 0.f;
#pragma unroll
        for (int d = 0; d < 64; ++d) ch += As2[c * 64 + d] * xs2[d * 65 + jt2];
        float xc = xs2[c * 65 + jt2];
        out[(size_t)(b * 64 + c) * 4096 + n0 + jt2] = pgv * sums[k] + cgv * ch + 2.0f * xc;
    }
}

extern "C" void kernel_launch(void* const* d_in, const int* in_sizes, int n_in,
                              void* d_out, int out_size, void* d_ws, size_t ws_size,
                              hipStream_t stream) {
    const float* x  = (const float*)d_in[0];
    const float* wq = (const float*)d_in[1];
    const float* bq = (const float*)d_in[2];
    const float* wk = (const float*)d_in[3];
    const float* bk = (const float*)d_in[4];
    const float* wv = (const float*)d_in[5];
    const float* bv = (const float*)d_in[6];
    const float* pg = (const float*)d_in[7];
    const float* cg = (const float*)d_in[8];
    float* out = (float*)d_out;

    if (ws_size < (size_t)WS_FLOATS * sizeof(float)) return;
    float* ws = (float*)d_ws;
    float* Gp64 = ws + OFF_POS;      // 64*4*4096 floats, reused scratch
    unsigned short* Q2  = (unsigned short*)(ws + OFF_Q2);
    unsigned short* K2  = (unsigned short*)(ws + OFF_K2);
    unsigned short* V2  = (unsigned short*)(ws + OFF_V2);
    unsigned short* VLO = (unsigned short*)(ws + OFF_VLO);
    float* wt   = ws + OFF_WT;
    float* invl = ws + OFF_INVL;
    float* A    = ws + OFF_A;

    k_wtrans<<<432, 256, 0, stream>>>(wq, wk, wv, wt);
    k_conv<<<dim3(128, 4, 3), 256, 0, stream>>>(x, wt, bq, bk, bv, Q2, K2, V2, VLO);
    k_gram<<<dim3(64, 4), 256, 0, stream>>>(x, Gp64);
    k_asm<<<256, 64, 0, stream>>>(Gp64, A);
    k_pass1<<<256, 512, 0, stream>>>(Q2, K2, invl);
    k_vnorm<<<512, 256, 0, stream>>>(V2, VLO, invl);
    k_pass2<<<256, 512, 0, stream>>>(Q2, K2, V2, x, A, pg, cg, out);
}

// Round 9
// 128.077 us; speedup vs baseline: 1.9926x; 1.3533x over previous
//
#include <hip/hip_runtime.h>

// Problem constants: B=4, C=64, H=W=64, N=4096
// Workspace layout (float offsets) — 4,747,264 floats (same proven footprint).
#define OFF_POS   0u          // Gram partials (64*4*4096 = 1,048,576 exact)
#define OFF_Q2    1048576u
#define OFF_K2    2097152u
#define OFF_V2    3145728u
#define OFF_VLO   3670016u
#define OFF_WT    4194304u    // W fragments split-bf16: 216 frags * 2 * 512 shorts = 110,592 floats exact
#define OFF_INVL  4452352u
#define OFF_GPART 4468736u
#define OFF_A     4730880u
#define WS_FLOATS 4747264u

typedef short s8v __attribute__((ext_vector_type(8)));
typedef float f4v __attribute__((ext_vector_type(4)));
typedef float f16v __attribute__((ext_vector_type(16)));

#define MFMA32(a, b, c) __builtin_amdgcn_mfma_f32_32x32x16_bf16((a), (b), (c), 0, 0, 0)

__device__ __forceinline__ unsigned short bf16_rne(float f) {
    union { float f; unsigned int u; } v; v.f = f;
    unsigned int r = v.u + 0x7FFFu + ((v.u >> 16) & 1u);
    return (unsigned short)(r >> 16);
}
__device__ __forceinline__ float bf2f(unsigned short h) {
    union { unsigned int u; float f; } t; t.u = ((unsigned int)h) << 16;
    return t.f;
}
__device__ __forceinline__ void split2(float f, unsigned short& h, unsigned short& l) {
    unsigned short hh = bf16_rne(f);
    h = hh;
    l = bf16_rne(f - bf2f(hh));
}
__device__ __forceinline__ unsigned int pk2(float lo, float hi) {
    return (unsigned int)bf16_rne(lo) | ((unsigned int)bf16_rne(hi) << 16);
}
// v_permlane32_swap_b32: a.high32lanes <-> b.low32lanes (both regs updated)
__device__ __forceinline__ void pl32swap(unsigned int& a, unsigned int& b) {
    asm volatile("v_permlane32_swap_b32 %0, %1" : "+v"(a), "+v"(b));
}
__device__ __forceinline__ s8v mk8(unsigned int w0, unsigned int w1,
                                   unsigned int w2, unsigned int w3) {
    union { unsigned int u[4]; s8v v; } t;
    t.u[0] = w0; t.u[1] = w1; t.u[2] = w2; t.u[3] = w3;
    return t.v;
}
__device__ __forceinline__ f16v zero16() {
    f16v z;
#pragma unroll
    for (int i = 0; i < 16; ++i) z[i] = 0.0f;
    return z;
}

// Fragment layouts (32x32x16-ready):
//  Q2/K2: idx = (((b*128 + nch)*4 + kst)*2 + hl)*512 + lane*8 + e
//         holds X[n = nch*32 + (lane&31)][c = kst*16 + (lane>>5)*8 + e]
//  V2:    idx = (((b*128 + ich)*2 + ksub)*2 + cb)*512 + lane*8 + e
//         holds V[c = cb*32 + (lane&31)][n = ich*32 + ksub*16 + (lane>>5)*8 + e]
//  WF:    frag f = ((conv*9 + tap)*4 + kst)*2 + oc; idx = (f*2 + hl)*512 + lane*8 + e
//         holds w[o = oc*32 + (lane&31)][ci = kst*16 + (lane>>5)*8 + e][tap]

// ---------------- weight fragment build (split-bf16)
__global__ void k_wtrans(const float* __restrict__ wq, const float* __restrict__ wk,
                         const float* __restrict__ wv, unsigned short* __restrict__ wf) {
    int t = blockIdx.x * 256 + threadIdx.x;   // < 110592
    int f = t >> 9, pos = t & 511;
    int lane = pos >> 3, e = pos & 7;
    int oc = f & 1, kst = (f >> 1) & 3;
    int ct = f >> 3;                           // conv*9 + tap
    int tap = ct % 9, conv = ct / 9;
    int o = oc * 32 + (lane & 31);
    int ci = kst * 16 + (lane >> 5) * 8 + e;
    const float* w = (conv == 0) ? wq : (conv == 1) ? wk : wv;
    float v = w[(o * 64 + ci) * 9 + tap];
    unsigned short hh, ll;
    split2(v, hh, ll);
    wf[(f * 2 + 0) * 512 + pos] = hh;
    wf[(f * 2 + 1) * 512 + pos] = ll;
}

// ---------------- MFMA 3x3 conv: block = (32-n half-row, b); 6 waves = (conv, ohalf).
// X window (3 dy x 34 W x 64 c) split-bf16 staged in LDS with XOR swizzle;
// W frags streamed from L2; outputs converted in-register to Q2/K2/V2 fragment
// layouts via the pass2-proven split+pack+permlane32_swap recipe.
__global__ __launch_bounds__(384) void k_conv(
        const float* __restrict__ x, const unsigned short* __restrict__ wf,
        const float* __restrict__ bq, const float* __restrict__ bk, const float* __restrict__ bv,
        unsigned short* __restrict__ Q2, unsigned short* __restrict__ K2,
        unsigned short* __restrict__ V2, unsigned short* __restrict__ VLO) {
    int nb = blockIdx.x;                 // 0..127 (n-block of 32)
    int b = blockIdx.y;
    int h = nb >> 1, w0 = (nb & 1) * 32;

    __shared__ unsigned short xwh[6528];  // [dy 3][W 34][c 64], XOR-swizzled
    __shared__ unsigned short xwl[6528];

    int tid = threadIdx.x;
    // stage X window with on-the-fly fp32 -> split-bf16 (zeros at SAME-pad edges)
    for (int idx = tid; idx < 6528; idx += 384) {
        int W = idx % 34;
        int c = (idx / 34) & 63;
        int dy = idx / (34 * 64);
        int hs = h + dy - 1, wi = w0 + W - 1;
        float v = 0.0f;
        if (hs >= 0 && hs < 64 && wi >= 0 && wi < 64)
            v = x[((b * 64 + c) * 64 + hs) * 64 + wi];
        unsigned short hh_, ll_;
        split2(v, hh_, ll_);
        int row = dy * 34 + W;
        int byt = row * 128 + c * 2;
        int swz = byt ^ ((row & 7) << 4);
        *(unsigned short*)((char*)xwh + swz) = hh_;
        *(unsigned short*)((char*)xwl + swz) = ll_;
    }
    __syncthreads();

    int lane = tid & 63, wv = tid >> 6;   // 6 waves
    int conv = wv >> 1, oc = wv & 1;
    int hh = lane >> 5, l31 = lane & 31;

    const float* bias = (conv == 0) ? bq : (conv == 1) ? bk : bv;
    f16v D;
    if (conv < 2) {
#pragma unroll
        for (int r = 0; r < 16; ++r)
            D[r] = bias[oc * 32 + (r & 3) + 8 * (r >> 2) + 4 * hh];
    } else {
        float bvv = bias[oc * 32 + l31];
#pragma unroll
        for (int r = 0; r < 16; ++r) D[r] = bvv;
    }

#pragma unroll
    for (int tap = 0; tap < 9; ++tap) {
        int dy = tap / 3, dx = tap % 3;
#pragma unroll
        for (int kst = 0; kst < 4; ++kst) {
            int f = ((conv * 9 + tap) * 4 + kst) * 2 + oc;
            s8v Wh = *(const s8v*)(wf + (f * 2 + 0) * 512 + lane * 8);
            s8v Wl = *(const s8v*)(wf + (f * 2 + 1) * 512 + lane * 8);
            int row = dy * 34 + dx + l31;
            int byt = row * 128 + kst * 32 + hh * 16;
            int swz = byt ^ ((row & 7) << 4);
            s8v Xh = *(const s8v*)((const char*)xwh + swz);
            s8v Xl = *(const s8v*)((const char*)xwl + swz);
            if (conv < 2) {
                D = MFMA32(Wh, Xh, D);    // D[col=n][row=o]
                D = MFMA32(Wh, Xl, D);
                D = MFMA32(Wl, Xh, D);
            } else {
                D = MFMA32(Xh, Wh, D);    // D[col=o][row=n]
                D = MFMA32(Xl, Wh, D);
                D = MFMA32(Xh, Wl, D);
            }
        }
    }

    // convert D (rows -> future-k) into two split-bf16 fragments (k 0..15, 16..31)
    unsigned short sh[16], sl[16];
#pragma unroll
    for (int r = 0; r < 16; ++r) split2(D[r], sh[r], sl[r]);
    unsigned int ah0 = sh[0] | ((unsigned int)sh[1] << 16), ah1 = sh[2] | ((unsigned int)sh[3] << 16);
    unsigned int ah2 = sh[4] | ((unsigned int)sh[5] << 16), ah3 = sh[6] | ((unsigned int)sh[7] << 16);
    pl32swap(ah0, ah2); pl32swap(ah1, ah3);
    s8v F0h = mk8(ah0, ah1, ah2, ah3);
    unsigned int al0 = sl[0] | ((unsigned int)sl[1] << 16), al1 = sl[2] | ((unsigned int)sl[3] << 16);
    unsigned int al2 = sl[4] | ((unsigned int)sl[5] << 16), al3 = sl[6] | ((unsigned int)sl[7] << 16);
    pl32swap(al0, al2); pl32swap(al1, al3);
    s8v F0l = mk8(al0, al1, al2, al3);
    unsigned int bh0 = sh[8] | ((unsigned int)sh[9] << 16), bh1 = sh[10] | ((unsigned int)sh[11] << 16);
    unsigned int bh2 = sh[12] | ((unsigned int)sh[13] << 16), bh3 = sh[14] | ((unsigned int)sh[15] << 16);
    pl32swap(bh0, bh2); pl32swap(bh1, bh3);
    s8v F1h = mk8(bh0, bh1, bh2, bh3);
    unsigned int bl0 = sl[8] | ((unsigned int)sl[9] << 16), bl1 = sl[10] | ((unsigned int)sl[11] << 16);
    unsigned int bl2 = sl[12] | ((unsigned int)sl[13] << 16), bl3 = sl[14] | ((unsigned int)sl[15] << 16);
    pl32swap(bl0, bl2); pl32swap(bl1, bl3);
    s8v F1l = mk8(bl0, bl1, bl2, bl3);

    if (conv < 2) {
        unsigned short* dst = (conv == 0) ? Q2 : K2;
        size_t b0 = (size_t)(((b * 128 + nb) * 4 + oc * 2 + 0) * 2) * 512 + lane * 8;
        size_t b1 = (size_t)(((b * 128 + nb) * 4 + oc * 2 + 1) * 2) * 512 + lane * 8;
        *(s8v*)(dst + b0) = F0h;
        *(s8v*)(dst + b0 + 512) = F0l;
        *(s8v*)(dst + b1) = F1h;
        *(s8v*)(dst + b1 + 512) = F1l;
    } else {
        size_t b0 = (size_t)((((b * 128 + nb) * 2 + 0) * 2 + oc)) * 512 + lane * 8;
        size_t b1 = (size_t)((((b * 128 + nb) * 2 + 1) * 2 + oc)) * 512 + lane * 8;
        *(s8v*)(V2 + b0) = F0h;
        *(s8v*)(VLO + b0) = F0l;
        *(s8v*)(V2 + b1) = F1h;
        *(s8v*)(VLO + b1) = F1l;
    }
}

// ---------------- channel Gram partials: 64 n-chunks x 4 b = 256 blocks
__global__ __launch_bounds__(256) void k_gram(const float* __restrict__ x, float* __restrict__ Gp64) {
    int nc = blockIdx.x, b = blockIdx.y;
    __shared__ float xs[64 * 65];
    int tid = threadIdx.x;
#pragma unroll
    for (int it = 0; it < 4; ++it) {
        int f4i = tid + it * 256;
        int c = f4i >> 4, n4 = f4i & 15;
        float4 vv = *(const float4*)(x + (size_t)(b * 64 + c) * 4096 + nc * 64 + n4 * 4);
        xs[c * 65 + n4 * 4 + 0] = vv.x;
        xs[c * 65 + n4 * 4 + 1] = vv.y;
        xs[c * 65 + n4 * 4 + 2] = vv.z;
        xs[c * 65 + n4 * 4 + 3] = vv.w;
    }
    __syncthreads();
    int tc = tid & 15, td = tid >> 4;
    int c0 = tc * 4, d0 = td * 4;
    float acc[4][4];
#pragma unroll
    for (int i = 0; i < 4; ++i)
#pragma unroll
        for (int j = 0; j < 4; ++j) acc[i][j] = 0.0f;
    for (int n = 0; n < 64; ++n) {
        float xc[4], xd[4];
#pragma unroll
        for (int i = 0; i < 4; ++i) xc[i] = xs[(c0 + i) * 65 + n];
#pragma unroll
        for (int j = 0; j < 4; ++j) xd[j] = xs[(d0 + j) * 65 + n];
#pragma unroll
        for (int i = 0; i < 4; ++i)
#pragma unroll
            for (int j = 0; j < 4; ++j) acc[i][j] += xc[i] * xd[j];
    }
#pragma unroll
    for (int i = 0; i < 4; ++i) {
        float4 o4 = {acc[i][0], acc[i][1], acc[i][2], acc[i][3]};
        *(float4*)(Gp64 + (size_t)(nc * 4 + b) * 4096 + (c0 + i) * 64 + d0) = o4;
    }
}

// ---------------- channel softmax rows (64 partials)
__global__ void k_asm(const float* __restrict__ Gp64, float* __restrict__ A) {
    int row = blockIdx.x;      // b*64 + c
    int d = threadIdx.x;
    int b = row >> 6, c = row & 63;
    float g = 0.0f;
    for (int p = 0; p < 64; ++p) g += Gp64[(size_t)(p * 4 + b) * 4096 + c * 64 + d];
    float mx = g;
    for (int off = 32; off >= 1; off >>= 1) mx = fmaxf(mx, __shfl_xor(mx, off, 64));
    float e = __expf(g - mx);
    float s = e;
    for (int off = 32; off >= 1; off >>= 1) s += __shfl_xor(s, off, 64);
    A[row * 64 + d] = e / s;
}

// ---------------- pass1: invl_i = 1 / sum_j exp(s_ij). S^T = mfma32(K, Q).
__global__ __launch_bounds__(512) void k_pass1(
        const unsigned short* __restrict__ Q2, const unsigned short* __restrict__ K2,
        float* __restrict__ invl) {
    int flat = blockIdx.x;
    int xcd = flat & 7;
    int b = xcd >> 1;
    int pr = (xcd & 1) * 32 + (flat >> 3);   // ich-pair 0..63
    int tid = threadIdx.x, lane = tid & 63, wv = tid >> 6;
    int jp = wv & 3, ichL = wv >> 2;
    int ich = pr * 2 + ichL;

    __shared__ float lsum[2][4][32];

    const unsigned short* qp = Q2 + (size_t)(b * 128 + ich) * 4096 + lane * 8;
    s8v qf0 = *(const s8v*)(qp);
    s8v qf1 = *(const s8v*)(qp + 512);
    s8v qf2 = *(const s8v*)(qp + 1024);
    s8v qf3 = *(const s8v*)(qp + 1536);
    s8v qf4 = *(const s8v*)(qp + 2048);
    s8v qf5 = *(const s8v*)(qp + 2560);
    s8v qf6 = *(const s8v*)(qp + 3072);
    s8v qf7 = *(const s8v*)(qp + 3584);

    float la0 = 0.f, la1 = 0.f;
#pragma unroll 1
    for (int t = 0; t < 32; ++t) {
        int jch = jp * 32 + t;
        const unsigned short* kp = K2 + (size_t)(b * 128 + jch) * 4096 + lane * 8;
        s8v kf0 = *(const s8v*)(kp);
        s8v kf1 = *(const s8v*)(kp + 512);
        s8v kf2 = *(const s8v*)(kp + 1024);
        s8v kf3 = *(const s8v*)(kp + 1536);
        s8v kf4 = *(const s8v*)(kp + 2048);
        s8v kf5 = *(const s8v*)(kp + 2560);
        s8v kf6 = *(const s8v*)(kp + 3072);
        s8v kf7 = *(const s8v*)(kp + 3584);
        f16v Sa = zero16(), Sb = zero16();
        Sa = MFMA32(kf0, qf0, Sa);
        Sa = MFMA32(kf0, qf1, Sa);
        Sa = MFMA32(kf1, qf0, Sa);
        Sa = MFMA32(kf2, qf2, Sa);
        Sa = MFMA32(kf2, qf3, Sa);
        Sa = MFMA32(kf3, qf2, Sa);
        Sb = MFMA32(kf4, qf4, Sb);
        Sb = MFMA32(kf4, qf5, Sb);
        Sb = MFMA32(kf5, qf4, Sb);
        Sb = MFMA32(kf6, qf6, Sb);
        Sb = MFMA32(kf6, qf7, Sb);
        Sb = MFMA32(kf7, qf6, Sb);
#pragma unroll
        for (int r = 0; r < 8; ++r) la0 += __expf(Sa[r] + Sb[r]);
#pragma unroll
        for (int r = 8; r < 16; ++r) la1 += __expf(Sa[r] + Sb[r]);
    }
    float lacc = la0 + la1;
    lacc += __shfl_xor(lacc, 32);
    if (lane < 32) lsum[ichL][jp][lane] = lacc;
    __syncthreads();
    if (tid < 64) {
        int iL = tid & 31, iH = tid >> 5;
        float s = lsum[iH][0][iL] + lsum[iH][1][iL] + lsum[iH][2][iL] + lsum[iH][3][iL];
        invl[b * 4096 + (pr * 2 + iH) * 32 + iL] = 1.0f / s;
    }
}

// ---------------- fold invl into V (hi-only), in V2 fragment layout, in place
__global__ __launch_bounds__(256) void k_vnorm(
        unsigned short* __restrict__ V2, const unsigned short* __restrict__ VLO,
        const float* __restrict__ invl) {
    int u = blockIdx.x * 256 + threadIdx.x;      // < 131072 16B-segs
    int lane = u & 63, ksub = (u >> 7) & 1;
    int ich = (u >> 8) & 127, b = u >> 15;
    int n0 = ich * 32 + ksub * 16 + (lane >> 5) * 8;
    size_t base = (size_t)u * 8;
    s8v vh = *(s8v*)(V2 + base);
    s8v vl = *(const s8v*)(VLO + base);
    float4 iv0 = *(const float4*)(invl + b * 4096 + n0);
    float4 iv1 = *(const float4*)(invl + b * 4096 + n0 + 4);
    float ivv[8] = {iv0.x, iv0.y, iv0.z, iv0.w, iv1.x, iv1.y, iv1.z, iv1.w};
    s8v o;
#pragma unroll
    for (int e = 0; e < 8; ++e) {
        float v = bf2f((unsigned short)vh[e]) + bf2f((unsigned short)vl[e]);
        o[e] = (short)bf16_rne(v * ivv[e]);
    }
    *(s8v*)(V2 + base) = o;
}

// ---------------- pass2 + fused final: barrier-free flash loop, in-register P
// via permlane; epilogue computes out = pg*pos + cg*(A@x) + 2x directly.
__global__ __launch_bounds__(512) void k_pass2(
        const unsigned short* __restrict__ Q2, const unsigned short* __restrict__ K2,
        const unsigned short* __restrict__ V2, const float* __restrict__ x,
        const float* __restrict__ A, const float* __restrict__ pg,
        const float* __restrict__ cg, float* __restrict__ out) {
    int flat = blockIdx.x;
    int xcd = flat & 7;
    int b = xcd >> 1;
    int pr = (xcd & 1) * 32 + (flat >> 3);   // jt-pair 0..63
    int tid = threadIdx.x, lane = tid & 63, wv = tid >> 6;
    int ip = wv & 3, jhalf = wv >> 2;
    int jt = pr * 2 + jhalf;

    __shared__ float rlds[2][4][64][32];     // [jhalf][ipart][c][j]; reused in epilogue

    const unsigned short* kp = K2 + (size_t)(b * 128 + jt) * 4096 + lane * 8;
    s8v kf0 = *(const s8v*)(kp);
    s8v kf1 = *(const s8v*)(kp + 512);
    s8v kf2 = *(const s8v*)(kp + 1024);
    s8v kf3 = *(const s8v*)(kp + 1536);
    s8v kf4 = *(const s8v*)(kp + 2048);
    s8v kf5 = *(const s8v*)(kp + 2560);
    s8v kf6 = *(const s8v*)(kp + 3072);
    s8v kf7 = *(const s8v*)(kp + 3584);

    f16v O0 = zero16(), O1 = zero16();

#pragma unroll 1
    for (int t = 0; t < 32; ++t) {
        int ich = ip * 32 + t;
        const unsigned short* qp = Q2 + (size_t)(b * 128 + ich) * 4096 + lane * 8;
        s8v qf0 = *(const s8v*)(qp);
        s8v qf1 = *(const s8v*)(qp + 512);
        s8v qf2 = *(const s8v*)(qp + 1024);
        s8v qf3 = *(const s8v*)(qp + 1536);
        s8v qf4 = *(const s8v*)(qp + 2048);
        s8v qf5 = *(const s8v*)(qp + 2560);
        s8v qf6 = *(const s8v*)(qp + 3072);
        s8v qf7 = *(const s8v*)(qp + 3584);
        const unsigned short* vp = V2 + (size_t)(b * 128 + ich) * 2048 + lane * 8;
        s8v vA = *(const s8v*)(vp);
        s8v vB = *(const s8v*)(vp + 512);
        s8v vC = *(const s8v*)(vp + 1024);
        s8v vD = *(const s8v*)(vp + 1536);

        f16v Sa = zero16(), Sb = zero16();
        Sa = MFMA32(qf0, kf0, Sa);
        Sa = MFMA32(qf0, kf1, Sa);
        Sa = MFMA32(qf1, kf0, Sa);
        Sa = MFMA32(qf2, kf2, Sa);
        Sa = MFMA32(qf2, kf3, Sa);
        Sa = MFMA32(qf3, kf2, Sa);
        Sb = MFMA32(qf4, kf4, Sb);
        Sb = MFMA32(qf4, kf5, Sb);
        Sb = MFMA32(qf5, kf4, Sb);
        Sb = MFMA32(qf6, kf6, Sb);
        Sb = MFMA32(qf6, kf7, Sb);
        Sb = MFMA32(qf7, kf6, Sb);

        float p[16];
#pragma unroll
        for (int r = 0; r < 16; ++r) p[r] = __expf(Sa[r] + Sb[r]);

        unsigned int a0 = pk2(p[0], p[1]),  a1 = pk2(p[2], p[3]);
        unsigned int a2 = pk2(p[4], p[5]),  a3 = pk2(p[6], p[7]);
        pl32swap(a0, a2);
        pl32swap(a1, a3);
        s8v P0 = mk8(a0, a1, a2, a3);
        unsigned int b0 = pk2(p[8], p[9]),  b1 = pk2(p[10], p[11]);
        unsigned int b2 = pk2(p[12], p[13]), b3 = pk2(p[14], p[15]);
        pl32swap(b0, b2);
        pl32swap(b1, b3);
        s8v P1 = mk8(b0, b1, b2, b3);

        O0 = MFMA32(vA, P0, O0);
        O0 = MFMA32(vC, P1, O0);
        O1 = MFMA32(vB, P0, O1);
        O1 = MFMA32(vD, P1, O1);
    }

    int hh = lane >> 5, jj = lane & 31;
#pragma unroll
    for (int r = 0; r < 16; ++r) {
        int c = (r & 3) + 8 * (r >> 2) + 4 * hh;
        rlds[jhalf][ip][c][jj] = O0[r];
        rlds[jhalf][ip][c + 32][jj] = O1[r];
    }
    __syncthreads();
    float sums[8];
#pragma unroll
    for (int k = 0; k < 8; ++k) {
        int e = tid + k * 512;
        int jh = e >> 11, rem = e & 2047, c = rem >> 5, j2 = rem & 31;
        sums[k] = rlds[jh][0][c][j2] + rlds[jh][1][c][j2]
                + rlds[jh][2][c][j2] + rlds[jh][3][c][j2];
    }
    __syncthreads();                 // all sums read; rlds reusable
    // restage x tile [64 d][64 j] and A [64 c][64 d] into rlds space
    float* sb = &rlds[0][0][0][0];
    float* xs2 = sb;                 // [64][65]
    float* As2 = sb + 4160;          // [64][64]
    int n0 = pr * 64;
#pragma unroll
    for (int it = 0; it < 2; ++it) {
        int f4i = tid + it * 512;
        int d = f4i >> 4, j4 = f4i & 15;
        float4 vv = *(const float4*)(x + (size_t)(b * 64 + d) * 4096 + n0 + j4 * 4);
        xs2[d * 65 + j4 * 4 + 0] = vv.x;
        xs2[d * 65 + j4 * 4 + 1] = vv.y;
        xs2[d * 65 + j4 * 4 + 2] = vv.z;
        xs2[d * 65 + j4 * 4 + 3] = vv.w;
        ((float4*)As2)[f4i] = ((const float4*)(A + (size_t)b * 4096))[f4i];
    }
    __syncthreads();
    float pgv = pg[0], cgv = cg[0];
#pragma unroll
    for (int k = 0; k < 8; ++k) {
        int e = tid + k * 512;
        int jh = e >> 11, rem = e & 2047, c = rem >> 5, j2 = rem & 31;
        int jt2 = jh * 32 + j2;
        float ch = 0.f;
#pragma unroll
        for (int d = 0; d < 64; ++d) ch += As2[c * 64 + d] * xs2[d * 65 + jt2];
        float xc = xs2[c * 65 + jt2];
        out[(size_t)(b * 64 + c) * 4096 + n0 + jt2] = pgv * sums[k] + cgv * ch + 2.0f * xc;
    }
}

extern "C" void kernel_launch(void* const* d_in, const int* in_sizes, int n_in,
                              void* d_out, int out_size, void* d_ws, size_t ws_size,
                              hipStream_t stream) {
    const float* x  = (const float*)d_in[0];
    const float* wq = (const float*)d_in[1];
    const float* bq = (const float*)d_in[2];
    const float* wk = (const float*)d_in[3];
    const float* bk = (const float*)d_in[4];
    const float* wv = (const float*)d_in[5];
    const float* bv = (const float*)d_in[6];
    const float* pg = (const float*)d_in[7];
    const float* cg = (const float*)d_in[8];
    float* out = (float*)d_out;

    if (ws_size < (size_t)WS_FLOATS * sizeof(float)) return;
    float* ws = (float*)d_ws;
    float* Gp64 = ws + OFF_POS;
    unsigned short* Q2  = (unsigned short*)(ws + OFF_Q2);
    unsigned short* K2  = (unsigned short*)(ws + OFF_K2);
    unsigned short* V2  = (unsigned short*)(ws + OFF_V2);
    unsigned short* VLO = (unsigned short*)(ws + OFF_VLO);
    unsigned short* wfb = (unsigned short*)(ws + OFF_WT);
    float* invl = ws + OFF_INVL;
    float* A    = ws + OFF_A;

    k_wtrans<<<432, 256, 0, stream>>>(wq, wk, wv, wfb);
    k_conv<<<dim3(128, 4), 384, 0, stream>>>(x, wfb, bq, bk, bv, Q2, K2, V2, VLO);
    k_gram<<<dim3(64, 4), 256, 0, stream>>>(x, Gp64);
    k_asm<<<256, 64, 0, stream>>>(Gp64, A);
    k_pass1<<<256, 512, 0, stream>>>(Q2, K2, invl);
    k_vnorm<<<512, 256, 0, stream>>>(V2, VLO, invl);
    k_pass2<<<256, 512, 0, stream>>>(Q2, K2, V2, x, A, pg, cg, out);
}

// Round 10
// 124.818 us; speedup vs baseline: 2.0446x; 1.0261x over previous
//
#include <hip/hip_runtime.h>

// Problem constants: B=4, C=64, H=W=64, N=4096
// Workspace layout (float offsets) — 4,747,264 floats (same proven footprint).
//  [0, 65536): Gram partials Gp (4 kp x 4 b x 4096)
//  [65536, 589824): XV2 = bf16(x) in V-frag layout (1,048,576 shorts)
#define OFF_Q2    1048576u
#define OFF_K2    2097152u
#define OFF_V2    3145728u    // V hi-only frags: 1,048,576 shorts = 524,288 floats
#define OFF_X2    3670016u    // bf16(x) Q-layout frags: 1,048,576 shorts
#define OFF_WT    4194304u    // W frags split-bf16: 221,184 shorts
#define OFF_INVL  4452352u
#define OFF_A     4730880u    // A2 frags: 16,384 shorts = 8,192 floats
#define WS_FLOATS 4747264u

typedef short s8v __attribute__((ext_vector_type(8)));
typedef float f16v __attribute__((ext_vector_type(16)));

#define MFMA32(a, b, c) __builtin_amdgcn_mfma_f32_32x32x16_bf16((a), (b), (c), 0, 0, 0)

__device__ __forceinline__ unsigned short bf16_rne(float f) {
    union { float f; unsigned int u; } v; v.f = f;
    unsigned int r = v.u + 0x7FFFu + ((v.u >> 16) & 1u);
    return (unsigned short)(r >> 16);
}
__device__ __forceinline__ float bf2f(unsigned short h) {
    union { unsigned int u; float f; } t; t.u = ((unsigned int)h) << 16;
    return t.f;
}
__device__ __forceinline__ void split2(float f, unsigned short& h, unsigned short& l) {
    unsigned short hh = bf16_rne(f);
    h = hh;
    l = bf16_rne(f - bf2f(hh));
}
// packed f32x2 -> bf16x2 (RNE), lo in low half
__device__ __forceinline__ unsigned int cvtpk(float lo, float hi) {
    unsigned int r;
    asm("v_cvt_pk_bf16_f32 %0, %1, %2" : "=v"(r) : "v"(lo), "v"(hi));
    return r;
}
// v_permlane32_swap_b32: a.high32lanes <-> b.low32lanes (both regs updated)
__device__ __forceinline__ void pl32swap(unsigned int& a, unsigned int& b) {
    asm volatile("v_permlane32_swap_b32 %0, %1" : "+v"(a), "+v"(b));
}
__device__ __forceinline__ s8v mk8(unsigned int w0, unsigned int w1,
                                   unsigned int w2, unsigned int w3) {
    union { unsigned int u[4]; s8v v; } t;
    t.u[0] = w0; t.u[1] = w1; t.u[2] = w2; t.u[3] = w3;
    return t.v;
}
__device__ __forceinline__ f16v zero16() {
    f16v z;
#pragma unroll
    for (int i = 0; i < 16; ++i) z[i] = 0.0f;
    return z;
}

// Fragment layouts (32x32x16; mfma(A,B): D[lane&31]=B's lane, D[regs]=A's lane):
//  Q2/K2: idx = (((b*128 + nch)*4 + kst)*2 + hl)*512 + lane*8 + e
//         holds X[n = nch*32 + (lane&31)][c = kst*16 + (lane>>5)*8 + e]
//  V2/XV2: idx = (((b*128 + ich)*2 + ksub)*2 + cb)*512 + lane*8 + e
//         holds V[c = cb*32 + (lane&31)][n = ich*32 + ksub*16 + (lane>>5)*8 + e]
//  X2:    Q2-pattern, hi only: idx = ((b*128 + nch)*4 + kst)*512 + lane*8 + e
//  A2:    idx = ((b*2 + cb)*4 + kst)*512 + lane*8 + e
//         holds A[c = cb*32 + (lane&31)][d = kst*16 + (lane>>5)*8 + e]

// ---------------- weight fragment build (split-bf16)
__global__ void k_wtrans(const float* __restrict__ wq, const float* __restrict__ wk,
                         const float* __restrict__ wv, unsigned short* __restrict__ wf) {
    int t = blockIdx.x * 256 + threadIdx.x;   // < 110592
    int f = t >> 9, pos = t & 511;
    int lane = pos >> 3, e = pos & 7;
    int oc = f & 1, kst = (f >> 1) & 3;
    int ct = f >> 3;                           // conv*9 + tap
    int tap = ct % 9, conv = ct / 9;
    int o = oc * 32 + (lane & 31);
    int ci = kst * 16 + (lane >> 5) * 8 + e;
    const float* w = (conv == 0) ? wq : (conv == 1) ? wk : wv;
    float v = w[(o * 64 + ci) * 9 + tap];
    unsigned short hh, ll;
    split2(v, hh, ll);
    wf[(f * 2 + 0) * 512 + pos] = hh;
    wf[(f * 2 + 1) * 512 + pos] = ll;
}

// ---------------- pack x into bf16 fragments: X2 (Q-layout) + XV2 (V-layout)
__global__ __launch_bounds__(256) void k_xpack(const float* __restrict__ x,
                                               unsigned short* __restrict__ X2,
                                               unsigned short* __restrict__ XV2) {
    int gid = blockIdx.x * 256 + threadIdx.x;   // < 262144
    int b = gid >> 16;
    int c = (gid >> 10) & 63;
    int n4 = (gid & 1023) * 4;
    float4 v = *(const float4*)(x + (size_t)(b * 64 + c) * 4096 + n4);
    unsigned short hv[4] = {bf16_rne(v.x), bf16_rne(v.y), bf16_rne(v.z), bf16_rne(v.w)};
    // X2 (lane = n, k = c)
    int kst = c >> 4, e = c & 7, hb = (c >> 3) & 1;
#pragma unroll
    for (int u = 0; u < 4; ++u) {
        int n = n4 + u;
        int nch = n >> 5, lane = (n & 31) + 32 * hb;
        X2[(size_t)((b * 128 + nch) * 4 + kst) * 512 + lane * 8 + e] = hv[u];
    }
    // XV2 (lane = c, k = n): 4 consecutive shorts
    int ich = n4 >> 5, ksub = (n4 >> 4) & 1, cb = c >> 5;
    int lane2 = (c & 31) + 32 * ((n4 >> 3) & 1);
    size_t xi = (size_t)(((b * 128 + ich) * 2 + ksub) * 2 + cb) * 512 + lane2 * 8 + (n4 & 7);
    unsigned long long w = (unsigned long long)hv[0]
                         | ((unsigned long long)hv[1] << 16)
                         | ((unsigned long long)hv[2] << 32)
                         | ((unsigned long long)hv[3] << 48);
    *(unsigned long long*)(XV2 + xi) = w;
}

// ---------------- MFMA 3x3 conv: block = (32-n half-row, b); 6 waves = (conv, ohalf).
__global__ __launch_bounds__(384) void k_conv(
        const float* __restrict__ x, const unsigned short* __restrict__ wf,
        const float* __restrict__ bq, const float* __restrict__ bk, const float* __restrict__ bv,
        unsigned short* __restrict__ Q2, unsigned short* __restrict__ K2,
        unsigned short* __restrict__ V2) {
    int nb = blockIdx.x;                 // 0..127 (n-block of 32)
    int b = blockIdx.y;
    int h = nb >> 1, w0 = (nb & 1) * 32;

    __shared__ unsigned short xwh[6528];  // [dy 3][W 34][c 64], XOR-swizzled
    __shared__ unsigned short xwl[6528];

    int tid = threadIdx.x;
    for (int idx = tid; idx < 6528; idx += 384) {
        int W = idx % 34;
        int c = (idx / 34) & 63;
        int dy = idx / (34 * 64);
        int hs = h + dy - 1, wi = w0 + W - 1;
        float v = 0.0f;
        if (hs >= 0 && hs < 64 && wi >= 0 && wi < 64)
            v = x[((b * 64 + c) * 64 + hs) * 64 + wi];
        unsigned short hh_, ll_;
        split2(v, hh_, ll_);
        int row = dy * 34 + W;
        int byt = row * 128 + c * 2;
        int swz = byt ^ ((row & 7) << 4);
        *(unsigned short*)((char*)xwh + swz) = hh_;
        *(unsigned short*)((char*)xwl + swz) = ll_;
    }
    __syncthreads();

    int lane = tid & 63, wv = tid >> 6;   // 6 waves
    int conv = wv >> 1, oc = wv & 1;
    int hh = lane >> 5, l31 = lane & 31;

    const float* bias = (conv == 0) ? bq : (conv == 1) ? bk : bv;
    f16v D;
    if (conv < 2) {
#pragma unroll
        for (int r = 0; r < 16; ++r)
            D[r] = bias[oc * 32 + (r & 3) + 8 * (r >> 2) + 4 * hh];
    } else {
        float bvv = bias[oc * 32 + l31];
#pragma unroll
        for (int r = 0; r < 16; ++r) D[r] = bvv;
    }

#pragma unroll
    for (int tap = 0; tap < 9; ++tap) {
        int dy = tap / 3, dx = tap % 3;
#pragma unroll
        for (int kst = 0; kst < 4; ++kst) {
            int f = ((conv * 9 + tap) * 4 + kst) * 2 + oc;
            s8v Wh = *(const s8v*)(wf + (f * 2 + 0) * 512 + lane * 8);
            s8v Wl = *(const s8v*)(wf + (f * 2 + 1) * 512 + lane * 8);
            int row = dy * 34 + dx + l31;
            int byt = row * 128 + kst * 32 + hh * 16;
            int swz = byt ^ ((row & 7) << 4);
            s8v Xh = *(const s8v*)((const char*)xwh + swz);
            s8v Xl = *(const s8v*)((const char*)xwl + swz);
            if (conv < 2) {
                D = MFMA32(Wh, Xh, D);
                D = MFMA32(Wh, Xl, D);
                D = MFMA32(Wl, Xh, D);
            } else {
                D = MFMA32(Xh, Wh, D);
                D = MFMA32(Xl, Wh, D);
                D = MFMA32(Xh, Wl, D);
            }
        }
    }

    if (conv < 2) {
        // split-bf16 fragments for Q/K (hi + lo)
        unsigned short sh[16], sl[16];
#pragma unroll
        for (int r = 0; r < 16; ++r) split2(D[r], sh[r], sl[r]);
        unsigned int ah0 = sh[0] | ((unsigned int)sh[1] << 16), ah1 = sh[2] | ((unsigned int)sh[3] << 16);
        unsigned int ah2 = sh[4] | ((unsigned int)sh[5] << 16), ah3 = sh[6] | ((unsigned int)sh[7] << 16);
        pl32swap(ah0, ah2); pl32swap(ah1, ah3);
        s8v F0h = mk8(ah0, ah1, ah2, ah3);
        unsigned int al0 = sl[0] | ((unsigned int)sl[1] << 16), al1 = sl[2] | ((unsigned int)sl[3] << 16);
        unsigned int al2 = sl[4] | ((unsigned int)sl[5] << 16), al3 = sl[6] | ((unsigned int)sl[7] << 16);
        pl32swap(al0, al2); pl32swap(al1, al3);
        s8v F0l = mk8(al0, al1, al2, al3);
        unsigned int bh0 = sh[8] | ((unsigned int)sh[9] << 16), bh1 = sh[10] | ((unsigned int)sh[11] << 16);
        unsigned int bh2 = sh[12] | ((unsigned int)sh[13] << 16), bh3 = sh[14] | ((unsigned int)sh[15] << 16);
        pl32swap(bh0, bh2); pl32swap(bh1, bh3);
        s8v F1h = mk8(bh0, bh1, bh2, bh3);
        unsigned int bl0 = sl[8] | ((unsigned int)sl[9] << 16), bl1 = sl[10] | ((unsigned int)sl[11] << 16);
        unsigned int bl2 = sl[12] | ((unsigned int)sl[13] << 16), bl3 = sl[14] | ((unsigned int)sl[15] << 16);
        pl32swap(bl0, bl2); pl32swap(bl1, bl3);
        s8v F1l = mk8(bl0, bl1, bl2, bl3);
        unsigned short* dst = (conv == 0) ? Q2 : K2;
        size_t b0 = (size_t)(((b * 128 + nb) * 4 + oc * 2 + 0) * 2) * 512 + lane * 8;
        size_t b1 = (size_t)(((b * 128 + nb) * 4 + oc * 2 + 1) * 2) * 512 + lane * 8;
        *(s8v*)(dst + b0) = F0h;
        *(s8v*)(dst + b0 + 512) = F0l;
        *(s8v*)(dst + b1) = F1h;
        *(s8v*)(dst + b1 + 512) = F1l;
    } else {
        // V: hi-only fragments
        unsigned int a0 = cvtpk(D[0], D[1]),  a1 = cvtpk(D[2], D[3]);
        unsigned int a2 = cvtpk(D[4], D[5]),  a3 = cvtpk(D[6], D[7]);
        pl32swap(a0, a2); pl32swap(a1, a3);
        s8v F0h = mk8(a0, a1, a2, a3);
        unsigned int b0w = cvtpk(D[8], D[9]),  b1w = cvtpk(D[10], D[11]);
        unsigned int b2w = cvtpk(D[12], D[13]), b3w = cvtpk(D[14], D[15]);
        pl32swap(b0w, b2w); pl32swap(b1w, b3w);
        s8v F1h = mk8(b0w, b1w, b2w, b3w);
        size_t v0 = (size_t)(((b * 128 + nb) * 2 + 0) * 2 + oc) * 512 + lane * 8;
        size_t v1 = (size_t)(((b * 128 + nb) * 2 + 1) * 2 + oc) * 512 + lane * 8;
        *(s8v*)(V2 + v0) = F0h;
        *(s8v*)(V2 + v1) = F1h;
    }
}

// ---------------- channel Gram via MFMA: grid (4 kp, 4 b), 4 waves = (cb1,cb2)
__global__ __launch_bounds__(256) void k_gram(const unsigned short* __restrict__ XV2,
                                              float* __restrict__ Gp) {
    int kp = blockIdx.x, b = blockIdx.y;
    int tid = threadIdx.x, lane = tid & 63, wv = tid >> 6;
    int cb1 = wv & 1, cb2 = wv >> 1;
    f16v G = zero16();
#pragma unroll 1
    for (int t = 0; t < 32; ++t) {
        int ich = kp * 32 + t;
        const unsigned short* base = XV2 + (size_t)(b * 128 + ich) * 2048 + lane * 8;
        s8v a0 = *(const s8v*)(base + (0 * 2 + cb1) * 512);
        s8v b0 = *(const s8v*)(base + (0 * 2 + cb2) * 512);
        s8v a1 = *(const s8v*)(base + (1 * 2 + cb1) * 512);
        s8v b1 = *(const s8v*)(base + (1 * 2 + cb2) * 512);
        G = MFMA32(a0, b0, G);
        G = MFMA32(a1, b1, G);
    }
    int hh = lane >> 5, l31 = lane & 31;
#pragma unroll
    for (int r = 0; r < 16; ++r) {
        int cc = cb1 * 32 + (r & 3) + 8 * (r >> 2) + 4 * hh;   // A's lane -> regs
        int dd = cb2 * 32 + l31;                               // B's lane -> lane
        Gp[(size_t)(kp * 4 + b) * 4096 + cc * 64 + dd] = G[r];
    }
}

// ---------------- channel softmax rows -> A2 bf16 fragments
__global__ void k_asm(const float* __restrict__ Gp, unsigned short* __restrict__ A2) {
    int row = blockIdx.x;      // b*64 + c
    int d = threadIdx.x;
    int b = row >> 6, c = row & 63;
    float g = 0.0f;
#pragma unroll
    for (int p = 0; p < 4; ++p) g += Gp[(size_t)(p * 4 + b) * 4096 + c * 64 + d];
    float mx = g;
    for (int off = 32; off >= 1; off >>= 1) mx = fmaxf(mx, __shfl_xor(mx, off, 64));
    float e = __expf(g - mx);
    float s = e;
    for (int off = 32; off >= 1; off >>= 1) s += __shfl_xor(s, off, 64);
    float a = e / s;
    int cb = c >> 5, kst = d >> 4;
    int lane2 = (c & 31) + 32 * ((d >> 3) & 1);
    A2[(size_t)((b * 2 + cb) * 4 + kst) * 512 + lane2 * 8 + (d & 7)] = bf16_rne(a);
}

// ---------------- pass1: invl_i = 1/sum_j exp(s_ij). S^T = mfma32(K, Q).
// grid 512 = (b x 128 ich); block 512 (8 waves = 8 j-parts of 16 jch).
__global__ __launch_bounds__(512) void k_pass1(
        const unsigned short* __restrict__ Q2, const unsigned short* __restrict__ K2,
        float* __restrict__ invl) {
    int flat = blockIdx.x;
    int xcd = flat & 7;
    int b = xcd >> 1;
    int ich = (xcd & 1) * 64 + (flat >> 3);   // 0..127
    int tid = threadIdx.x, lane = tid & 63, wv = tid >> 6;

    __shared__ float lsum[8][32];

    const unsigned short* qp = Q2 + (size_t)(b * 128 + ich) * 4096 + lane * 8;
    s8v qf0 = *(const s8v*)(qp);
    s8v qf1 = *(const s8v*)(qp + 512);
    s8v qf2 = *(const s8v*)(qp + 1024);
    s8v qf3 = *(const s8v*)(qp + 1536);
    s8v qf4 = *(const s8v*)(qp + 2048);
    s8v qf5 = *(const s8v*)(qp + 2560);
    s8v qf6 = *(const s8v*)(qp + 3072);
    s8v qf7 = *(const s8v*)(qp + 3584);

    float la0 = 0.f, la1 = 0.f;
#pragma unroll 1
    for (int t = 0; t < 16; ++t) {
        int jch = wv * 16 + t;
        const unsigned short* kp = K2 + (size_t)(b * 128 + jch) * 4096 + lane * 8;
        s8v kf0 = *(const s8v*)(kp);
        s8v kf1 = *(const s8v*)(kp + 512);
        s8v kf2 = *(const s8v*)(kp + 1024);
        s8v kf3 = *(const s8v*)(kp + 1536);
        s8v kf4 = *(const s8v*)(kp + 2048);
        s8v kf5 = *(const s8v*)(kp + 2560);
        s8v kf6 = *(const s8v*)(kp + 3072);
        s8v kf7 = *(const s8v*)(kp + 3584);
        f16v Sa = zero16(), Sb = zero16();
        Sa = MFMA32(kf0, qf0, Sa);
        Sa = MFMA32(kf0, qf1, Sa);
        Sa = MFMA32(kf1, qf0, Sa);
        Sa = MFMA32(kf2, qf2, Sa);
        Sa = MFMA32(kf2, qf3, Sa);
        Sa = MFMA32(kf3, qf2, Sa);
        Sb = MFMA32(kf4, qf4, Sb);
        Sb = MFMA32(kf4, qf5, Sb);
        Sb = MFMA32(kf5, qf4, Sb);
        Sb = MFMA32(kf6, qf6, Sb);
        Sb = MFMA32(kf6, qf7, Sb);
        Sb = MFMA32(kf7, qf6, Sb);
#pragma unroll
        for (int r = 0; r < 8; ++r) la0 += __expf(Sa[r] + Sb[r]);
#pragma unroll
        for (int r = 8; r < 16; ++r) la1 += __expf(Sa[r] + Sb[r]);
    }
    float lacc = la0 + la1;
    lacc += __shfl_xor(lacc, 32);
    if (lane < 32) lsum[wv][lane] = lacc;
    __syncthreads();
    if (tid < 32) {
        float s = 0.f;
#pragma unroll
        for (int p = 0; p < 8; ++p) s += lsum[p][tid];
        invl[b * 4096 + ich * 32 + tid] = 1.0f / s;
    }
}

// ---------------- fold invl into V (hi-only, in place)
__global__ __launch_bounds__(256) void k_vnorm(
        unsigned short* __restrict__ V2, const float* __restrict__ invl) {
    int u = blockIdx.x * 256 + threadIdx.x;      // < 131072 16B-segs
    int lane = u & 63, ksub = (u >> 7) & 1;
    int ich = (u >> 8) & 127, b = u >> 15;
    int n0 = ich * 32 + ksub * 16 + (lane >> 5) * 8;
    size_t base = (size_t)u * 8;
    s8v vh = *(s8v*)(V2 + base);
    float4 iv0 = *(const float4*)(invl + b * 4096 + n0);
    float4 iv1 = *(const float4*)(invl + b * 4096 + n0 + 4);
    float ivv[8] = {iv0.x, iv0.y, iv0.z, iv0.w, iv1.x, iv1.y, iv1.z, iv1.w};
    s8v o;
#pragma unroll
    for (int e = 0; e < 8; ++e)
        o[e] = (short)bf16_rne(bf2f((unsigned short)vh[e]) * ivv[e]);
    *(s8v*)(V2 + base) = o;
}

// ---------------- pass2 + fused final. grid 512 = (b x 128 jt); block 512
// (8 waves = 8 i-parts of 16). Barrier-free flash loop; in-register P via
// cvt_pk + permlane; epilogue: MFMA chan apply + fp32 residual.
__global__ __launch_bounds__(512) void k_pass2(
        const unsigned short* __restrict__ Q2, const unsigned short* __restrict__ K2,
        const unsigned short* __restrict__ V2, const unsigned short* __restrict__ X2,
        const unsigned short* __restrict__ A2, const float* __restrict__ x,
        const float* __restrict__ pg, const float* __restrict__ cg,
        float* __restrict__ out) {
    int flat = blockIdx.x;
    int xcd = flat & 7;
    int b = xcd >> 1;
    int jt = (xcd & 1) * 64 + (flat >> 3);   // 0..127
    int tid = threadIdx.x, lane = tid & 63, wv = tid >> 6;

    __shared__ float rlds[8][64][32];        // 64 KB; reused in epilogue

    const unsigned short* kp = K2 + (size_t)(b * 128 + jt) * 4096 + lane * 8;
    s8v kf0 = *(const s8v*)(kp);
    s8v kf1 = *(const s8v*)(kp + 512);
    s8v kf2 = *(const s8v*)(kp + 1024);
    s8v kf3 = *(const s8v*)(kp + 1536);
    s8v kf4 = *(const s8v*)(kp + 2048);
    s8v kf5 = *(const s8v*)(kp + 2560);
    s8v kf6 = *(const s8v*)(kp + 3072);
    s8v kf7 = *(const s8v*)(kp + 3584);

    f16v O0 = zero16(), O1 = zero16();

#pragma unroll 1
    for (int t = 0; t < 16; ++t) {
        int ich = wv * 16 + t;
        const unsigned short* qp = Q2 + (size_t)(b * 128 + ich) * 4096 + lane * 8;
        s8v qf0 = *(const s8v*)(qp);
        s8v qf1 = *(const s8v*)(qp + 512);
        s8v qf2 = *(const s8v*)(qp + 1024);
        s8v qf3 = *(const s8v*)(qp + 1536);
        s8v qf4 = *(const s8v*)(qp + 2048);
        s8v qf5 = *(const s8v*)(qp + 2560);
        s8v qf6 = *(const s8v*)(qp + 3072);
        s8v qf7 = *(const s8v*)(qp + 3584);
        const unsigned short* vp = V2 + (size_t)(b * 128 + ich) * 2048 + lane * 8;
        s8v vA = *(const s8v*)(vp);
        s8v vB = *(const s8v*)(vp + 512);
        s8v vC = *(const s8v*)(vp + 1024);
        s8v vD = *(const s8v*)(vp + 1536);

        f16v Sa = zero16(), Sb = zero16();
        Sa = MFMA32(qf0, kf0, Sa);
        Sa = MFMA32(qf0, kf1, Sa);
        Sa = MFMA32(qf1, kf0, Sa);
        Sa = MFMA32(qf2, kf2, Sa);
        Sa = MFMA32(qf2, kf3, Sa);
        Sa = MFMA32(qf3, kf2, Sa);
        Sb = MFMA32(qf4, kf4, Sb);
        Sb = MFMA32(qf4, kf5, Sb);
        Sb = MFMA32(qf5, kf4, Sb);
        Sb = MFMA32(qf6, kf6, Sb);
        Sb = MFMA32(qf6, kf7, Sb);
        Sb = MFMA32(qf7, kf6, Sb);

        float p[16];
#pragma unroll
        for (int r = 0; r < 16; ++r) p[r] = __expf(Sa[r] + Sb[r]);

        unsigned int a0 = cvtpk(p[0], p[1]),  a1 = cvtpk(p[2], p[3]);
        unsigned int a2 = cvtpk(p[4], p[5]),  a3 = cvtpk(p[6], p[7]);
        pl32swap(a0, a2);
        pl32swap(a1, a3);
        s8v P0 = mk8(a0, a1, a2, a3);
        unsigned int b0 = cvtpk(p[8], p[9]),  b1 = cvtpk(p[10], p[11]);
        unsigned int b2 = cvtpk(p[12], p[13]), b3 = cvtpk(p[14], p[15]);
        pl32swap(b0, b2);
        pl32swap(b1, b3);
        s8v P1 = mk8(b0, b1, b2, b3);

        O0 = MFMA32(vA, P0, O0);
        O0 = MFMA32(vC, P1, O0);
        O1 = MFMA32(vB, P0, O1);
        O1 = MFMA32(vD, P1, O1);
    }

    int hh = lane >> 5, jj = lane & 31;
#pragma unroll
    for (int r = 0; r < 16; ++r) {
        int c = (r & 3) + 8 * (r >> 2) + 4 * hh;
        rlds[wv][c][jj] = O0[r];
        rlds[wv][c + 32][jj] = O1[r];
    }
    __syncthreads();
    float sums[4];
#pragma unroll
    for (int k = 0; k < 4; ++k) {
        int el = tid + k * 512;
        int c = el >> 5, j2 = el & 31;
        float s = 0.f;
#pragma unroll
        for (int p = 0; p < 8; ++p) s += rlds[p][c][j2];
        sums[k] = s;
    }
    __syncthreads();                 // rlds free for reuse
    float* sb = &rlds[0][0][0];      // chan[64][33] at [0,2112); xres at [2112,4160)
    if (wv < 2) {
        int cb = wv;
        f16v Dc = zero16();
#pragma unroll
        for (int kst = 0; kst < 4; ++kst) {
            s8v af = *(const s8v*)(A2 + (size_t)((b * 2 + cb) * 4 + kst) * 512 + lane * 8);
            s8v xf = *(const s8v*)(X2 + (size_t)((b * 128 + jt) * 4 + kst) * 512 + lane * 8);
            Dc = MFMA32(af, xf, Dc);
        }
#pragma unroll
        for (int r = 0; r < 16; ++r) {
            int c = cb * 32 + (r & 3) + 8 * (r >> 2) + 4 * hh;   // A's lane -> regs
            sb[c * 33 + jj] = Dc[r];                             // B's lane (n) -> lane
        }
    }
#pragma unroll
    for (int k = 0; k < 4; ++k) {
        int el = tid + k * 512;
        int c = el >> 5, j2 = el & 31;
        sb[2112 + el] = x[(size_t)(b * 64 + c) * 4096 + jt * 32 + j2];
    }
    __syncthreads();
    float pgv = pg[0], cgv = cg[0];
#pragma unroll
    for (int k = 0; k < 4; ++k) {
        int el = tid + k * 512;
        int c = el >> 5, j2 = el & 31;
        out[(size_t)(b * 64 + c) * 4096 + jt * 32 + j2] =
            pgv * sums[k] + cgv * sb[c * 33 + j2] + 2.0f * sb[2112 + el];
    }
}

extern "C" void kernel_launch(void* const* d_in, const int* in_sizes, int n_in,
                              void* d_out, int out_size, void* d_ws, size_t ws_size,
                              hipStream_t stream) {
    const float* x  = (const float*)d_in[0];
    const float* wq = (const float*)d_in[1];
    const float* bq = (const float*)d_in[2];
    const float* wk = (const float*)d_in[3];
    const float* bk = (const float*)d_in[4];
    const float* wv = (const float*)d_in[5];
    const float* bv = (const float*)d_in[6];
    const float* pg = (const float*)d_in[7];
    const float* cg = (const float*)d_in[8];
    float* out = (float*)d_out;

    if (ws_size < (size_t)WS_FLOATS * sizeof(float)) return;
    float* ws = (float*)d_ws;
    float* Gp = ws;                                      // [0, 65536)
    unsigned short* XV2 = (unsigned short*)(ws + 65536); // 1,048,576 shorts
    unsigned short* Q2  = (unsigned short*)(ws + OFF_Q2);
    unsigned short* K2  = (unsigned short*)(ws + OFF_K2);
    unsigned short* V2  = (unsigned short*)(ws + OFF_V2);
    unsigned short* X2  = (unsigned short*)(ws + OFF_X2);
    unsigned short* wfb = (unsigned short*)(ws + OFF_WT);
    float* invl = ws + OFF_INVL;
    unsigned short* A2  = (unsigned short*)(ws + OFF_A);

    k_wtrans<<<432, 256, 0, stream>>>(wq, wk, wv, wfb);
    k_xpack<<<1024, 256, 0, stream>>>(x, X2, XV2);
    k_conv<<<dim3(128, 4), 384, 0, stream>>>(x, wfb, bq, bk, bv, Q2, K2, V2);
    k_gram<<<dim3(4, 4), 256, 0, stream>>>(XV2, Gp);
    k_asm<<<256, 64, 0, stream>>>(Gp, A2);
    k_pass1<<<512, 512, 0, stream>>>(Q2, K2, invl);
    k_vnorm<<<512, 256, 0, stream>>>(V2, invl);
    k_pass2<<<512, 512, 0, stream>>>(Q2, K2, V2, X2, A2, x, pg, cg, out);
}

// Round 11
// 119.993 us; speedup vs baseline: 2.1269x; 1.0402x over previous
//
#include <hip/hip_runtime.h>

// Problem constants: B=4, C=64, H=W=64, N=4096
// Workspace layout (float offsets) — 4,747,264 floats (same proven footprint).
//  [0, 65536): free
//  [65536, 589824): XV2 = bf16(x) in V-frag layout (1,048,576 shorts)
//  [589824, 851968): Gram partials Gp (16 kp x 4 b x 4096)
#define OFF_XV2   65536u
#define OFF_GP    589824u
#define OFF_Q2    1048576u
#define OFF_K2    2097152u
#define OFF_V2    3145728u    // V hi-only frags: 1,048,576 shorts
#define OFF_X2    3670016u    // bf16(x) Q-layout frags: 1,048,576 shorts
#define OFF_WT    4194304u    // W frags split-bf16: 221,184 shorts
#define OFF_INVL  4452352u
#define OFF_A     4730880u    // A2 frags: 16,384 shorts
#define WS_FLOATS 4747264u

typedef short s8v __attribute__((ext_vector_type(8)));
typedef float f16v __attribute__((ext_vector_type(16)));

#define MFMA32(a, b, c) __builtin_amdgcn_mfma_f32_32x32x16_bf16((a), (b), (c), 0, 0, 0)

__device__ __forceinline__ unsigned short bf16_rne(float f) {
    union { float f; unsigned int u; } v; v.f = f;
    unsigned int r = v.u + 0x7FFFu + ((v.u >> 16) & 1u);
    return (unsigned short)(r >> 16);
}
__device__ __forceinline__ float bf2f(unsigned short h) {
    union { unsigned int u; float f; } t; t.u = ((unsigned int)h) << 16;
    return t.f;
}
__device__ __forceinline__ void split2(float f, unsigned short& h, unsigned short& l) {
    unsigned short hh = bf16_rne(f);
    h = hh;
    l = bf16_rne(f - bf2f(hh));
}
// packed f32x2 -> bf16x2 (RNE), lo in low half
__device__ __forceinline__ unsigned int cvtpk(float lo, float hi) {
    unsigned int r;
    asm("v_cvt_pk_bf16_f32 %0, %1, %2" : "=v"(r) : "v"(lo), "v"(hi));
    return r;
}
// v_permlane32_swap_b32: a.high32lanes <-> b.low32lanes (both regs updated)
__device__ __forceinline__ void pl32swap(unsigned int& a, unsigned int& b) {
    asm volatile("v_permlane32_swap_b32 %0, %1" : "+v"(a), "+v"(b));
}
__device__ __forceinline__ s8v mk8(unsigned int w0, unsigned int w1,
                                   unsigned int w2, unsigned int w3) {
    union { unsigned int u[4]; s8v v; } t;
    t.u[0] = w0; t.u[1] = w1; t.u[2] = w2; t.u[3] = w3;
    return t.v;
}
__device__ __forceinline__ f16v zero16() {
    f16v z;
#pragma unroll
    for (int i = 0; i < 16; ++i) z[i] = 0.0f;
    return z;
}

// Fragment layouts (32x32x16; mfma(A,B): D[lane&31]=B's lane, D[regs]=A's lane):
//  Q2/K2: idx = (((b*128 + nch)*4 + kst)*2 + hl)*512 + lane*8 + e
//  V2/XV2: idx = (((b*128 + ich)*2 + ksub)*2 + cb)*512 + lane*8 + e
//  X2:    Q2-pattern hi only; A2: ((b*2+cb)*4+kst)*512 + lane*8 + e

// ---------------- weight fragment build (split-bf16)
__global__ void k_wtrans(const float* __restrict__ wq, const float* __restrict__ wk,
                         const float* __restrict__ wv, unsigned short* __restrict__ wf) {
    int t = blockIdx.x * 256 + threadIdx.x;   // < 110592
    int f = t >> 9, pos = t & 511;
    int lane = pos >> 3, e = pos & 7;
    int oc = f & 1, kst = (f >> 1) & 3;
    int ct = f >> 3;                           // conv*9 + tap
    int tap = ct % 9, conv = ct / 9;
    int o = oc * 32 + (lane & 31);
    int ci = kst * 16 + (lane >> 5) * 8 + e;
    const float* w = (conv == 0) ? wq : (conv == 1) ? wk : wv;
    float v = w[(o * 64 + ci) * 9 + tap];
    unsigned short hh, ll;
    split2(v, hh, ll);
    wf[(f * 2 + 0) * 512 + pos] = hh;
    wf[(f * 2 + 1) * 512 + pos] = ll;
}

// ---------------- pack x into bf16 fragments: X2 (Q-layout) + XV2 (V-layout)
__global__ __launch_bounds__(256) void k_xpack(const float* __restrict__ x,
                                               unsigned short* __restrict__ X2,
                                               unsigned short* __restrict__ XV2) {
    int gid = blockIdx.x * 256 + threadIdx.x;   // < 262144
    int b = gid >> 16;
    int c = (gid >> 10) & 63;
    int n4 = (gid & 1023) * 4;
    float4 v = *(const float4*)(x + (size_t)(b * 64 + c) * 4096 + n4);
    unsigned short hv[4] = {bf16_rne(v.x), bf16_rne(v.y), bf16_rne(v.z), bf16_rne(v.w)};
    int kst = c >> 4, e = c & 7, hb = (c >> 3) & 1;
#pragma unroll
    for (int u = 0; u < 4; ++u) {
        int n = n4 + u;
        int nch = n >> 5, lane = (n & 31) + 32 * hb;
        X2[(size_t)((b * 128 + nch) * 4 + kst) * 512 + lane * 8 + e] = hv[u];
    }
    int ich = n4 >> 5, ksub = (n4 >> 4) & 1, cb = c >> 5;
    int lane2 = (c & 31) + 32 * ((n4 >> 3) & 1);
    size_t xi = (size_t)(((b * 128 + ich) * 2 + ksub) * 2 + cb) * 512 + lane2 * 8 + (n4 & 7);
    unsigned long long w = (unsigned long long)hv[0]
                         | ((unsigned long long)hv[1] << 16)
                         | ((unsigned long long)hv[2] << 32)
                         | ((unsigned long long)hv[3] << 48);
    *(unsigned long long*)(XV2 + xi) = w;
}

// ---------------- MFMA 3x3 conv: block = (32-n half-row, b); 6 waves = (conv, ohalf).
__global__ __launch_bounds__(384) void k_conv(
        const float* __restrict__ x, const unsigned short* __restrict__ wf,
        const float* __restrict__ bq, const float* __restrict__ bk, const float* __restrict__ bv,
        unsigned short* __restrict__ Q2, unsigned short* __restrict__ K2,
        unsigned short* __restrict__ V2) {
    int nb = blockIdx.x;                 // 0..127 (n-block of 32)
    int b = blockIdx.y;
    int h = nb >> 1, w0 = (nb & 1) * 32;

    __shared__ unsigned short xwh[6528];  // [dy 3][W 34][c 64], XOR-swizzled
    __shared__ unsigned short xwl[6528];

    int tid = threadIdx.x;
    for (int idx = tid; idx < 6528; idx += 384) {
        int W = idx % 34;
        int c = (idx / 34) & 63;
        int dy = idx / (34 * 64);
        int hs = h + dy - 1, wi = w0 + W - 1;
        float v = 0.0f;
        if (hs >= 0 && hs < 64 && wi >= 0 && wi < 64)
            v = x[((b * 64 + c) * 64 + hs) * 64 + wi];
        unsigned short hh_, ll_;
        split2(v, hh_, ll_);
        int row = dy * 34 + W;
        int byt = row * 128 + c * 2;
        int swz = byt ^ ((row & 7) << 4);
        *(unsigned short*)((char*)xwh + swz) = hh_;
        *(unsigned short*)((char*)xwl + swz) = ll_;
    }
    __syncthreads();

    int lane = tid & 63, wv = tid >> 6;   // 6 waves
    int conv = wv >> 1, oc = wv & 1;
    int hh = lane >> 5, l31 = lane & 31;

    const float* bias = (conv == 0) ? bq : (conv == 1) ? bk : bv;
    f16v D;
    if (conv < 2) {
#pragma unroll
        for (int r = 0; r < 16; ++r)
            D[r] = bias[oc * 32 + (r & 3) + 8 * (r >> 2) + 4 * hh];
    } else {
        float bvv = bias[oc * 32 + l31];
#pragma unroll
        for (int r = 0; r < 16; ++r) D[r] = bvv;
    }

#pragma unroll
    for (int tap = 0; tap < 9; ++tap) {
        int dy = tap / 3, dx = tap % 3;
#pragma unroll
        for (int kst = 0; kst < 4; ++kst) {
            int f = ((conv * 9 + tap) * 4 + kst) * 2 + oc;
            s8v Wh = *(const s8v*)(wf + (f * 2 + 0) * 512 + lane * 8);
            s8v Wl = *(const s8v*)(wf + (f * 2 + 1) * 512 + lane * 8);
            int row = dy * 34 + dx + l31;
            int byt = row * 128 + kst * 32 + hh * 16;
            int swz = byt ^ ((row & 7) << 4);
            s8v Xh = *(const s8v*)((const char*)xwh + swz);
            s8v Xl = *(const s8v*)((const char*)xwl + swz);
            if (conv < 2) {
                D = MFMA32(Wh, Xh, D);
                D = MFMA32(Wh, Xl, D);
                D = MFMA32(Wl, Xh, D);
            } else {
                D = MFMA32(Xh, Wh, D);
                D = MFMA32(Xl, Wh, D);
                D = MFMA32(Xh, Wl, D);
            }
        }
    }

    if (conv < 2) {
        unsigned short sh[16], sl[16];
#pragma unroll
        for (int r = 0; r < 16; ++r) split2(D[r], sh[r], sl[r]);
        unsigned int ah0 = sh[0] | ((unsigned int)sh[1] << 16), ah1 = sh[2] | ((unsigned int)sh[3] << 16);
        unsigned int ah2 = sh[4] | ((unsigned int)sh[5] << 16), ah3 = sh[6] | ((unsigned int)sh[7] << 16);
        pl32swap(ah0, ah2); pl32swap(ah1, ah3);
        s8v F0h = mk8(ah0, ah1, ah2, ah3);
        unsigned int al0 = sl[0] | ((unsigned int)sl[1] << 16), al1 = sl[2] | ((unsigned int)sl[3] << 16);
        unsigned int al2 = sl[4] | ((unsigned int)sl[5] << 16), al3 = sl[6] | ((unsigned int)sl[7] << 16);
        pl32swap(al0, al2); pl32swap(al1, al3);
        s8v F0l = mk8(al0, al1, al2, al3);
        unsigned int bh0 = sh[8] | ((unsigned int)sh[9] << 16), bh1 = sh[10] | ((unsigned int)sh[11] << 16);
        unsigned int bh2 = sh[12] | ((unsigned int)sh[13] << 16), bh3 = sh[14] | ((unsigned int)sh[15] << 16);
        pl32swap(bh0, bh2); pl32swap(bh1, bh3);
        s8v F1h = mk8(bh0, bh1, bh2, bh3);
        unsigned int bl0 = sl[8] | ((unsigned int)sl[9] << 16), bl1 = sl[10] | ((unsigned int)sl[11] << 16);
        unsigned int bl2 = sl[12] | ((unsigned int)sl[13] << 16), bl3 = sl[14] | ((unsigned int)sl[15] << 16);
        pl32swap(bl0, bl2); pl32swap(bl1, bl3);
        s8v F1l = mk8(bl0, bl1, bl2, bl3);
        unsigned short* dst = (conv == 0) ? Q2 : K2;
        size_t b0 = (size_t)(((b * 128 + nb) * 4 + oc * 2 + 0) * 2) * 512 + lane * 8;
        size_t b1 = (size_t)(((b * 128 + nb) * 4 + oc * 2 + 1) * 2) * 512 + lane * 8;
        *(s8v*)(dst + b0) = F0h;
        *(s8v*)(dst + b0 + 512) = F0l;
        *(s8v*)(dst + b1) = F1h;
        *(s8v*)(dst + b1 + 512) = F1l;
    } else {
        unsigned int a0 = cvtpk(D[0], D[1]),  a1 = cvtpk(D[2], D[3]);
        unsigned int a2 = cvtpk(D[4], D[5]),  a3 = cvtpk(D[6], D[7]);
        pl32swap(a0, a2); pl32swap(a1, a3);
        s8v F0h = mk8(a0, a1, a2, a3);
        unsigned int b0w = cvtpk(D[8], D[9]),  b1w = cvtpk(D[10], D[11]);
        unsigned int b2w = cvtpk(D[12], D[13]), b3w = cvtpk(D[14], D[15]);
        pl32swap(b0w, b2w); pl32swap(b1w, b3w);
        s8v F1h = mk8(b0w, b1w, b2w, b3w);
        size_t v0 = (size_t)(((b * 128 + nb) * 2 + 0) * 2 + oc) * 512 + lane * 8;
        size_t v1 = (size_t)(((b * 128 + nb) * 2 + 1) * 2 + oc) * 512 + lane * 8;
        *(s8v*)(V2 + v0) = F0h;
        *(s8v*)(V2 + v1) = F1h;
    }
}

// ---------------- channel Gram via MFMA: grid (16 kp, 4 b), 4 waves = (cb1,cb2)
__global__ __launch_bounds__(256) void k_gram(const unsigned short* __restrict__ XV2,
                                              float* __restrict__ Gp) {
    int kp = blockIdx.x, b = blockIdx.y;
    int tid = threadIdx.x, lane = tid & 63, wv = tid >> 6;
    int cb1 = wv & 1, cb2 = wv >> 1;
    f16v G = zero16();
#pragma unroll
    for (int t = 0; t < 8; ++t) {
        int ich = kp * 8 + t;
        const unsigned short* base = XV2 + (size_t)(b * 128 + ich) * 2048 + lane * 8;
        s8v a0 = *(const s8v*)(base + (0 * 2 + cb1) * 512);
        s8v b0 = *(const s8v*)(base + (0 * 2 + cb2) * 512);
        s8v a1 = *(const s8v*)(base + (1 * 2 + cb1) * 512);
        s8v b1 = *(const s8v*)(base + (1 * 2 + cb2) * 512);
        G = MFMA32(a0, b0, G);
        G = MFMA32(a1, b1, G);
    }
    int hh = lane >> 5, l31 = lane & 31;
#pragma unroll
    for (int r = 0; r < 16; ++r) {
        int cc = cb1 * 32 + (r & 3) + 8 * (r >> 2) + 4 * hh;   // A's lane -> regs
        int dd = cb2 * 32 + l31;                               // B's lane -> lane
        Gp[(size_t)(kp * 4 + b) * 4096 + cc * 64 + dd] = G[r];
    }
}

// ---------------- channel softmax rows -> A2 bf16 fragments
__global__ void k_asm(const float* __restrict__ Gp, unsigned short* __restrict__ A2) {
    int row = blockIdx.x;      // b*64 + c
    int d = threadIdx.x;
    int b = row >> 6, c = row & 63;
    float g = 0.0f;
#pragma unroll
    for (int p = 0; p < 16; ++p) g += Gp[(size_t)(p * 4 + b) * 4096 + c * 64 + d];
    float mx = g;
    for (int off = 32; off >= 1; off >>= 1) mx = fmaxf(mx, __shfl_xor(mx, off, 64));
    float e = __expf(g - mx);
    float s = e;
    for (int off = 32; off >= 1; off >>= 1) s += __shfl_xor(s, off, 64);
    float a = e / s;
    int cb = c >> 5, kst = d >> 4;
    int lane2 = (c & 31) + 32 * ((d >> 3) & 1);
    A2[(size_t)((b * 2 + cb) * 4 + kst) * 512 + lane2 * 8 + (d & 7)] = bf16_rne(a);
}

// ---------------- pass1: invl_i = 1/sum_j exp(s_ij). S^T = mfma32(K, Q).
// grid 512 = (b x 128 ich); block 1024 (16 waves = 16 j-parts of 8 jch).
// 2 blocks/CU = 2048 threads/CU = full occupancy.
__global__ __launch_bounds__(1024) void k_pass1(
        const unsigned short* __restrict__ Q2, const unsigned short* __restrict__ K2,
        float* __restrict__ invl) {
    int flat = blockIdx.x;
    int xcd = flat & 7;
    int b = xcd >> 1;
    int ich = (xcd & 1) * 64 + (flat >> 3);   // 0..127
    int tid = threadIdx.x, lane = tid & 63, wv = tid >> 6;

    __shared__ float lsum[16][32];

    const unsigned short* qp = Q2 + (size_t)(b * 128 + ich) * 4096 + lane * 8;
    s8v qf0 = *(const s8v*)(qp);
    s8v qf1 = *(const s8v*)(qp + 512);
    s8v qf2 = *(const s8v*)(qp + 1024);
    s8v qf3 = *(const s8v*)(qp + 1536);
    s8v qf4 = *(const s8v*)(qp + 2048);
    s8v qf5 = *(const s8v*)(qp + 2560);
    s8v qf6 = *(const s8v*)(qp + 3072);
    s8v qf7 = *(const s8v*)(qp + 3584);

    float la0 = 0.f, la1 = 0.f;
#pragma unroll 1
    for (int t = 0; t < 8; ++t) {
        int jch = wv * 8 + t;
        const unsigned short* kp = K2 + (size_t)(b * 128 + jch) * 4096 + lane * 8;
        s8v kf0 = *(const s8v*)(kp);
        s8v kf1 = *(const s8v*)(kp + 512);
        s8v kf2 = *(const s8v*)(kp + 1024);
        s8v kf3 = *(const s8v*)(kp + 1536);
        s8v kf4 = *(const s8v*)(kp + 2048);
        s8v kf5 = *(const s8v*)(kp + 2560);
        s8v kf6 = *(const s8v*)(kp + 3072);
        s8v kf7 = *(const s8v*)(kp + 3584);
        f16v Sa = zero16(), Sb = zero16();
        Sa = MFMA32(kf0, qf0, Sa);
        Sa = MFMA32(kf0, qf1, Sa);
        Sa = MFMA32(kf1, qf0, Sa);
        Sa = MFMA32(kf2, qf2, Sa);
        Sa = MFMA32(kf2, qf3, Sa);
        Sa = MFMA32(kf3, qf2, Sa);
        Sb = MFMA32(kf4, qf4, Sb);
        Sb = MFMA32(kf4, qf5, Sb);
        Sb = MFMA32(kf5, qf4, Sb);
        Sb = MFMA32(kf6, qf6, Sb);
        Sb = MFMA32(kf6, qf7, Sb);
        Sb = MFMA32(kf7, qf6, Sb);
#pragma unroll
        for (int r = 0; r < 8; ++r) la0 += __expf(Sa[r] + Sb[r]);
#pragma unroll
        for (int r = 8; r < 16; ++r) la1 += __expf(Sa[r] + Sb[r]);
    }
    float lacc = la0 + la1;
    lacc += __shfl_xor(lacc, 32);
    if (lane < 32) lsum[wv][lane] = lacc;
    __syncthreads();
    if (tid < 32) {
        float s = 0.f;
#pragma unroll
        for (int p = 0; p < 16; ++p) s += lsum[p][tid];
        invl[b * 4096 + ich * 32 + tid] = 1.0f / s;
    }
}

// ---------------- fold invl into V (hi-only, in place)
__global__ __launch_bounds__(256) void k_vnorm(
        unsigned short* __restrict__ V2, const float* __restrict__ invl) {
    int u = blockIdx.x * 256 + threadIdx.x;      // < 131072 16B-segs
    int lane = u & 63, ksub = (u >> 7) & 1;
    int ich = (u >> 8) & 127, b = u >> 15;
    int n0 = ich * 32 + ksub * 16 + (lane >> 5) * 8;
    size_t base = (size_t)u * 8;
    s8v vh = *(s8v*)(V2 + base);
    float4 iv0 = *(const float4*)(invl + b * 4096 + n0);
    float4 iv1 = *(const float4*)(invl + b * 4096 + n0 + 4);
    float ivv[8] = {iv0.x, iv0.y, iv0.z, iv0.w, iv1.x, iv1.y, iv1.z, iv1.w};
    s8v o;
#pragma unroll
    for (int e = 0; e < 8; ++e)
        o[e] = (short)bf16_rne(bf2f((unsigned short)vh[e]) * ivv[e]);
    *(s8v*)(V2 + base) = o;
}

// ---------------- pass2 + fused final. grid 512 = (b x 128 jt); block 512
// (8 waves = 8 i-parts of 16). Two-round reduction in 32KB LDS -> 4 blocks/CU.
__global__ __launch_bounds__(512) void k_pass2(
        const unsigned short* __restrict__ Q2, const unsigned short* __restrict__ K2,
        const unsigned short* __restrict__ V2, const unsigned short* __restrict__ X2,
        const unsigned short* __restrict__ A2, const float* __restrict__ x,
        const float* __restrict__ pg, const float* __restrict__ cg,
        float* __restrict__ out) {
    int flat = blockIdx.x;
    int xcd = flat & 7;
    int b = xcd >> 1;
    int jt = (xcd & 1) * 64 + (flat >> 3);   // 0..127
    int tid = threadIdx.x, lane = tid & 63, wv = tid >> 6;

    __shared__ float rlds[4][64][32];        // 32 KB; two-round reduce + epilogue reuse

    const unsigned short* kp = K2 + (size_t)(b * 128 + jt) * 4096 + lane * 8;
    s8v kf0 = *(const s8v*)(kp);
    s8v kf1 = *(const s8v*)(kp + 512);
    s8v kf2 = *(const s8v*)(kp + 1024);
    s8v kf3 = *(const s8v*)(kp + 1536);
    s8v kf4 = *(const s8v*)(kp + 2048);
    s8v kf5 = *(const s8v*)(kp + 2560);
    s8v kf6 = *(const s8v*)(kp + 3072);
    s8v kf7 = *(const s8v*)(kp + 3584);

    f16v O0 = zero16(), O1 = zero16();

#pragma unroll 1
    for (int t = 0; t < 16; ++t) {
        int ich = wv * 16 + t;
        const unsigned short* qp = Q2 + (size_t)(b * 128 + ich) * 4096 + lane * 8;
        s8v qf0 = *(const s8v*)(qp);
        s8v qf1 = *(const s8v*)(qp + 512);
        s8v qf2 = *(const s8v*)(qp + 1024);
        s8v qf3 = *(const s8v*)(qp + 1536);
        s8v qf4 = *(const s8v*)(qp + 2048);
        s8v qf5 = *(const s8v*)(qp + 2560);
        s8v qf6 = *(const s8v*)(qp + 3072);
        s8v qf7 = *(const s8v*)(qp + 3584);
        const unsigned short* vp = V2 + (size_t)(b * 128 + ich) * 2048 + lane * 8;
        s8v vA = *(const s8v*)(vp);
        s8v vB = *(const s8v*)(vp + 512);
        s8v vC = *(const s8v*)(vp + 1024);
        s8v vD = *(const s8v*)(vp + 1536);

        f16v Sa = zero16(), Sb = zero16();
        Sa = MFMA32(qf0, kf0, Sa);
        Sa = MFMA32(qf0, kf1, Sa);
        Sa = MFMA32(qf1, kf0, Sa);
        Sa = MFMA32(qf2, kf2, Sa);
        Sa = MFMA32(qf2, kf3, Sa);
        Sa = MFMA32(qf3, kf2, Sa);
        Sb = MFMA32(qf4, kf4, Sb);
        Sb = MFMA32(qf4, kf5, Sb);
        Sb = MFMA32(qf5, kf4, Sb);
        Sb = MFMA32(qf6, kf6, Sb);
        Sb = MFMA32(qf6, kf7, Sb);
        Sb = MFMA32(qf7, kf6, Sb);

        float p[16];
#pragma unroll
        for (int r = 0; r < 16; ++r) p[r] = __expf(Sa[r] + Sb[r]);

        unsigned int a0 = cvtpk(p[0], p[1]),  a1 = cvtpk(p[2], p[3]);
        unsigned int a2 = cvtpk(p[4], p[5]),  a3 = cvtpk(p[6], p[7]);
        pl32swap(a0, a2);
        pl32swap(a1, a3);
        s8v P0 = mk8(a0, a1, a2, a3);
        unsigned int b0 = cvtpk(p[8], p[9]),  b1 = cvtpk(p[10], p[11]);
        unsigned int b2 = cvtpk(p[12], p[13]), b3 = cvtpk(p[14], p[15]);
        pl32swap(b0, b2);
        pl32swap(b1, b3);
        s8v P1 = mk8(b0, b1, b2, b3);

        O0 = MFMA32(vA, P0, O0);
        O0 = MFMA32(vC, P1, O0);
        O1 = MFMA32(vB, P0, O1);
        O1 = MFMA32(vD, P1, O1);
    }

    int hh = lane >> 5, jj = lane & 31;
    // round 1: i-parts 0..3
    if (wv < 4) {
#pragma unroll
        for (int r = 0; r < 16; ++r) {
            int c = (r & 3) + 8 * (r >> 2) + 4 * hh;
            rlds[wv][c][jj] = O0[r];
            rlds[wv][c + 32][jj] = O1[r];
        }
    }
    __syncthreads();
    float sums[4];
#pragma unroll
    for (int k = 0; k < 4; ++k) {
        int el = tid + k * 512;
        int c = el >> 5, j2 = el & 31;
        sums[k] = ((rlds[0][c][j2] + rlds[1][c][j2]) + rlds[2][c][j2]) + rlds[3][c][j2];
    }
    __syncthreads();
    // round 2: i-parts 4..7
    if (wv >= 4) {
#pragma unroll
        for (int r = 0; r < 16; ++r) {
            int c = (r & 3) + 8 * (r >> 2) + 4 * hh;
            rlds[wv - 4][c][jj] = O0[r];
            rlds[wv - 4][c + 32][jj] = O1[r];
        }
    }
    __syncthreads();
#pragma unroll
    for (int k = 0; k < 4; ++k) {
        int el = tid + k * 512;
        int c = el >> 5, j2 = el & 31;
        sums[k] = ((sums[k] + rlds[0][c][j2]) + rlds[1][c][j2]) + rlds[2][c][j2];
        sums[k] += rlds[3][c][j2];
    }
    __syncthreads();                 // rlds free for epilogue reuse
    float* sb = &rlds[0][0][0];      // chan[64][33] at [0,2112); xres at [2112,4160)
    if (wv < 2) {
        int cb = wv;
        f16v Dc = zero16();
#pragma unroll
        for (int kst = 0; kst < 4; ++kst) {
            s8v af = *(const s8v*)(A2 + (size_t)((b * 2 + cb) * 4 + kst) * 512 + lane * 8);
            s8v xf = *(const s8v*)(X2 + (size_t)((b * 128 + jt) * 4 + kst) * 512 + lane * 8);
            Dc = MFMA32(af, xf, Dc);
        }
#pragma unroll
        for (int r = 0; r < 16; ++r) {
            int c = cb * 32 + (r & 3) + 8 * (r >> 2) + 4 * hh;   // A's lane -> regs
            sb[c * 33 + jj] = Dc[r];                             // B's lane (n) -> lane
        }
    }
#pragma unroll
    for (int k = 0; k < 4; ++k) {
        int el = tid + k * 512;
        int c = el >> 5, j2 = el & 31;
        sb[2112 + el] = x[(size_t)(b * 64 + c) * 4096 + jt * 32 + j2];
    }
    __syncthreads();
    float pgv = pg[0], cgv = cg[0];
#pragma unroll
    for (int k = 0; k < 4; ++k) {
        int el = tid + k * 512;
        int c = el >> 5, j2 = el & 31;
        out[(size_t)(b * 64 + c) * 4096 + jt * 32 + j2] =
            pgv * sums[k] + cgv * sb[c * 33 + j2] + 2.0f * sb[2112 + el];
    }
}

extern "C" void kernel_launch(void* const* d_in, const int* in_sizes, int n_in,
                              void* d_out, int out_size, void* d_ws, size_t ws_size,
                              hipStream_t stream) {
    const float* x  = (const float*)d_in[0];
    const float* wq = (const float*)d_in[1];
    const float* bq = (const float*)d_in[2];
    const float* wk = (const float*)d_in[3];
    const float* bk = (const float*)d_in[4];
    const float* wv = (const float*)d_in[5];
    const float* bv = (const float*)d_in[6];
    const float* pg = (const float*)d_in[7];
    const float* cg = (const float*)d_in[8];
    float* out = (float*)d_out;

    if (ws_size < (size_t)WS_FLOATS * sizeof(float)) return;
    float* ws = (float*)d_ws;
    unsigned short* XV2 = (unsigned short*)(ws + OFF_XV2);
    float* Gp = ws + OFF_GP;
    unsigned short* Q2  = (unsigned short*)(ws + OFF_Q2);
    unsigned short* K2  = (unsigned short*)(ws + OFF_K2);
    unsigned short* V2  = (unsigned short*)(ws + OFF_V2);
    unsigned short* X2  = (unsigned short*)(ws + OFF_X2);
    unsigned short* wfb = (unsigned short*)(ws + OFF_WT);
    float* invl = ws + OFF_INVL;
    unsigned short* A2  = (unsigned short*)(ws + OFF_A);

    k_wtrans<<<432, 256, 0, stream>>>(wq, wk, wv, wfb);
    k_xpack<<<1024, 256, 0, stream>>>(x, X2, XV2);
    k_conv<<<dim3(128, 4), 384, 0, stream>>>(x, wfb, bq, bk, bv, Q2, K2, V2);
    k_gram<<<dim3(16, 4), 256, 0, stream>>>(XV2, Gp);
    k_asm<<<256, 64, 0, stream>>>(Gp, A2);
    k_pass1<<<512, 1024, 0, stream>>>(Q2, K2, invl);
    k_vnorm<<<512, 256, 0, stream>>>(V2, invl);
    k_pass2<<<512, 512, 0, stream>>>(Q2, K2, V2, X2, A2, x, pg, cg, out);
}

// Round 12
// 110.214 us; speedup vs baseline: 2.3156x; 1.0887x over previous
//
#include <hip/hip_runtime.h>

// Problem constants: B=4, C=64, H=W=64, N=4096
// Workspace layout (float offsets) — 4,747,264 floats (same proven footprint).
#define OFF_XV2   65536u
#define OFF_GP    589824u
#define OFF_Q2    1048576u
#define OFF_K2    2097152u
#define OFF_V2    3145728u    // V hi-only frags: 1,048,576 shorts
#define OFF_X2    3670016u    // bf16(x) Q-layout frags: 1,048,576 shorts
#define OFF_WT    4194304u    // W frags split-bf16: 221,184 shorts
#define OFF_INVL  4452352u
#define OFF_A     4730880u    // A2 frags: 16,384 shorts
#define WS_FLOATS 4747264u

typedef short s8v __attribute__((ext_vector_type(8)));
typedef float f16v __attribute__((ext_vector_type(16)));

#define MFMA32(a, b, c) __builtin_amdgcn_mfma_f32_32x32x16_bf16((a), (b), (c), 0, 0, 0)

__device__ __forceinline__ unsigned short bf16_rne(float f) {
    union { float f; unsigned int u; } v; v.f = f;
    unsigned int r = v.u + 0x7FFFu + ((v.u >> 16) & 1u);
    return (unsigned short)(r >> 16);
}
__device__ __forceinline__ float bf2f(unsigned short h) {
    union { unsigned int u; float f; } t; t.u = ((unsigned int)h) << 16;
    return t.f;
}
__device__ __forceinline__ void split2(float f, unsigned short& h, unsigned short& l) {
    unsigned short hh = bf16_rne(f);
    h = hh;
    l = bf16_rne(f - bf2f(hh));
}
// packed f32x2 -> bf16x2 (RNE), lo in low half
__device__ __forceinline__ unsigned int cvtpk(float lo, float hi) {
    unsigned int r;
    asm("v_cvt_pk_bf16_f32 %0, %1, %2" : "=v"(r) : "v"(lo), "v"(hi));
    return r;
}
// v_permlane32_swap_b32: a.high32lanes <-> b.low32lanes (both regs updated)
__device__ __forceinline__ void pl32swap(unsigned int& a, unsigned int& b) {
    asm volatile("v_permlane32_swap_b32 %0, %1" : "+v"(a), "+v"(b));
}
__device__ __forceinline__ s8v mk8(unsigned int w0, unsigned int w1,
                                   unsigned int w2, unsigned int w3) {
    union { unsigned int u[4]; s8v v; } t;
    t.u[0] = w0; t.u[1] = w1; t.u[2] = w2; t.u[3] = w3;
    return t.v;
}
__device__ __forceinline__ f16v zero16() {
    f16v z;
#pragma unroll
    for (int i = 0; i < 16; ++i) z[i] = 0.0f;
    return z;
}

// Fragment layouts (32x32x16; mfma(A,B): D[lane&31]=B's lane, D[regs]=A's lane):
//  Q2/K2: idx = (((b*128 + nch)*4 + kst)*2 + hl)*512 + lane*8 + e
//  V2/XV2: idx = (((b*128 + ich)*2 + ksub)*2 + cb)*512 + lane*8 + e
//  X2:    Q2-pattern hi only; A2: ((b*2+cb)*4+kst)*512 + lane*8 + e

// ---------------- weight fragment build (split-bf16)
__global__ void k_wtrans(const float* __restrict__ wq, const float* __restrict__ wk,
                         const float* __restrict__ wv, unsigned short* __restrict__ wf) {
    int t = blockIdx.x * 256 + threadIdx.x;   // < 110592
    int f = t >> 9, pos = t & 511;
    int lane = pos >> 3, e = pos & 7;
    int oc = f & 1, kst = (f >> 1) & 3;
    int ct = f >> 3;                           // conv*9 + tap
    int tap = ct % 9, conv = ct / 9;
    int o = oc * 32 + (lane & 31);
    int ci = kst * 16 + (lane >> 5) * 8 + e;
    const float* w = (conv == 0) ? wq : (conv == 1) ? wk : wv;
    float v = w[(o * 64 + ci) * 9 + tap];
    unsigned short hh, ll;
    split2(v, hh, ll);
    wf[(f * 2 + 0) * 512 + pos] = hh;
    wf[(f * 2 + 1) * 512 + pos] = ll;
}

// ---------------- pack x into bf16 fragments: X2 (Q-layout) + XV2 (V-layout)
__global__ __launch_bounds__(256) void k_xpack(const float* __restrict__ x,
                                               unsigned short* __restrict__ X2,
                                               unsigned short* __restrict__ XV2) {
    int gid = blockIdx.x * 256 + threadIdx.x;   // < 262144
    int b = gid >> 16;
    int c = (gid >> 10) & 63;
    int n4 = (gid & 1023) * 4;
    float4 v = *(const float4*)(x + (size_t)(b * 64 + c) * 4096 + n4);
    unsigned short hv[4] = {bf16_rne(v.x), bf16_rne(v.y), bf16_rne(v.z), bf16_rne(v.w)};
    int kst = c >> 4, e = c & 7, hb = (c >> 3) & 1;
#pragma unroll
    for (int u = 0; u < 4; ++u) {
        int n = n4 + u;
        int nch = n >> 5, lane = (n & 31) + 32 * hb;
        X2[(size_t)((b * 128 + nch) * 4 + kst) * 512 + lane * 8 + e] = hv[u];
    }
    int ich = n4 >> 5, ksub = (n4 >> 4) & 1, cb = c >> 5;
    int lane2 = (c & 31) + 32 * ((n4 >> 3) & 1);
    size_t xi = (size_t)(((b * 128 + ich) * 2 + ksub) * 2 + cb) * 512 + lane2 * 8 + (n4 & 7);
    unsigned long long w = (unsigned long long)hv[0]
                         | ((unsigned long long)hv[1] << 16)
                         | ((unsigned long long)hv[2] << 32)
                         | ((unsigned long long)hv[3] << 48);
    *(unsigned long long*)(XV2 + xi) = w;
}

// ---------------- MFMA 3x3 conv (unchanged from r10)
__global__ __launch_bounds__(384) void k_conv(
        const float* __restrict__ x, const unsigned short* __restrict__ wf,
        const float* __restrict__ bq, const float* __restrict__ bk, const float* __restrict__ bv,
        unsigned short* __restrict__ Q2, unsigned short* __restrict__ K2,
        unsigned short* __restrict__ V2) {
    int nb = blockIdx.x;                 // 0..127 (n-block of 32)
    int b = blockIdx.y;
    int h = nb >> 1, w0 = (nb & 1) * 32;

    __shared__ unsigned short xwh[6528];  // [dy 3][W 34][c 64], XOR-swizzled
    __shared__ unsigned short xwl[6528];

    int tid = threadIdx.x;
    for (int idx = tid; idx < 6528; idx += 384) {
        int W = idx % 34;
        int c = (idx / 34) & 63;
        int dy = idx / (34 * 64);
        int hs = h + dy - 1, wi = w0 + W - 1;
        float v = 0.0f;
        if (hs >= 0 && hs < 64 && wi >= 0 && wi < 64)
            v = x[((b * 64 + c) * 64 + hs) * 64 + wi];
        unsigned short hh_, ll_;
        split2(v, hh_, ll_);
        int row = dy * 34 + W;
        int byt = row * 128 + c * 2;
        int swz = byt ^ ((row & 7) << 4);
        *(unsigned short*)((char*)xwh + swz) = hh_;
        *(unsigned short*)((char*)xwl + swz) = ll_;
    }
    __syncthreads();

    int lane = tid & 63, wv = tid >> 6;   // 6 waves
    int conv = wv >> 1, oc = wv & 1;
    int hh = lane >> 5, l31 = lane & 31;

    const float* bias = (conv == 0) ? bq : (conv == 1) ? bk : bv;
    f16v D;
    if (conv < 2) {
#pragma unroll
        for (int r = 0; r < 16; ++r)
            D[r] = bias[oc * 32 + (r & 3) + 8 * (r >> 2) + 4 * hh];
    } else {
        float bvv = bias[oc * 32 + l31];
#pragma unroll
        for (int r = 0; r < 16; ++r) D[r] = bvv;
    }

#pragma unroll
    for (int tap = 0; tap < 9; ++tap) {
        int dy = tap / 3, dx = tap % 3;
#pragma unroll
        for (int kst = 0; kst < 4; ++kst) {
            int f = ((conv * 9 + tap) * 4 + kst) * 2 + oc;
            s8v Wh = *(const s8v*)(wf + (f * 2 + 0) * 512 + lane * 8);
            s8v Wl = *(const s8v*)(wf + (f * 2 + 1) * 512 + lane * 8);
            int row = dy * 34 + dx + l31;
            int byt = row * 128 + kst * 32 + hh * 16;
            int swz = byt ^ ((row & 7) << 4);
            s8v Xh = *(const s8v*)((const char*)xwh + swz);
            s8v Xl = *(const s8v*)((const char*)xwl + swz);
            if (conv < 2) {
                D = MFMA32(Wh, Xh, D);
                D = MFMA32(Wh, Xl, D);
                D = MFMA32(Wl, Xh, D);
            } else {
                D = MFMA32(Xh, Wh, D);
                D = MFMA32(Xl, Wh, D);
                D = MFMA32(Xh, Wl, D);
            }
        }
    }

    if (conv < 2) {
        unsigned short sh[16], sl[16];
#pragma unroll
        for (int r = 0; r < 16; ++r) split2(D[r], sh[r], sl[r]);
        unsigned int ah0 = sh[0] | ((unsigned int)sh[1] << 16), ah1 = sh[2] | ((unsigned int)sh[3] << 16);
        unsigned int ah2 = sh[4] | ((unsigned int)sh[5] << 16), ah3 = sh[6] | ((unsigned int)sh[7] << 16);
        pl32swap(ah0, ah2); pl32swap(ah1, ah3);
        s8v F0h = mk8(ah0, ah1, ah2, ah3);
        unsigned int al0 = sl[0] | ((unsigned int)sl[1] << 16), al1 = sl[2] | ((unsigned int)sl[3] << 16);
        unsigned int al2 = sl[4] | ((unsigned int)sl[5] << 16), al3 = sl[6] | ((unsigned int)sl[7] << 16);
        pl32swap(al0, al2); pl32swap(al1, al3);
        s8v F0l = mk8(al0, al1, al2, al3);
        unsigned int bh0 = sh[8] | ((unsigned int)sh[9] << 16), bh1 = sh[10] | ((unsigned int)sh[11] << 16);
        unsigned int bh2 = sh[12] | ((unsigned int)sh[13] << 16), bh3 = sh[14] | ((unsigned int)sh[15] << 16);
        pl32swap(bh0, bh2); pl32swap(bh1, bh3);
        s8v F1h = mk8(bh0, bh1, bh2, bh3);
        unsigned int bl0 = sl[8] | ((unsigned int)sl[9] << 16), bl1 = sl[10] | ((unsigned int)sl[11] << 16);
        unsigned int bl2 = sl[12] | ((unsigned int)sl[13] << 16), bl3 = sl[14] | ((unsigned int)sl[15] << 16);
        pl32swap(bl0, bl2); pl32swap(bl1, bl3);
        s8v F1l = mk8(bl0, bl1, bl2, bl3);
        unsigned short* dst = (conv == 0) ? Q2 : K2;
        size_t b0 = (size_t)(((b * 128 + nb) * 4 + oc * 2 + 0) * 2) * 512 + lane * 8;
        size_t b1 = (size_t)(((b * 128 + nb) * 4 + oc * 2 + 1) * 2) * 512 + lane * 8;
        *(s8v*)(dst + b0) = F0h;
        *(s8v*)(dst + b0 + 512) = F0l;
        *(s8v*)(dst + b1) = F1h;
        *(s8v*)(dst + b1 + 512) = F1l;
    } else {
        unsigned int a0 = cvtpk(D[0], D[1]),  a1 = cvtpk(D[2], D[3]);
        unsigned int a2 = cvtpk(D[4], D[5]),  a3 = cvtpk(D[6], D[7]);
        pl32swap(a0, a2); pl32swap(a1, a3);
        s8v F0h = mk8(a0, a1, a2, a3);
        unsigned int b0w = cvtpk(D[8], D[9]),  b1w = cvtpk(D[10], D[11]);
        unsigned int b2w = cvtpk(D[12], D[13]), b3w = cvtpk(D[14], D[15]);
        pl32swap(b0w, b2w); pl32swap(b1w, b3w);
        s8v F1h = mk8(b0w, b1w, b2w, b3w);
        size_t v0 = (size_t)(((b * 128 + nb) * 2 + 0) * 2 + oc) * 512 + lane * 8;
        size_t v1 = (size_t)(((b * 128 + nb) * 2 + 1) * 2 + oc) * 512 + lane * 8;
        *(s8v*)(V2 + v0) = F0h;
        *(s8v*)(V2 + v1) = F1h;
    }
}

// ---------------- channel Gram via MFMA: grid (16 kp, 4 b), 4 waves = (cb1,cb2)
__global__ __launch_bounds__(256) void k_gram(const unsigned short* __restrict__ XV2,
                                              float* __restrict__ Gp) {
    int kp = blockIdx.x, b = blockIdx.y;
    int tid = threadIdx.x, lane = tid & 63, wv = tid >> 6;
    int cb1 = wv & 1, cb2 = wv >> 1;
    f16v G = zero16();
#pragma unroll
    for (int t = 0; t < 8; ++t) {
        int ich = kp * 8 + t;
        const unsigned short* base = XV2 + (size_t)(b * 128 + ich) * 2048 + lane * 8;
        s8v a0 = *(const s8v*)(base + (0 * 2 + cb1) * 512);
        s8v b0 = *(const s8v*)(base + (0 * 2 + cb2) * 512);
        s8v a1 = *(const s8v*)(base + (1 * 2 + cb1) * 512);
        s8v b1 = *(const s8v*)(base + (1 * 2 + cb2) * 512);
        G = MFMA32(a0, b0, G);
        G = MFMA32(a1, b1, G);
    }
    int hh = lane >> 5, l31 = lane & 31;
#pragma unroll
    for (int r = 0; r < 16; ++r) {
        int cc = cb1 * 32 + (r & 3) + 8 * (r >> 2) + 4 * hh;   // A's lane -> regs
        int dd = cb2 * 32 + l31;                               // B's lane -> lane
        Gp[(size_t)(kp * 4 + b) * 4096 + cc * 64 + dd] = G[r];
    }
}

// ---------------- channel softmax rows -> A2 bf16 fragments
__global__ void k_asm(const float* __restrict__ Gp, unsigned short* __restrict__ A2) {
    int row = blockIdx.x;      // b*64 + c
    int d = threadIdx.x;
    int b = row >> 6, c = row & 63;
    float g = 0.0f;
#pragma unroll
    for (int p = 0; p < 16; ++p) g += Gp[(size_t)(p * 4 + b) * 4096 + c * 64 + d];
    float mx = g;
    for (int off = 32; off >= 1; off >>= 1) mx = fmaxf(mx, __shfl_xor(mx, off, 64));
    float e = __expf(g - mx);
    float s = e;
    for (int off = 32; off >= 1; off >>= 1) s += __shfl_xor(s, off, 64);
    float a = e / s;
    int cb = c >> 5, kst = d >> 4;
    int lane2 = (c & 31) + 32 * ((d >> 3) & 1);
    A2[(size_t)((b * 2 + cb) * 4 + kst) * 512 + lane2 * 8 + (d & 7)] = bf16_rne(a);
}

// ---------------- pass1: ich-PAIR per block (K stream reused for both ich).
// grid 256 = (b x 64 ichp); block 512 (8 waves x 16 jch). L2 K-traffic halved.
__global__ __launch_bounds__(512, 2) void k_pass1(
        const unsigned short* __restrict__ Q2, const unsigned short* __restrict__ K2,
        float* __restrict__ invl) {
    int flat = blockIdx.x;
    int xcd = flat & 7;
    int b = xcd >> 1;
    int ichp = (xcd & 1) * 32 + (flat >> 3);   // 0..63
    int ich0 = ichp * 2;
    int tid = threadIdx.x, lane = tid & 63, wv = tid >> 6;

    __shared__ float lsum[8][2][32];

    const unsigned short* qp = Q2 + (size_t)(b * 128 + ich0) * 4096 + lane * 8;
    s8v q0f0 = *(const s8v*)(qp);
    s8v q0f1 = *(const s8v*)(qp + 512);
    s8v q0f2 = *(const s8v*)(qp + 1024);
    s8v q0f3 = *(const s8v*)(qp + 1536);
    s8v q0f4 = *(const s8v*)(qp + 2048);
    s8v q0f5 = *(const s8v*)(qp + 2560);
    s8v q0f6 = *(const s8v*)(qp + 3072);
    s8v q0f7 = *(const s8v*)(qp + 3584);
    s8v q1f0 = *(const s8v*)(qp + 4096);
    s8v q1f1 = *(const s8v*)(qp + 4608);
    s8v q1f2 = *(const s8v*)(qp + 5120);
    s8v q1f3 = *(const s8v*)(qp + 5632);
    s8v q1f4 = *(const s8v*)(qp + 6144);
    s8v q1f5 = *(const s8v*)(qp + 6656);
    s8v q1f6 = *(const s8v*)(qp + 7168);
    s8v q1f7 = *(const s8v*)(qp + 7680);

    float la0 = 0.f, la1 = 0.f, lb0 = 0.f, lb1 = 0.f;
#pragma unroll 1
    for (int t = 0; t < 16; ++t) {
        int jch = wv * 16 + t;
        const unsigned short* kp = K2 + (size_t)(b * 128 + jch) * 4096 + lane * 8;
        s8v kf0 = *(const s8v*)(kp);
        s8v kf1 = *(const s8v*)(kp + 512);
        s8v kf2 = *(const s8v*)(kp + 1024);
        s8v kf3 = *(const s8v*)(kp + 1536);
        s8v kf4 = *(const s8v*)(kp + 2048);
        s8v kf5 = *(const s8v*)(kp + 2560);
        s8v kf6 = *(const s8v*)(kp + 3072);
        s8v kf7 = *(const s8v*)(kp + 3584);
        {
            f16v Sa = zero16(), Sb = zero16();
            Sa = MFMA32(kf0, q0f0, Sa);
            Sa = MFMA32(kf0, q0f1, Sa);
            Sa = MFMA32(kf1, q0f0, Sa);
            Sa = MFMA32(kf2, q0f2, Sa);
            Sa = MFMA32(kf2, q0f3, Sa);
            Sa = MFMA32(kf3, q0f2, Sa);
            Sb = MFMA32(kf4, q0f4, Sb);
            Sb = MFMA32(kf4, q0f5, Sb);
            Sb = MFMA32(kf5, q0f4, Sb);
            Sb = MFMA32(kf6, q0f6, Sb);
            Sb = MFMA32(kf6, q0f7, Sb);
            Sb = MFMA32(kf7, q0f6, Sb);
#pragma unroll
            for (int r = 0; r < 8; ++r) la0 += __expf(Sa[r] + Sb[r]);
#pragma unroll
            for (int r = 8; r < 16; ++r) la1 += __expf(Sa[r] + Sb[r]);
        }
        {
            f16v Sa = zero16(), Sb = zero16();
            Sa = MFMA32(kf0, q1f0, Sa);
            Sa = MFMA32(kf0, q1f1, Sa);
            Sa = MFMA32(kf1, q1f0, Sa);
            Sa = MFMA32(kf2, q1f2, Sa);
            Sa = MFMA32(kf2, q1f3, Sa);
            Sa = MFMA32(kf3, q1f2, Sa);
            Sb = MFMA32(kf4, q1f4, Sb);
            Sb = MFMA32(kf4, q1f5, Sb);
            Sb = MFMA32(kf5, q1f4, Sb);
            Sb = MFMA32(kf6, q1f6, Sb);
            Sb = MFMA32(kf6, q1f7, Sb);
            Sb = MFMA32(kf7, q1f6, Sb);
#pragma unroll
            for (int r = 0; r < 8; ++r) lb0 += __expf(Sa[r] + Sb[r]);
#pragma unroll
            for (int r = 8; r < 16; ++r) lb1 += __expf(Sa[r] + Sb[r]);
        }
    }
    float lacc0 = la0 + la1;
    lacc0 += __shfl_xor(lacc0, 32);
    float lacc1 = lb0 + lb1;
    lacc1 += __shfl_xor(lacc1, 32);
    if (lane < 32) {
        lsum[wv][0][lane] = lacc0;
        lsum[wv][1][lane] = lacc1;
    }
    __syncthreads();
    if (tid < 64) {
        int ic = tid >> 5, iL = tid & 31;
        float s = 0.f;
#pragma unroll
        for (int p = 0; p < 8; ++p) s += lsum[p][ic][iL];
        invl[b * 4096 + (ich0 + ic) * 32 + iL] = 1.0f / s;
    }
}

// ---------------- fold invl into V (hi-only, in place)
__global__ __launch_bounds__(256) void k_vnorm(
        unsigned short* __restrict__ V2, const float* __restrict__ invl) {
    int u = blockIdx.x * 256 + threadIdx.x;      // < 131072 16B-segs
    int lane = u & 63, ksub = (u >> 7) & 1;
    int ich = (u >> 8) & 127, b = u >> 15;
    int n0 = ich * 32 + ksub * 16 + (lane >> 5) * 8;
    size_t base = (size_t)u * 8;
    s8v vh = *(s8v*)(V2 + base);
    float4 iv0 = *(const float4*)(invl + b * 4096 + n0);
    float4 iv1 = *(const float4*)(invl + b * 4096 + n0 + 4);
    float ivv[8] = {iv0.x, iv0.y, iv0.z, iv0.w, iv1.x, iv1.y, iv1.z, iv1.w};
    s8v o;
#pragma unroll
    for (int e = 0; e < 8; ++e)
        o[e] = (short)bf16_rne(bf2f((unsigned short)vh[e]) * ivv[e]);
    *(s8v*)(V2 + base) = o;
}

// ---------------- pass2 + fused final: jt-PAIR per block (Q/V stream reused
// for 64 j-cols -> L2 traffic halved). grid 256 = (b x 64 jtp); block 512
// (8 waves = 8 i-parts of 16 chunks). K frags for both jt staged in LDS.
__global__ __launch_bounds__(512, 2) void k_pass2(
        const unsigned short* __restrict__ Q2, const unsigned short* __restrict__ K2,
        const unsigned short* __restrict__ V2, const unsigned short* __restrict__ X2,
        const unsigned short* __restrict__ A2, const float* __restrict__ x,
        const float* __restrict__ pg, const float* __restrict__ cg,
        float* __restrict__ out) {
    int flat = blockIdx.x;
    int xcd = flat & 7;
    int b = xcd >> 1;
    int jtp = (xcd & 1) * 32 + (flat >> 3);   // 0..63
    int jt0 = jtp * 2;
    int tid = threadIdx.x, lane = tid & 63, wv = tid >> 6;

    __shared__ float smem[12288];             // 48 KB
    unsigned short* Klds = (unsigned short*)(smem + 8192);   // 16 KB: [jtsub][8 frags][512]
    float* rl = smem;                         // [4][64][32] reduce buffer

    // stage K for jt0, jt0+1 (contiguous 8192 shorts in K2)
    {
        const unsigned short* ksrc = K2 + (size_t)(b * 128 + jt0) * 4096;
#pragma unroll
        for (int s = 0; s < 2; ++s) {
            int seg = tid + s * 512;
            *(s8v*)(Klds + seg * 8) = *(const s8v*)(ksrc + seg * 8);
        }
    }
    __syncthreads();

    f16v O0a = zero16(), O1a = zero16();   // jt0: c-halves 0/1
    f16v O0b = zero16(), O1b = zero16();   // jt1

#pragma unroll 1
    for (int t = 0; t < 16; ++t) {
        int ich = wv * 16 + t;
        const unsigned short* qp = Q2 + (size_t)(b * 128 + ich) * 4096 + lane * 8;
        s8v qf0 = *(const s8v*)(qp);
        s8v qf1 = *(const s8v*)(qp + 512);
        s8v qf2 = *(const s8v*)(qp + 1024);
        s8v qf3 = *(const s8v*)(qp + 1536);
        s8v qf4 = *(const s8v*)(qp + 2048);
        s8v qf5 = *(const s8v*)(qp + 2560);
        s8v qf6 = *(const s8v*)(qp + 3072);
        s8v qf7 = *(const s8v*)(qp + 3584);
        const unsigned short* vp = V2 + (size_t)(b * 128 + ich) * 2048 + lane * 8;
        s8v vA = *(const s8v*)(vp);
        s8v vB = *(const s8v*)(vp + 512);
        s8v vC = *(const s8v*)(vp + 1024);
        s8v vD = *(const s8v*)(vp + 1536);

#pragma unroll
        for (int js = 0; js < 2; ++js) {
            const unsigned short* kl = Klds + js * 4096 + lane * 8;
            s8v kf0 = *(const s8v*)(kl);
            s8v kf1 = *(const s8v*)(kl + 512);
            s8v kf2 = *(const s8v*)(kl + 1024);
            s8v kf3 = *(const s8v*)(kl + 1536);
            s8v kf4 = *(const s8v*)(kl + 2048);
            s8v kf5 = *(const s8v*)(kl + 2560);
            s8v kf6 = *(const s8v*)(kl + 3072);
            s8v kf7 = *(const s8v*)(kl + 3584);

            f16v Sa = zero16(), Sb = zero16();
            Sa = MFMA32(qf0, kf0, Sa);
            Sa = MFMA32(qf0, kf1, Sa);
            Sa = MFMA32(qf1, kf0, Sa);
            Sa = MFMA32(qf2, kf2, Sa);
            Sa = MFMA32(qf2, kf3, Sa);
            Sa = MFMA32(qf3, kf2, Sa);
            Sb = MFMA32(qf4, kf4, Sb);
            Sb = MFMA32(qf4, kf5, Sb);
            Sb = MFMA32(qf5, kf4, Sb);
            Sb = MFMA32(qf6, kf6, Sb);
            Sb = MFMA32(qf6, kf7, Sb);
            Sb = MFMA32(qf7, kf6, Sb);

            float p[16];
#pragma unroll
            for (int r = 0; r < 16; ++r) p[r] = __expf(Sa[r] + Sb[r]);

            unsigned int a0 = cvtpk(p[0], p[1]),  a1 = cvtpk(p[2], p[3]);
            unsigned int a2 = cvtpk(p[4], p[5]),  a3 = cvtpk(p[6], p[7]);
            pl32swap(a0, a2);
            pl32swap(a1, a3);
            s8v P0 = mk8(a0, a1, a2, a3);
            unsigned int b0 = cvtpk(p[8], p[9]),  b1 = cvtpk(p[10], p[11]);
            unsigned int b2 = cvtpk(p[12], p[13]), b3 = cvtpk(p[14], p[15]);
            pl32swap(b0, b2);
            pl32swap(b1, b3);
            s8v P1 = mk8(b0, b1, b2, b3);

            if (js == 0) {
                O0a = MFMA32(vA, P0, O0a);
                O0a = MFMA32(vC, P1, O0a);
                O1a = MFMA32(vB, P0, O1a);
                O1a = MFMA32(vD, P1, O1a);
            } else {
                O0b = MFMA32(vA, P0, O0b);
                O0b = MFMA32(vC, P1, O0b);
                O1b = MFMA32(vB, P0, O1b);
                O1b = MFMA32(vD, P1, O1b);
            }
        }
    }

    int hh = lane >> 5, jj = lane & 31;
    float s0[4], s1[4];
    // ---- jt0 reduction (two rounds over i-parts)
    if (wv < 4) {
#pragma unroll
        for (int r = 0; r < 16; ++r) {
            int c = (r & 3) + 8 * (r >> 2) + 4 * hh;
            rl[(wv * 64 + c) * 32 + jj] = O0a[r];
            rl[(wv * 64 + c + 32) * 32 + jj] = O1a[r];
        }
    }
    __syncthreads();
#pragma unroll
    for (int k = 0; k < 4; ++k) {
        int el = tid + k * 512;
        s0[k] = ((rl[el] + rl[2048 + el]) + rl[4096 + el]) + rl[6144 + el];
    }
    __syncthreads();
    if (wv >= 4) {
#pragma unroll
        for (int r = 0; r < 16; ++r) {
            int c = (r & 3) + 8 * (r >> 2) + 4 * hh;
            rl[((wv - 4) * 64 + c) * 32 + jj] = O0a[r];
            rl[((wv - 4) * 64 + c + 32) * 32 + jj] = O1a[r];
        }
    }
    __syncthreads();
#pragma unroll
    for (int k = 0; k < 4; ++k) {
        int el = tid + k * 512;
        s0[k] = ((s0[k] + rl[el]) + rl[2048 + el]) + rl[4096 + el];
        s0[k] += rl[6144 + el];
    }
    __syncthreads();
    // ---- jt1 reduction
    if (wv < 4) {
#pragma unroll
        for (int r = 0; r < 16; ++r) {
            int c = (r & 3) + 8 * (r >> 2) + 4 * hh;
            rl[(wv * 64 + c) * 32 + jj] = O0b[r];
            rl[(wv * 64 + c + 32) * 32 + jj] = O1b[r];
        }
    }
    __syncthreads();
#pragma unroll
    for (int k = 0; k < 4; ++k) {
        int el = tid + k * 512;
        s1[k] = ((rl[el] + rl[2048 + el]) + rl[4096 + el]) + rl[6144 + el];
    }
    __syncthreads();
    if (wv >= 4) {
#pragma unroll
        for (int r = 0; r < 16; ++r) {
            int c = (r & 3) + 8 * (r >> 2) + 4 * hh;
            rl[((wv - 4) * 64 + c) * 32 + jj] = O0b[r];
            rl[((wv - 4) * 64 + c + 32) * 32 + jj] = O1b[r];
        }
    }
    __syncthreads();
#pragma unroll
    for (int k = 0; k < 4; ++k) {
        int el = tid + k * 512;
        s1[k] = ((s1[k] + rl[el]) + rl[2048 + el]) + rl[4096 + el];
        s1[k] += rl[6144 + el];
    }
    __syncthreads();                 // smem free for epilogue

    // ---- epilogue: chan apply (MFMA) + residual, for both jt
    float* chan = smem;              // [64][65] = 4160 floats
    float* xres = smem + 4160;       // [64][64] = 4096 floats
    if (wv < 4) {
        int jts = wv >> 1, cb = wv & 1;
        f16v Dc = zero16();
#pragma unroll
        for (int kst = 0; kst < 4; ++kst) {
            s8v af = *(const s8v*)(A2 + (size_t)((b * 2 + cb) * 4 + kst) * 512 + lane * 8);
            s8v xf = *(const s8v*)(X2 + (size_t)((b * 128 + jt0 + jts) * 4 + kst) * 512 + lane * 8);
            Dc = MFMA32(af, xf, Dc);
        }
#pragma unroll
        for (int r = 0; r < 16; ++r) {
            int c = cb * 32 + (r & 3) + 8 * (r >> 2) + 4 * hh;   // A's lane -> regs
            chan[c * 65 + jts * 32 + jj] = Dc[r];                // B's lane (n) -> lane
        }
    }
#pragma unroll
    for (int k = 0; k < 8; ++k) {
        int el = tid + k * 512;
        int c = el >> 6, j2 = el & 63;
        xres[el] = x[(size_t)(b * 64 + c) * 4096 + jtp * 64 + j2];
    }
    __syncthreads();
    float pgv = pg[0], cgv = cg[0];
#pragma unroll
    for (int k = 0; k < 4; ++k) {
        int el = tid + k * 512;
        int c = el >> 5, j2 = el & 31;
        size_t ob = (size_t)(b * 64 + c) * 4096 + jtp * 64;
        out[ob + j2] = pgv * s0[k] + cgv * chan[c * 65 + j2] + 2.0f * xres[c * 64 + j2];
        out[ob + 32 + j2] = pgv * s1[k] + cgv * chan[c * 65 + 32 + j2] + 2.0f * xres[c * 64 + 32 + j2];
    }
}

extern "C" void kernel_launch(void* const* d_in, const int* in_sizes, int n_in,
                              void* d_out, int out_size, void* d_ws, size_t ws_size,
                              hipStream_t stream) {
    const float* x  = (const float*)d_in[0];
    const float* wq = (const float*)d_in[1];
    const float* bq = (const float*)d_in[2];
    const float* wk = (const float*)d_in[3];
    const float* bk = (const float*)d_in[4];
    const float* wv = (const float*)d_in[5];
    const float* bv = (const float*)d_in[6];
    const float* pg = (const float*)d_in[7];
    const float* cg = (const float*)d_in[8];
    float* out = (float*)d_out;

    if (ws_size < (size_t)WS_FLOATS * sizeof(float)) return;
    float* ws = (float*)d_ws;
    unsigned short* XV2 = (unsigned short*)(ws + OFF_XV2);
    float* Gp = ws + OFF_GP;
    unsigned short* Q2  = (unsigned short*)(ws + OFF_Q2);
    unsigned short* K2  = (unsigned short*)(ws + OFF_K2);
    unsigned short* V2  = (unsigned short*)(ws + OFF_V2);
    unsigned short* X2  = (unsigned short*)(ws + OFF_X2);
    unsigned short* wfb = (unsigned short*)(ws + OFF_WT);
    float* invl = ws + OFF_INVL;
    unsigned short* A2  = (unsigned short*)(ws + OFF_A);

    k_wtrans<<<432, 256, 0, stream>>>(wq, wk, wv, wfb);
    k_xpack<<<1024, 256, 0, stream>>>(x, X2, XV2);
    k_conv<<<dim3(128, 4), 384, 0, stream>>>(x, wfb, bq, bk, bv, Q2, K2, V2);
    k_gram<<<dim3(16, 4), 256, 0, stream>>>(XV2, Gp);
    k_asm<<<256, 64, 0, stream>>>(Gp, A2);
    k_pass1<<<256, 512, 0, stream>>>(Q2, K2, invl);
    k_vnorm<<<512, 256, 0, stream>>>(V2, invl);
    k_pass2<<<256, 512, 0, stream>>>(Q2, K2, V2, X2, A2, x, pg, cg, out);
}